// Round 7
// baseline (620.373 us; speedup 1.0000x reference)
//
#include <hip/hip_runtime.h>
#include <math.h>

#define LL 2048
#define MM 12
#define DD 128
#define TP 256   // T
#define MEGA_LDS 78464

typedef short short8 __attribute__((ext_vector_type(8)));
typedef short short4v __attribute__((ext_vector_type(4)));
typedef float float4v __attribute__((ext_vector_type(4)));

static __device__ __forceinline__ unsigned short f2b(float f) {
  union { float f; unsigned int u; } x; x.f = f;
  unsigned int r = x.u + 0x7fffu + ((x.u >> 16) & 1u);
  return (unsigned short)(r >> 16);
}
static __device__ __forceinline__ float b2f(unsigned short u) {
  union { unsigned int u; float f; } x; x.u = ((unsigned int)u) << 16;
  return x.f;
}
// branch-free erf (A&S 7.1.26, |err| <= ~5e-7): rcp + exp + 5 FMA
static __device__ __forceinline__ float fast_gelu(float x) {
  float xs = x * 0.70710678118654752f;
  float y = fabsf(xs);
  float t = __builtin_amdgcn_rcpf(fmaf(0.3275911f, y, 1.0f));
  float p = fmaf(fmaf(fmaf(fmaf(1.061405429f, t, -1.453152027f), t,
                           1.421413741f), t, -0.284496736f), t, 0.254829592f);
  p = p * t;
  float e = __expf(-y * y);
  float er = fmaf(-p, e, 1.0f);
  er = copysignf(er, xs);
  return 0.5f * x * (1.0f + er);
}
static __device__ __forceinline__ float qxor1(float x) {
  int r = __builtin_amdgcn_mov_dpp(__builtin_bit_cast(int, x), 0xB1, 0xF, 0xF, true);
  return __builtin_bit_cast(float, r);
}
static __device__ __forceinline__ float qxor2(float x) {
  int r = __builtin_amdgcn_mov_dpp(__builtin_bit_cast(int, x), 0x4E, 0xF, 0xF, true);
  return __builtin_bit_cast(float, r);
}

// ---------------- convert weights to bf16 (pw, in_w, out_w, padded xp_w, padded ew, padded fc_w) ----------------
// grid 5168x256: first 274432 ids = small weights; remaining 1048576 = fc_w -> fwbf [32][32768]
__global__ __launch_bounds__(256) void k_cvt(const float* __restrict__ pw_w, const float* __restrict__ in_w,
                                             const float* __restrict__ out_w, const float* __restrict__ xp_w,
                                             const float* __restrict__ ew, const float* __restrict__ fw,
                                             unsigned short* __restrict__ pwbf, unsigned short* __restrict__ fwbf) {
  int i = blockIdx.x * 256 + threadIdx.x;
  if (i >= 274432) {
    int j = i - 274432;
    int m = j >> 15, k = j & 32767;
    fwbf[j] = f2b((m < 18) ? fw[m * 32768 + k] : 0.0f);
    return;
  }
  if (i < 49152) { pwbf[i] = f2b(pw_w[i]); return; }
  int i2 = i - 49152;
  if (i2 < 131072) { pwbf[i] = f2b(in_w[i2]); return; }
  int i3 = i2 - 131072;
  if (i3 < 65536) { pwbf[i] = f2b(out_w[i3]); return; }
  int i4 = i3 - 65536;
  if (i4 < 24576) {
    int layer = (i4 < 12288) ? 0 : 1;
    int rem = i4 - layer * 12288;
    int k = rem >> 8, c = rem & 255;
    float v = (k < 40) ? xp_w[layer * 10240 + k * 256 + c] : 0.0f;
    pwbf[i] = f2b(v);
    return;
  }
  int i5 = i4 - 24576;
  if (i5 < 4096) {
    int d = i5 >> 5, k = i5 & 31;
    float v = (k < 16) ? ew[d * 16 + k] : 0.0f;
    pwbf[i] = f2b(v);
  }
}

// ---------------- embedding via MFMA ----------------
__global__ __launch_bounds__(256) void k_emb(const float* __restrict__ inp,
                                             const unsigned short* __restrict__ ewbf,
                                             const float* __restrict__ eb,
                                             unsigned short* __restrict__ xe) {
  int sig = blockIdx.x;
  int b = sig / MM, m = sig % MM;
  __shared__ float xs[LL];
  const float* ib = inp + (size_t)b * LL * MM + m;
  int tid = threadIdx.x;
  for (int i = tid; i < LL; i += 256) xs[i] = ib[(size_t)i * MM];
  __syncthreads();
  int wv = tid >> 6, ln = tid & 15, q = (tid >> 4) & 3;
  short8 af[8];
#pragma unroll
  for (int et = 0; et < 8; ++et)
    af[et] = *(const short8*)(ewbf + (et * 16 + ln) * 32 + q * 8);
#pragma unroll
  for (int pass = 0; pass < 4; ++pass) {
    int t = pass * 64 + wv * 16 + ln;
    int l0 = t * 8 - 4;
    short8 bfrag;
#pragma unroll
    for (int j = 0; j < 8; ++j) {
      int k = q * 8 + j;
      int l = l0 + k;
      float v = (k < 16 && l >= 0 && l < LL) ? xs[l] : 0.0f;
      bfrag[j] = (short)f2b(v);
    }
    float4v acc[8];
#pragma unroll
    for (int et = 0; et < 8; ++et) {
      acc[et] = (float4v){0.f, 0.f, 0.f, 0.f};
      acc[et] = __builtin_amdgcn_mfma_f32_16x16x32_bf16(af[et], bfrag, acc[et], 0, 0, 0);
    }
    unsigned short* orow = xe + (size_t)sig * 32768 + (size_t)t * 128;
#pragma unroll
    for (int et = 0; et < 8; ++et) {
      int e = et * 16 + q * 4;
      float4 pb = *(const float4*)&eb[e];
      short4v st = {(short)f2b(acc[et][0] + pb.x), (short)f2b(acc[et][1] + pb.y),
                    (short)f2b(acc[et][2] + pb.z), (short)f2b(acc[et][3] + pb.w)};
      *(short4v*)(orow + e) = st;
    }
  }
}

// ---------------- MEGA block stage: all 3 layers + SE, signal resident in LDS ----------------
// grid 768 x 512 threads; dynamic LDS 78464 B
// Register-diet variant: af JIT-loaded per et (same #loads, 4 live regs vs 32),
// wt JIT-loaded per (tl,k) from dwT (lane-broadcast LDS reads, ~free).
// __launch_bounds__(512,4): 16 waves/CU = 2 blocks/CU (unified VGPR+AGPR <= 128/thread)
__global__ __launch_bounds__(512, 4) void k_mega(const unsigned short* __restrict__ u0,
                                              const float* __restrict__ dww, const float* __restrict__ dwb,
                                              const unsigned short* __restrict__ pwbf,
                                              const float* __restrict__ pwb,
                                              const float* __restrict__ w1, const float* __restrict__ b1,
                                              const float* __restrict__ w2, const float* __restrict__ b2,
                                              unsigned short* __restrict__ uout) {
  extern __shared__ char smemraw[];
  unsigned short* us = (unsigned short*)smemraw;
  float* dwT  = (float*)(smemraw + 69632);
  float* dwbL = dwT + 640;
  float* pwbL = dwbL + 128;
  float* sred = pwbL + 128;
  float* smv  = sred + 1024;
  float* hh   = smv + 128;
  float* aL   = hh + 32;

  int sig = blockIdx.x;
  int tid = threadIdx.x;
  const size_t gbase = (size_t)sig * 32768;
  int cu = tid & 15;
  int r0 = tid >> 4;   // 0..31

#pragma unroll
  for (int p = 0; p < 8; ++p) {
    int t = p * 32 + r0;
    short8 v = *(const short8*)(u0 + gbase + (size_t)t * 128 + cu * 8);
    *(short8*)(us + t * 136 + cu * 8) = v;
  }

  int wv = tid >> 6;
  int ln = tid & 15;
  int q  = (tid >> 4) & 3;
  int tb = wv * 32;

  for (int layer = 0; layer < 3; ++layer) {
    __syncthreads();
    for (int i = tid; i < 640; i += 512) dwT[(i % 5) * 128 + (i / 5)] = dww[layer * 640 + i];
    if (tid < 128) { dwbL[tid] = dwb[layer * 128 + tid]; pwbL[tid] = pwb[layer * 128 + tid]; }
    __syncthreads();

    const unsigned short* pwL = pwbf + layer * 16384;
    float4v acc[2][8];
#pragma unroll
    for (int tl = 0; tl < 2; ++tl)
#pragma unroll
      for (int et = 0; et < 8; ++et) acc[tl][et] = (float4v){0.f, 0.f, 0.f, 0.f};

#pragma unroll
    for (int kc = 0; kc < 4; ++kc) {
      int dc = kc * 32 + q * 8;
      float bl8[8];
      {
        float4 ba = *(const float4*)&dwbL[dc];
        float4 bb2 = *(const float4*)&dwbL[dc + 4];
        bl8[0] = ba.x; bl8[1] = ba.y; bl8[2] = ba.z; bl8[3] = ba.w;
        bl8[4] = bb2.x; bl8[5] = bb2.y; bl8[6] = bb2.z; bl8[7] = bb2.w;
      }
      short8 bf[2];
#pragma unroll
      for (int tl = 0; tl < 2; ++tl) {
        int t = tb + tl * 16 + ln;
        float a8[8];
#pragma unroll
        for (int j = 0; j < 8; ++j) a8[j] = bl8[j];
#pragma unroll
        for (int k = 0; k < 5; ++k) {
          int tt = t - 2 + k;
          if (tt >= 0 && tt < 256) {
            short8 u8 = *(const short8*)(us + tt * 136 + dc);
            float4 wa = *(const float4*)&dwT[k * 128 + dc];      // lane-broadcast
            float4 wb = *(const float4*)&dwT[k * 128 + dc + 4];  // lane-broadcast
            a8[0] += b2f((unsigned short)u8[0]) * wa.x;
            a8[1] += b2f((unsigned short)u8[1]) * wa.y;
            a8[2] += b2f((unsigned short)u8[2]) * wa.z;
            a8[3] += b2f((unsigned short)u8[3]) * wa.w;
            a8[4] += b2f((unsigned short)u8[4]) * wb.x;
            a8[5] += b2f((unsigned short)u8[5]) * wb.y;
            a8[6] += b2f((unsigned short)u8[6]) * wb.z;
            a8[7] += b2f((unsigned short)u8[7]) * wb.w;
          }
        }
#pragma unroll
        for (int j = 0; j < 8; ++j)
          bf[tl][j] = (short)f2b(fast_gelu(a8[j]));
      }
#pragma unroll
      for (int et = 0; et < 8; ++et) {
        short8 af = *(const short8*)(pwL + (size_t)(et * 16 + ln) * 128 + dc);  // JIT, L2-hot
        acc[0][et] = __builtin_amdgcn_mfma_f32_16x16x32_bf16(af, bf[0], acc[0][et], 0, 0, 0);
        acc[1][et] = __builtin_amdgcn_mfma_f32_16x16x32_bf16(af, bf[1], acc[1][et], 0, 0, 0);
      }
    }
    __syncthreads();   // all us reads done; sred free

    // SE t-partial sums -> sred
#pragma unroll
    for (int et = 0; et < 8; ++et) {
      int e = et * 16 + q * 4;
      float4 pb = *(const float4*)&pwbL[e];
      float sv0 = acc[0][et][0] + acc[1][et][0] + 2.0f * pb.x;
      float sv1 = acc[0][et][1] + acc[1][et][1] + 2.0f * pb.y;
      float sv2 = acc[0][et][2] + acc[1][et][2] + 2.0f * pb.z;
      float sv3 = acc[0][et][3] + acc[1][et][3] + 2.0f * pb.w;
#pragma unroll
      for (int m = 1; m <= 8; m <<= 1) {
        sv0 += __shfl_xor(sv0, m, 64);
        sv1 += __shfl_xor(sv1, m, 64);
        sv2 += __shfl_xor(sv2, m, 64);
        sv3 += __shfl_xor(sv3, m, 64);
      }
      if (ln == 0) {
        float4 sv = {sv0, sv1, sv2, sv3};
        *(float4*)&sred[wv * 128 + e] = sv;
      }
    }
    __syncthreads();
    if (tid < 128) {
      float s = 0.f;
#pragma unroll
      for (int w = 0; w < 8; ++w) s += sred[w * 128 + tid];
      smv[tid] = s * (1.0f / 256.0f);
    }
    __syncthreads();
    // SE hidden layer: 256 threads, 8 lanes per output, shuffle-reduce
    if (tid < 256) {
      int o = tid >> 3, part = tid & 7;
      const float* wr = w1 + layer * 4096 + o * 128 + part * 16;
      const float* sv = smv + part * 16;
      float s = 0.f;
#pragma unroll
      for (int j = 0; j < 16; j += 4) {
        float4 w4 = *(const float4*)(wr + j);
        float4 v4 = *(const float4*)(sv + j);
        s += w4.x * v4.x + w4.y * v4.y + w4.z * v4.z + w4.w * v4.w;
      }
      s += __shfl_xor(s, 1, 64);
      s += __shfl_xor(s, 2, 64);
      s += __shfl_xor(s, 4, 64);
      if (part == 0) hh[o] = fmaxf(s + b1[layer * 32 + o], 0.0f);
    }
    __syncthreads();
    // SE gate: all 512 threads, 4 lanes per output
    {
      int o = tid >> 2, part = tid & 3;
      const float* wr = w2 + layer * 4096 + o * 32 + part * 8;
      float s = 0.f;
#pragma unroll
      for (int j = 0; j < 8; j += 4) {
        float4 w4 = *(const float4*)(wr + j);
        float4 h4 = *(const float4*)(hh + part * 8 + j);
        s += w4.x * h4.x + w4.y * h4.y + w4.z * h4.z + w4.w * h4.w;
      }
      s += __shfl_xor(s, 1, 64);
      s += __shfl_xor(s, 2, 64);
      if (part == 0) aL[o] = 1.0f / (1.0f + __expf(-(s + b2[layer * 128 + o])));
    }
    __syncthreads();

    // u += w * a  (in LDS, disjoint per lane)
#pragma unroll
    for (int tl = 0; tl < 2; ++tl) {
      int t = tb + tl * 16 + ln;
#pragma unroll
      for (int et = 0; et < 8; ++et) {
        int e = et * 16 + q * 4;
        float4 pb = *(const float4*)&pwbL[e];
        float4 ga = *(const float4*)&aL[e];
        short4v u4 = *(short4v*)(us + t * 136 + e);
        short4v r;
        r[0] = (short)f2b(b2f((unsigned short)u4[0]) + (acc[tl][et][0] + pb.x) * ga.x);
        r[1] = (short)f2b(b2f((unsigned short)u4[1]) + (acc[tl][et][1] + pb.y) * ga.y);
        r[2] = (short)f2b(b2f((unsigned short)u4[2]) + (acc[tl][et][2] + pb.z) * ga.z);
        r[3] = (short)f2b(b2f((unsigned short)u4[3]) + (acc[tl][et][3] + pb.w) * ga.w);
        *(short4v*)(us + t * 136 + e) = r;
      }
    }
  }
  __syncthreads();
#pragma unroll
  for (int p = 0; p < 8; ++p) {
    int t = p * 32 + r0;
    short8 v = *(short8*)(us + t * 136 + cu * 8);
    *(short8*)(uout + gbase + (size_t)t * 128 + cu * 8) = v;
  }
}

// ---------------- mean over M -> xe2 fp32 + xe2bf bf16 ----------------
__global__ __launch_bounds__(256) void k_reduce2(const unsigned short* __restrict__ u,
                                                 float* __restrict__ xe2,
                                                 unsigned short* __restrict__ xe2bf) {
  int i = blockIdx.x * 256 + threadIdx.x;
  int d0 = (i & 15) * 8;
  int t = (i >> 4) & 255;
  int b = i >> 12;
  float acc[8] = {0.f, 0.f, 0.f, 0.f, 0.f, 0.f, 0.f, 0.f};
#pragma unroll 4
  for (int m = 0; m < 12; ++m) {
    size_t base = ((size_t)(b * 12 + m) * 256 + t) * 128 + d0;
    short8 u8 = *(const short8*)(u + base);
#pragma unroll
    for (int j = 0; j < 8; ++j) acc[j] += b2f((unsigned short)u8[j]);
  }
  size_t off = (size_t)b * 32768 + (size_t)t * 128 + d0;
  float4 o0 = {acc[0] / 12.f, acc[1] / 12.f, acc[2] / 12.f, acc[3] / 12.f};
  float4 o1 = {acc[4] / 12.f, acc[5] / 12.f, acc[6] / 12.f, acc[7] / 12.f};
  *(float4*)(xe2 + off) = o0;
  *(float4*)(xe2 + off + 4) = o1;
  short8 ob;
#pragma unroll
  for (int j = 0; j < 8; ++j) ob[j] = (short)f2b(acc[j] / 12.f);
  *(short8*)(xe2bf + off) = ob;
}

// ---------------- mamba: in-projection via MFMA, zero-LDS -> bf16 xz[t][e] ----------------
__global__ __launch_bounds__(256) void k_inproj(const unsigned short* __restrict__ xe2bf,
                                                const unsigned short* __restrict__ inwbf,
                                                unsigned short* __restrict__ xz) {
  int blk = blockIdx.x;
  int b = blk >> 3;
  int tt = (blk >> 1) & 3;
  int eh = blk & 1;
  int t0 = tt * 64, e0 = eh * 256;
  int tid = threadIdx.x;
  int wv = tid >> 6, ln = tid & 15, q = (tid >> 4) & 3;
  int t = t0 + wv * 16 + ln;
  const unsigned short* xrow = xe2bf + ((size_t)b * 256 + t) * 128 + q * 8;
  short8 bfrag[4];
#pragma unroll
  for (int kc = 0; kc < 4; ++kc) bfrag[kc] = *(const short8*)(xrow + kc * 32);
  float4v acc[16];
#pragma unroll
  for (int et = 0; et < 16; ++et) acc[et] = (float4v){0.f, 0.f, 0.f, 0.f};
#pragma unroll
  for (int et = 0; et < 16; ++et) {
    const unsigned short* arow = inwbf + (size_t)(e0 + et * 16 + ln) * 128 + q * 8;
#pragma unroll
    for (int kc = 0; kc < 4; ++kc) {
      short8 af = *(const short8*)(arow + kc * 32);
      acc[et] = __builtin_amdgcn_mfma_f32_16x16x32_bf16(af, bfrag[kc], acc[et], 0, 0, 0);
    }
  }
  unsigned short* orow = xz + ((size_t)b * 256 + t) * 512 + e0 + q * 4;
#pragma unroll
  for (int et = 0; et < 16; ++et) {
    short4v st = {(short)f2b(acc[et][0]), (short)f2b(acc[et][1]),
                  (short)f2b(acc[et][2]), (short)f2b(acc[et][3])};
    *(short4v*)(orow + et * 16) = st;
  }
}

// ---------------- mamba: fused causal conv+SiLU -> x-projection MFMA; writes xc + dbl ----------------
__global__ __launch_bounds__(256) void k_xproj(const unsigned short* __restrict__ xz,
                                               const float* __restrict__ cw, const float* __restrict__ cb,
                                               const unsigned short* __restrict__ xwbf,
                                               unsigned short* __restrict__ xcg,
                                               float* __restrict__ dbl) {
  __shared__ unsigned short xis[67 * 264];
  int blk = blockIdx.x;
  int b = blk >> 2;
  int tq = blk & 3;
  int t0 = tq * 64;
  int tid = threadIdx.x;

  const short8 ZV = {0, 0, 0, 0, 0, 0, 0, 0};
  for (int idx = tid; idx < 2144; idx += 256) {
    int row = idx >> 5, cu = idx & 31;
    int t = t0 - 3 + row;
    short8 v = ZV;
    if (t >= 0) v = *(const short8*)(xz + ((size_t)b * 256 + t) * 512 + cu * 8);
    *(short8*)(xis + row * 264 + cu * 8) = v;
  }
  __syncthreads();

  int cu = tid & 31;
  int rb = tid >> 5;
  int c8 = cu * 8;
  float wl[4][8], bl[8];
#pragma unroll
  for (int j = 0; j < 8; ++j) {
    float4 w4 = *(const float4*)&cw[(c8 + j) * 4];
    wl[0][j] = w4.x; wl[1][j] = w4.y; wl[2][j] = w4.z; wl[3][j] = w4.w;
    bl[j] = cb[c8 + j];
  }

  short8 vv[4];
#pragma unroll
  for (int s = 0; s < 4; ++s) {
    int r = rb + s * 8;
    float acc[8];
#pragma unroll
    for (int j = 0; j < 8; ++j) acc[j] = bl[j];
#pragma unroll
    for (int k = 0; k < 4; ++k) {
      short8 u8 = *(const short8*)(xis + (r + k) * 264 + c8);
#pragma unroll
      for (int j = 0; j < 8; ++j) acc[j] += b2f((unsigned short)u8[j]) * wl[k][j];
    }
#pragma unroll
    for (int j = 0; j < 8; ++j)
      vv[s][j] = (short)f2b(acc[j] / (1.0f + __expf(-acc[j])));
    *(short8*)(xcg + ((size_t)b * 256 + t0 + r) * 256 + c8) = vv[s];
  }
  __syncthreads();
#pragma unroll
  for (int s = 0; s < 4; ++s)
    *(short8*)(xis + (rb + s * 8) * 264 + c8) = vv[s];

#pragma unroll
  for (int s = 0; s < 4; ++s) {
    int r = 32 + rb + s * 8;
    float acc[8];
#pragma unroll
    for (int j = 0; j < 8; ++j) acc[j] = bl[j];
#pragma unroll
    for (int k = 0; k < 4; ++k) {
      short8 u8 = *(const short8*)(xis + (r + k) * 264 + c8);
#pragma unroll
      for (int j = 0; j < 8; ++j) acc[j] += b2f((unsigned short)u8[j]) * wl[k][j];
    }
#pragma unroll
    for (int j = 0; j < 8; ++j)
      vv[s][j] = (short)f2b(acc[j] / (1.0f + __expf(-acc[j])));
    *(short8*)(xcg + ((size_t)b * 256 + t0 + r) * 256 + c8) = vv[s];
  }
  __syncthreads();
#pragma unroll
  for (int s = 0; s < 4; ++s)
    *(short8*)(xis + (32 + rb + s * 8) * 264 + c8) = vv[s];
  __syncthreads();

  int wv = tid >> 6, ln = tid & 15, q = (tid >> 4) & 3;
  int tl = wv * 16 + ln;
  short8 bfrag[8];
#pragma unroll
  for (int kc = 0; kc < 8; ++kc)
    bfrag[kc] = *(const short8*)(xis + tl * 264 + kc * 32 + q * 8);
  float4v acc[3];
#pragma unroll
  for (int et = 0; et < 3; ++et) acc[et] = (float4v){0.f, 0.f, 0.f, 0.f};
#pragma unroll
  for (int et = 0; et < 3; ++et) {
    const unsigned short* arow = xwbf + (size_t)(et * 16 + ln) * 256 + q * 8;
#pragma unroll
    for (int kc = 0; kc < 8; ++kc) {
      short8 af = *(const short8*)(arow + kc * 32);
      acc[et] = __builtin_amdgcn_mfma_f32_16x16x32_bf16(af, bfrag[kc], acc[et], 0, 0, 0);
    }
  }
  float* drow = dbl + ((size_t)b * 256 + t0 + tl) * 40;
#pragma unroll
  for (int et = 0; et < 3; ++et)
#pragma unroll
    for (int r = 0; r < 4; ++r) {
      int k = et * 16 + q * 4 + r;
      if (k < 40) drow[k] = acc[et][r];
    }
}

// ---------------- mamba: fused dt + selective scan + y-finalize ----------------
// 256 threads: parallel phases stride 256 (8 waves/CU); serial scan keeps the
// original 128-thread lane mapping (guarded, no barrier inside guard)
__global__ __launch_bounds__(256) void k_scan2(const float* __restrict__ dbl,
                                               const unsigned short* __restrict__ xc,
                                               const unsigned short* __restrict__ xz,
                                               const float* __restrict__ Alog,
                                               const float* __restrict__ dtw, const float* __restrict__ dtbv,
                                               const float* __restrict__ Dp, unsigned short* __restrict__ y) {
  __shared__ float ds[32][40];
  __shared__ float dxs[32][32][4];
  __shared__ float yl[32][32];
  __shared__ float dtwL[32][8];
  __shared__ float dtbL[32];
  __shared__ float DpL[32];

  int b = blockIdx.x >> 3;
  int c0 = (blockIdx.x & 7) * 32;
  int tid = threadIdx.x;

  for (int idx = tid; idx < 256; idx += 256) dtwL[idx >> 3][idx & 7] = dtw[(c0 + (idx >> 3)) * 8 + (idx & 7)];
  if (tid < 32) { dtbL[tid] = dtbv[c0 + tid]; DpL[tid] = Dp[c0 + tid]; }

  int lane = tid & 63;
  int wv = tid >> 6;
  int c_loc = (wv & 1) * 16 + (lane >> 2);   // masked so tid>=128 stays in-bounds
  int c = c0 + c_loc;
  int sblk = (lane & 3) * 4;

  float4 Al = *(const float4*)&Alog[c * 16 + sblk];
  float A[4] = {-__expf(Al.x), -__expf(Al.y), -__expf(Al.z), -__expf(Al.w)};
  float h[4] = {0.f, 0.f, 0.f, 0.f};

  const float* dbp = dbl + (size_t)b * 10240;
  const unsigned short* xcp = xc + (size_t)b * 65536;
  const unsigned short* xzp = xz + (size_t)b * 131072;
  unsigned short* yp = y + (size_t)b * 65536;

  for (int chk = 0; chk < 8; ++chk) {
    int t0c = chk * 32;
    for (int idx = tid; idx < 1280; idx += 256) ((float*)ds)[idx] = dbp[t0c * 40 + idx];
    for (int idx = tid; idx < 512; idx += 256) {
      int t = idx >> 4, cc2 = (idx & 15) * 2;
      ushort2 xv = *(const ushort2*)&xcp[(size_t)(t0c + t) * 256 + c0 + cc2];
      ushort2 zv = *(const ushort2*)&xzp[(size_t)(t0c + t) * 512 + 256 + c0 + cc2];
      dxs[t][cc2][1] = b2f(xv.x);
      dxs[t][cc2 + 1][1] = b2f(xv.y);
      dxs[t][cc2][2] = b2f(zv.x);
      dxs[t][cc2 + 1][2] = b2f(zv.y);
    }
    __syncthreads();
    for (int idx = tid; idx < 1024; idx += 256) {
      int t = idx >> 5, cc = idx & 31;
      const float* dr = ds[t];
      const float* wr = dtwL[cc];
      float acc = dtbL[cc];
#pragma unroll
      for (int j = 0; j < 8; ++j) acc += wr[j] * dr[j];
      dxs[t][cc][0] = (acc > 20.0f) ? acc : __logf(1.0f + __expf(acc));
    }
    __syncthreads();
    if (tid < 128) {
#pragma unroll 4
      for (int t = 0; t < 32; ++t) {
        float4 dx = *(const float4*)&dxs[t][c_loc][0];
        float4 Bv = *(const float4*)&ds[t][8 + sblk];
        float4 Cv = *(const float4*)&ds[t][24 + sblk];
        float dtv = dx.x;
        float bx = dtv * dx.y;
        h[0] = __expf(dtv * A[0]) * h[0] + Bv.x * bx;
        h[1] = __expf(dtv * A[1]) * h[1] + Bv.y * bx;
        h[2] = __expf(dtv * A[2]) * h[2] + Bv.z * bx;
        h[3] = __expf(dtv * A[3]) * h[3] + Bv.w * bx;
        float p = h[0] * Cv.x;
        p = fmaf(h[1], Cv.y, p);
        p = fmaf(h[2], Cv.z, p);
        p = fmaf(h[3], Cv.w, p);
        p += qxor1(p);
        p += qxor2(p);
        if ((lane & 3) == 0) yl[t][c_loc] = p;
      }
    }
    __syncthreads();
    for (int idx = tid; idx < 512; idx += 256) {
      int t = idx >> 4, cc2 = (idx & 15) * 2;
      float p0 = yl[t][cc2], p1 = yl[t][cc2 + 1];
      float x0 = dxs[t][cc2][1], x1 = dxs[t][cc2 + 1][1];
      float z0 = dxs[t][cc2][2], z1 = dxs[t][cc2 + 1][2];
      float s0 = z0 / (1.0f + __expf(-z0));
      float s1 = z1 / (1.0f + __expf(-z1));
      ushort2 o = {f2b((p0 + DpL[cc2] * x0) * s0), f2b((p1 + DpL[cc2 + 1] * x1) * s1)};
      *(ushort2*)&yp[(size_t)(t0c + t) * 256 + c0 + cc2] = o;
    }
    __syncthreads();
  }
}

// ---------------- mamba: MFMA out-projection + residual + LayerNorm, zero-LDS ----------------
__global__ __launch_bounds__(128) void k_outln(const unsigned short* __restrict__ yb,
                                               const unsigned short* __restrict__ owbf,
                                               float* __restrict__ xe2, unsigned short* __restrict__ xe2bf,
                                               const float* __restrict__ g, const float* __restrict__ bb) {
  int blk = blockIdx.x;
  int b = blk >> 3;
  int t0 = (blk & 7) * 32;
  int tid = threadIdx.x;
  int wv = tid >> 6, ln = tid & 15, q = (tid >> 4) & 3;
  int t = t0 + wv * 16 + ln;

  const unsigned short* yrow = yb + ((size_t)b * 256 + t) * 256 + q * 8;
  short8 bfrag[8];
#pragma unroll
  for (int kc = 0; kc < 8; ++kc) bfrag[kc] = *(const short8*)(yrow + kc * 32);

  float4v acc[8];
#pragma unroll
  for (int et = 0; et < 8; ++et) acc[et] = (float4v){0.f, 0.f, 0.f, 0.f};
#pragma unroll
  for (int et = 0; et < 8; ++et) {
    const unsigned short* arow = owbf + (size_t)(et * 16 + ln) * 256 + q * 8;
#pragma unroll
    for (int kc = 0; kc < 8; ++kc) {
      short8 af = *(const short8*)(arow + kc * 32);
      acc[et] = __builtin_amdgcn_mfma_f32_16x16x32_bf16(af, bfrag[kc], acc[et], 0, 0, 0);
    }
  }

  float* xrow = xe2 + ((size_t)b * 256 + t) * 128;
  float vals[8][4];
  float s1 = 0.f, s2 = 0.f;
#pragma unroll
  for (int et = 0; et < 8; ++et) {
    float4 res = *(const float4*)(xrow + et * 16 + q * 4);
    float rv[4] = {res.x, res.y, res.z, res.w};
#pragma unroll
    for (int r = 0; r < 4; ++r) {
      float v = acc[et][r] + rv[r];
      vals[et][r] = v;
      s1 += v;
      s2 += v * v;
    }
  }
  s1 += __shfl_xor(s1, 16, 64);
  s1 += __shfl_xor(s1, 32, 64);
  s2 += __shfl_xor(s2, 16, 64);
  s2 += __shfl_xor(s2, 32, 64);
  float mu = s1 * (1.0f / 128.0f);
  float rs = rsqrtf(s2 * (1.0f / 128.0f) - mu * mu + 1e-5f);

  unsigned short* brow = xe2bf + ((size_t)b * 256 + t) * 128;
#pragma unroll
  for (int et = 0; et < 8; ++et) {
    int d = et * 16 + q * 4;
    float4 g4 = *(const float4*)(g + d);
    float4 b4 = *(const float4*)(bb + d);
    float o0 = (vals[et][0] - mu) * rs * g4.x + b4.x;
    float o1 = (vals[et][1] - mu) * rs * g4.y + b4.y;
    float o2 = (vals[et][2] - mu) * rs * g4.z + b4.z;
    float o3 = (vals[et][3] - mu) * rs * g4.w + b4.w;
    float4 of = {o0, o1, o2, o3};
    *(float4*)(xrow + d) = of;
    short4v ob = {(short)f2b(o0), (short)f2b(o1), (short)f2b(o2), (short)f2b(o3)};
    *(short4v*)(brow + d) = ob;
  }
}

// ---------------- xflat transpose (+bf16 copy, + pred bias init) ----------------
__global__ __launch_bounds__(256) void k_xflat(const float* __restrict__ xe2, float* __restrict__ out,
                                               unsigned short* __restrict__ outbf,
                                               const float* __restrict__ fcb, float* __restrict__ pred) {
  int b = blockIdx.x >> 5;
  int blk = blockIdx.x & 31;
  int t0 = (blk >> 2) * 32, d0 = (blk & 3) * 32;
  __shared__ float tile[32][33];
  int tid = threadIdx.x;
  if (blockIdx.x == 0) {
    for (int i = tid; i < 1152; i += 256) pred[i] = fcb[i % 18];
  }
#pragma unroll
  for (int q = 0; q < 4; ++q) {
    int t = (tid >> 5) + q * 8, dd = tid & 31;
    tile[t][dd] = xe2[(size_t)b * 32768 + (size_t)(t0 + t) * 128 + d0 + dd];
  }
  __syncthreads();
#pragma unroll
  for (int q = 0; q < 4; ++q) {
    int dd = (tid >> 5) + q * 8, t = tid & 31;
    float v = tile[t][dd];
    size_t o = (size_t)b * 32768 + (size_t)(d0 + dd) * 256 + t0 + t;
    out[o] = v;
    outbf[o] = f2b(v);
  }
}

// ---------------- final FC via MFMA ----------------
__global__ __launch_bounds__(256) void k_fc(const unsigned short* __restrict__ xflatbf,
                                            const unsigned short* __restrict__ fwbf,
                                            float* __restrict__ pred) {
  int kb = blockIdx.x;
  int k0 = kb * 256;
  int tid = threadIdx.x;
  int wv = tid >> 6, ln = tid & 15, q = (tid >> 4) & 3;
  int b = wv * 16 + ln;
  const unsigned short* xrow = xflatbf + (size_t)b * 32768 + k0 + q * 8;
  float4v acc[2];
  acc[0] = (float4v){0.f, 0.f, 0.f, 0.f};
  acc[1] = (float4v){0.f, 0.f, 0.f, 0.f};
#pragma unroll
  for (int kc = 0; kc < 8; ++kc) {
    short8 bfrag = *(const short8*)(xrow + kc * 32);
#pragma unroll
    for (int et = 0; et < 2; ++et) {
      short8 af = *(const short8*)(fwbf + (size_t)(et * 16 + ln) * 32768 + k0 + kc * 32 + q * 8);
      acc[et] = __builtin_amdgcn_mfma_f32_16x16x32_bf16(af, bfrag, acc[et], 0, 0, 0);
    }
  }
#pragma unroll
  for (int et = 0; et < 2; ++et)
#pragma unroll
    for (int r = 0; r < 4; ++r) {
      int c = et * 16 + q * 4 + r;
      if (c < 18) atomicAdd(&pred[b * 18 + c], acc[et][r]);
    }
}

extern "C" void kernel_launch(void* const* d_in, const int* in_sizes, int n_in,
                              void* d_out, int out_size, void* d_ws, size_t ws_size,
                              hipStream_t stream) {
  (void)in_sizes; (void)n_in; (void)out_size; (void)ws_size;
  const float* inp    = (const float*)d_in[0];
  const float* emb_w  = (const float*)d_in[1];
  const float* emb_b  = (const float*)d_in[2];
  const float* dw_w   = (const float*)d_in[3];
  const float* dw_b   = (const float*)d_in[4];
  const float* pw_w   = (const float*)d_in[5];
  const float* pw_b   = (const float*)d_in[6];
  const float* se_w1  = (const float*)d_in[7];
  const float* se_b1  = (const float*)d_in[8];
  const float* se_w2  = (const float*)d_in[9];
  const float* se_b2  = (const float*)d_in[10];
  const float* in_w   = (const float*)d_in[11];
  const float* conv_w = (const float*)d_in[12];
  const float* conv_b = (const float*)d_in[13];
  const float* xp_w   = (const float*)d_in[14];
  const float* dt_w   = (const float*)d_in[15];
  const float* dt_b   = (const float*)d_in[16];
  const float* Alog   = (const float*)d_in[17];
  const float* Dp     = (const float*)d_in[18];
  const float* out_w  = (const float*)d_in[19];
  const float* ln_g   = (const float*)d_in[20];
  const float* ln_b   = (const float*)d_in[21];
  const float* fc_w   = (const float*)d_in[22];
  const float* fc_b   = (const float*)d_in[23];

  char* ws = (char*)d_ws;
  unsigned short* U0 = (unsigned short*)(ws);
  unsigned short* xz = (unsigned short*)(ws);                 // after reduce2
  unsigned short* xc = (unsigned short*)(ws + 33554432);
  unsigned short* yb = (unsigned short*)(ws + 50331648);
  float* xe2 = (float*)(ws + 100663296);
  unsigned short* xflatbf = (unsigned short*)(ws + 109051904);
  unsigned short* fwbf = (unsigned short*)(ws + 113246208);
  float* dbl = (float*)(ws + 150994944);
  unsigned short* xe2bf = (unsigned short*)(ws + 153616384);

  float* xflat = (float*)d_out;
  float* pred  = xflat + (size_t)64 * 32768;
  unsigned short* pwbf  = (unsigned short*)d_out;   // weight scratch until k_xflat
  unsigned short* inwbf = pwbf + 49152;
  unsigned short* owbf  = inwbf + 131072;
  unsigned short* xwbf  = owbf + 65536;
  unsigned short* ewbf  = xwbf + 24576;

  hipFuncSetAttribute((const void*)k_mega, hipFuncAttributeMaxDynamicSharedMemorySize, MEGA_LDS);

  k_cvt<<<5168, 256, 0, stream>>>(pw_w, in_w, out_w, xp_w, emb_w, fc_w, pwbf, fwbf);
  k_emb<<<768, 256, 0, stream>>>(inp, ewbf, emb_b, U0);

  k_mega<<<768, 512, MEGA_LDS, stream>>>(U0, dw_w, dw_b, pwbf, pw_b,
                                         se_w1, se_b1, se_w2, se_b2, U0);

  k_reduce2<<<1024, 256, 0, stream>>>(U0, xe2, xe2bf);

  for (int i = 0; i < 2; ++i) {
    k_inproj<<<512, 256, 0, stream>>>(xe2bf, inwbf + i * 65536, xz);
    k_xproj<<<256, 256, 0, stream>>>(xz, conv_w + i * 1024, conv_b + i * 256,
                                     xwbf + i * 12288, xc, dbl);
    k_scan2<<<512, 256, 0, stream>>>(dbl, xc, xz, Alog + i * 4096,
                                     dt_w + i * 2048, dt_b + i * 256, Dp + i * 256, yb);
    k_outln<<<512, 128, 0, stream>>>(yb, owbf + i * 32768, xe2, xe2bf,
                                     ln_g + i * 128, ln_b + i * 128);
  }

  k_xflat<<<2048, 256, 0, stream>>>(xe2, xflat, xflatbf, fc_b, pred);
  k_fc<<<128, 256, 0, stream>>>(xflatbf, fwbf, pred);
}

// Round 8
// 567.884 us; speedup vs baseline: 1.0924x; 1.0924x over previous
//
#include <hip/hip_runtime.h>
#include <math.h>

#define LL 2048
#define MM 12
#define DD 128
#define TP 256   // T
#define MEGA_LDS 78464

typedef short short8 __attribute__((ext_vector_type(8)));
typedef short short4v __attribute__((ext_vector_type(4)));
typedef float float4v __attribute__((ext_vector_type(4)));

static __device__ __forceinline__ unsigned short f2b(float f) {
  union { float f; unsigned int u; } x; x.f = f;
  unsigned int r = x.u + 0x7fffu + ((x.u >> 16) & 1u);
  return (unsigned short)(r >> 16);
}
static __device__ __forceinline__ float b2f(unsigned short u) {
  union { unsigned int u; float f; } x; x.u = ((unsigned int)u) << 16;
  return x.f;
}
// branch-free erf (A&S 7.1.26, |err| <= ~5e-7): rcp + exp + 5 FMA
static __device__ __forceinline__ float fast_gelu(float x) {
  float xs = x * 0.70710678118654752f;
  float y = fabsf(xs);
  float t = __builtin_amdgcn_rcpf(fmaf(0.3275911f, y, 1.0f));
  float p = fmaf(fmaf(fmaf(fmaf(1.061405429f, t, -1.453152027f), t,
                           1.421413741f), t, -0.284496736f), t, 0.254829592f);
  p = p * t;
  float e = __expf(-y * y);
  float er = fmaf(-p, e, 1.0f);
  er = copysignf(er, xs);
  return 0.5f * x * (1.0f + er);
}
static __device__ __forceinline__ float qxor1(float x) {
  int r = __builtin_amdgcn_mov_dpp(__builtin_bit_cast(int, x), 0xB1, 0xF, 0xF, true);
  return __builtin_bit_cast(float, r);
}
static __device__ __forceinline__ float qxor2(float x) {
  int r = __builtin_amdgcn_mov_dpp(__builtin_bit_cast(int, x), 0x4E, 0xF, 0xF, true);
  return __builtin_bit_cast(float, r);
}

// ---------------- convert weights to bf16 + pred bias init ----------------
// grid 5173x256: [0,274432) small weights; [274432,1323008) fc_w -> fwbf [32][32768];
// [1323008,1324160) pred init = fcb
__global__ __launch_bounds__(256) void k_cvt(const float* __restrict__ pw_w, const float* __restrict__ in_w,
                                             const float* __restrict__ out_w, const float* __restrict__ xp_w,
                                             const float* __restrict__ ew, const float* __restrict__ fw,
                                             const float* __restrict__ fcb,
                                             unsigned short* __restrict__ pwbf, unsigned short* __restrict__ fwbf,
                                             float* __restrict__ pred) {
  int i = blockIdx.x * 256 + threadIdx.x;
  if (i >= 1323008) {
    int j2 = i - 1323008;
    if (j2 < 1152) pred[j2] = fcb[j2 % 18];
    return;
  }
  if (i >= 274432) {
    int j = i - 274432;
    int m = j >> 15, k = j & 32767;
    fwbf[j] = f2b((m < 18) ? fw[m * 32768 + k] : 0.0f);
    return;
  }
  if (i < 49152) { pwbf[i] = f2b(pw_w[i]); return; }
  int i2 = i - 49152;
  if (i2 < 131072) { pwbf[i] = f2b(in_w[i2]); return; }
  int i3 = i2 - 131072;
  if (i3 < 65536) { pwbf[i] = f2b(out_w[i3]); return; }
  int i4 = i3 - 65536;
  if (i4 < 24576) {
    int layer = (i4 < 12288) ? 0 : 1;
    int rem = i4 - layer * 12288;
    int k = rem >> 8, c = rem & 255;
    float v = (k < 40) ? xp_w[layer * 10240 + k * 256 + c] : 0.0f;
    pwbf[i] = f2b(v);
    return;
  }
  int i5 = i4 - 24576;
  if (i5 < 4096) {
    int d = i5 >> 5, k = i5 & 31;
    float v = (k < 16) ? ew[d * 16 + k] : 0.0f;
    pwbf[i] = f2b(v);
  }
}

// ---------------- embedding via MFMA ----------------
__global__ __launch_bounds__(256) void k_emb(const float* __restrict__ inp,
                                             const unsigned short* __restrict__ ewbf,
                                             const float* __restrict__ eb,
                                             unsigned short* __restrict__ xe) {
  int sig = blockIdx.x;
  int b = sig / MM, m = sig % MM;
  __shared__ float xs[LL];
  const float* ib = inp + (size_t)b * LL * MM + m;
  int tid = threadIdx.x;
  for (int i = tid; i < LL; i += 256) xs[i] = ib[(size_t)i * MM];
  __syncthreads();
  int wv = tid >> 6, ln = tid & 15, q = (tid >> 4) & 3;
  short8 af[8];
#pragma unroll
  for (int et = 0; et < 8; ++et)
    af[et] = *(const short8*)(ewbf + (et * 16 + ln) * 32 + q * 8);
#pragma unroll
  for (int pass = 0; pass < 4; ++pass) {
    int t = pass * 64 + wv * 16 + ln;
    int l0 = t * 8 - 4;
    short8 bfrag;
#pragma unroll
    for (int j = 0; j < 8; ++j) {
      int k = q * 8 + j;
      int l = l0 + k;
      float v = (k < 16 && l >= 0 && l < LL) ? xs[l] : 0.0f;
      bfrag[j] = (short)f2b(v);
    }
    float4v acc[8];
#pragma unroll
    for (int et = 0; et < 8; ++et) {
      acc[et] = (float4v){0.f, 0.f, 0.f, 0.f};
      acc[et] = __builtin_amdgcn_mfma_f32_16x16x32_bf16(af[et], bfrag, acc[et], 0, 0, 0);
    }
    unsigned short* orow = xe + (size_t)sig * 32768 + (size_t)t * 128;
#pragma unroll
    for (int et = 0; et < 8; ++et) {
      int e = et * 16 + q * 4;
      float4 pb = *(const float4*)&eb[e];
      short4v st = {(short)f2b(acc[et][0] + pb.x), (short)f2b(acc[et][1] + pb.y),
                    (short)f2b(acc[et][2] + pb.z), (short)f2b(acc[et][3] + pb.w)};
      *(short4v*)(orow + e) = st;
    }
  }
}

// ---------------- MEGA block stage: all 3 layers + SE, signal resident in LDS ----------------
// grid 768 x 512 threads; dynamic LDS 78464 B (round-6 verified 170us structure)
__global__ __launch_bounds__(512) void k_mega(const unsigned short* __restrict__ u0,
                                              const float* __restrict__ dww, const float* __restrict__ dwb,
                                              const unsigned short* __restrict__ pwbf,
                                              const float* __restrict__ pwb,
                                              const float* __restrict__ w1, const float* __restrict__ b1,
                                              const float* __restrict__ w2, const float* __restrict__ b2,
                                              unsigned short* __restrict__ uout) {
  extern __shared__ char smemraw[];
  unsigned short* us = (unsigned short*)smemraw;
  float* dwT  = (float*)(smemraw + 69632);
  float* dwbL = dwT + 640;
  float* pwbL = dwbL + 128;
  float* sred = pwbL + 128;
  float* smv  = sred + 1024;
  float* hh   = smv + 128;
  float* aL   = hh + 32;

  int sig = blockIdx.x;
  int tid = threadIdx.x;
  const size_t gbase = (size_t)sig * 32768;
  int cu = tid & 15;
  int r0 = tid >> 4;   // 0..31

#pragma unroll
  for (int p = 0; p < 8; ++p) {
    int t = p * 32 + r0;
    short8 v = *(const short8*)(u0 + gbase + (size_t)t * 128 + cu * 8);
    *(short8*)(us + t * 136 + cu * 8) = v;
  }

  int wv = tid >> 6;
  int ln = tid & 15;
  int q  = (tid >> 4) & 3;
  int tb = wv * 32;

  for (int layer = 0; layer < 3; ++layer) {
    __syncthreads();
    for (int i = tid; i < 640; i += 512) dwT[(i % 5) * 128 + (i / 5)] = dww[layer * 640 + i];
    if (tid < 128) { dwbL[tid] = dwb[layer * 128 + tid]; pwbL[tid] = pwb[layer * 128 + tid]; }
    __syncthreads();

    const unsigned short* pwL = pwbf + layer * 16384;
    float4v acc[2][8];
#pragma unroll
    for (int tl = 0; tl < 2; ++tl)
#pragma unroll
      for (int et = 0; et < 8; ++et) acc[tl][et] = (float4v){0.f, 0.f, 0.f, 0.f};

#pragma unroll
    for (int kc = 0; kc < 4; ++kc) {
      int dc = kc * 32 + q * 8;
      short8 af[8];
#pragma unroll
      for (int et = 0; et < 8; ++et)
        af[et] = *(const short8*)(pwL + (size_t)(et * 16 + ln) * 128 + dc);
      float wt[5][8], bl8[8];
#pragma unroll
      for (int k = 0; k < 5; ++k) {
        float4 wa = *(const float4*)&dwT[k * 128 + dc];
        float4 wb = *(const float4*)&dwT[k * 128 + dc + 4];
        wt[k][0] = wa.x; wt[k][1] = wa.y; wt[k][2] = wa.z; wt[k][3] = wa.w;
        wt[k][4] = wb.x; wt[k][5] = wb.y; wt[k][6] = wb.z; wt[k][7] = wb.w;
      }
      {
        float4 ba = *(const float4*)&dwbL[dc];
        float4 bb2 = *(const float4*)&dwbL[dc + 4];
        bl8[0] = ba.x; bl8[1] = ba.y; bl8[2] = ba.z; bl8[3] = ba.w;
        bl8[4] = bb2.x; bl8[5] = bb2.y; bl8[6] = bb2.z; bl8[7] = bb2.w;
      }
#pragma unroll
      for (int tl = 0; tl < 2; ++tl) {
        int t = tb + tl * 16 + ln;
        float a8[8];
#pragma unroll
        for (int j = 0; j < 8; ++j) a8[j] = bl8[j];
#pragma unroll
        for (int k = 0; k < 5; ++k) {
          int tt = t - 2 + k;
          if (tt >= 0 && tt < 256) {
            short8 u8 = *(const short8*)(us + tt * 136 + dc);
#pragma unroll
            for (int j = 0; j < 8; ++j) a8[j] += b2f((unsigned short)u8[j]) * wt[k][j];
          }
        }
        short8 bf;
#pragma unroll
        for (int j = 0; j < 8; ++j)
          bf[j] = (short)f2b(fast_gelu(a8[j]));
#pragma unroll
        for (int et = 0; et < 8; ++et)
          acc[tl][et] = __builtin_amdgcn_mfma_f32_16x16x32_bf16(af[et], bf, acc[tl][et], 0, 0, 0);
      }
    }
    __syncthreads();   // all us reads done; sred free

    // SE t-partial sums -> sred
#pragma unroll
    for (int et = 0; et < 8; ++et) {
      int e = et * 16 + q * 4;
      float4 pb = *(const float4*)&pwbL[e];
      float sv0 = acc[0][et][0] + acc[1][et][0] + 2.0f * pb.x;
      float sv1 = acc[0][et][1] + acc[1][et][1] + 2.0f * pb.y;
      float sv2 = acc[0][et][2] + acc[1][et][2] + 2.0f * pb.z;
      float sv3 = acc[0][et][3] + acc[1][et][3] + 2.0f * pb.w;
#pragma unroll
      for (int m = 1; m <= 8; m <<= 1) {
        sv0 += __shfl_xor(sv0, m, 64);
        sv1 += __shfl_xor(sv1, m, 64);
        sv2 += __shfl_xor(sv2, m, 64);
        sv3 += __shfl_xor(sv3, m, 64);
      }
      if (ln == 0) {
        float4 sv = {sv0, sv1, sv2, sv3};
        *(float4*)&sred[wv * 128 + e] = sv;
      }
    }
    __syncthreads();
    if (tid < 128) {
      float s = 0.f;
#pragma unroll
      for (int w = 0; w < 8; ++w) s += sred[w * 128 + tid];
      smv[tid] = s * (1.0f / 256.0f);
    }
    __syncthreads();
    // SE hidden layer: 256 threads, 8 lanes per output, shuffle-reduce
    if (tid < 256) {
      int o = tid >> 3, part = tid & 7;
      const float* wr = w1 + layer * 4096 + o * 128 + part * 16;
      const float* sv = smv + part * 16;
      float s = 0.f;
#pragma unroll
      for (int j = 0; j < 16; j += 4) {
        float4 w4 = *(const float4*)(wr + j);
        float4 v4 = *(const float4*)(sv + j);
        s += w4.x * v4.x + w4.y * v4.y + w4.z * v4.z + w4.w * v4.w;
      }
      s += __shfl_xor(s, 1, 64);
      s += __shfl_xor(s, 2, 64);
      s += __shfl_xor(s, 4, 64);
      if (part == 0) hh[o] = fmaxf(s + b1[layer * 32 + o], 0.0f);
    }
    __syncthreads();
    // SE gate: all 512 threads, 4 lanes per output
    {
      int o = tid >> 2, part = tid & 3;
      const float* wr = w2 + layer * 4096 + o * 32 + part * 8;
      float s = 0.f;
#pragma unroll
      for (int j = 0; j < 8; j += 4) {
        float4 w4 = *(const float4*)(wr + j);
        float4 h4 = *(const float4*)(hh + part * 8 + j);
        s += w4.x * h4.x + w4.y * h4.y + w4.z * h4.z + w4.w * h4.w;
      }
      s += __shfl_xor(s, 1, 64);
      s += __shfl_xor(s, 2, 64);
      if (part == 0) aL[o] = 1.0f / (1.0f + __expf(-(s + b2[layer * 128 + o])));
    }
    __syncthreads();

    // u += w * a  (in LDS, disjoint per lane)
#pragma unroll
    for (int tl = 0; tl < 2; ++tl) {
      int t = tb + tl * 16 + ln;
#pragma unroll
      for (int et = 0; et < 8; ++et) {
        int e = et * 16 + q * 4;
        float4 pb = *(const float4*)&pwbL[e];
        float4 ga = *(const float4*)&aL[e];
        short4v u4 = *(short4v*)(us + t * 136 + e);
        short4v r;
        r[0] = (short)f2b(b2f((unsigned short)u4[0]) + (acc[tl][et][0] + pb.x) * ga.x);
        r[1] = (short)f2b(b2f((unsigned short)u4[1]) + (acc[tl][et][1] + pb.y) * ga.y);
        r[2] = (short)f2b(b2f((unsigned short)u4[2]) + (acc[tl][et][2] + pb.z) * ga.z);
        r[3] = (short)f2b(b2f((unsigned short)u4[3]) + (acc[tl][et][3] + pb.w) * ga.w);
        *(short4v*)(us + t * 136 + e) = r;
      }
    }
  }
  __syncthreads();
#pragma unroll
  for (int p = 0; p < 8; ++p) {
    int t = p * 32 + r0;
    short8 v = *(short8*)(us + t * 136 + cu * 8);
    *(short8*)(uout + gbase + (size_t)t * 128 + cu * 8) = v;
  }
}

// ---------------- mean over M -> xe2 fp32 + xe2bf bf16 ----------------
__global__ __launch_bounds__(256) void k_reduce2(const unsigned short* __restrict__ u,
                                                 float* __restrict__ xe2,
                                                 unsigned short* __restrict__ xe2bf) {
  int i = blockIdx.x * 256 + threadIdx.x;
  int d0 = (i & 15) * 8;
  int t = (i >> 4) & 255;
  int b = i >> 12;
  float acc[8] = {0.f, 0.f, 0.f, 0.f, 0.f, 0.f, 0.f, 0.f};
#pragma unroll 4
  for (int m = 0; m < 12; ++m) {
    size_t base = ((size_t)(b * 12 + m) * 256 + t) * 128 + d0;
    short8 u8 = *(const short8*)(u + base);
#pragma unroll
    for (int j = 0; j < 8; ++j) acc[j] += b2f((unsigned short)u8[j]);
  }
  size_t off = (size_t)b * 32768 + (size_t)t * 128 + d0;
  float4 o0 = {acc[0] / 12.f, acc[1] / 12.f, acc[2] / 12.f, acc[3] / 12.f};
  float4 o1 = {acc[4] / 12.f, acc[5] / 12.f, acc[6] / 12.f, acc[7] / 12.f};
  *(float4*)(xe2 + off) = o0;
  *(float4*)(xe2 + off + 4) = o1;
  short8 ob;
#pragma unroll
  for (int j = 0; j < 8; ++j) ob[j] = (short)f2b(acc[j] / 12.f);
  *(short8*)(xe2bf + off) = ob;
}

// ---------------- mamba: in-projection via MFMA, zero-LDS -> bf16 xz[t][e] ----------------
__global__ __launch_bounds__(256) void k_inproj(const unsigned short* __restrict__ xe2bf,
                                                const unsigned short* __restrict__ inwbf,
                                                unsigned short* __restrict__ xz) {
  int blk = blockIdx.x;
  int b = blk >> 3;
  int tt = (blk >> 1) & 3;
  int eh = blk & 1;
  int t0 = tt * 64, e0 = eh * 256;
  int tid = threadIdx.x;
  int wv = tid >> 6, ln = tid & 15, q = (tid >> 4) & 3;
  int t = t0 + wv * 16 + ln;
  const unsigned short* xrow = xe2bf + ((size_t)b * 256 + t) * 128 + q * 8;
  short8 bfrag[4];
#pragma unroll
  for (int kc = 0; kc < 4; ++kc) bfrag[kc] = *(const short8*)(xrow + kc * 32);
  float4v acc[16];
#pragma unroll
  for (int et = 0; et < 16; ++et) acc[et] = (float4v){0.f, 0.f, 0.f, 0.f};
#pragma unroll
  for (int et = 0; et < 16; ++et) {
    const unsigned short* arow = inwbf + (size_t)(e0 + et * 16 + ln) * 128 + q * 8;
#pragma unroll
    for (int kc = 0; kc < 4; ++kc) {
      short8 af = *(const short8*)(arow + kc * 32);
      acc[et] = __builtin_amdgcn_mfma_f32_16x16x32_bf16(af, bfrag[kc], acc[et], 0, 0, 0);
    }
  }
  unsigned short* orow = xz + ((size_t)b * 256 + t) * 512 + e0 + q * 4;
#pragma unroll
  for (int et = 0; et < 16; ++et) {
    short4v st = {(short)f2b(acc[et][0]), (short)f2b(acc[et][1]),
                  (short)f2b(acc[et][2]), (short)f2b(acc[et][3])};
    *(short4v*)(orow + et * 16) = st;
  }
}

// ---------------- mamba: fused causal conv+SiLU -> x-projection MFMA; writes xc + dbl ----------------
__global__ __launch_bounds__(256) void k_xproj(const unsigned short* __restrict__ xz,
                                               const float* __restrict__ cw, const float* __restrict__ cb,
                                               const unsigned short* __restrict__ xwbf,
                                               unsigned short* __restrict__ xcg,
                                               float* __restrict__ dbl) {
  __shared__ unsigned short xis[67 * 264];
  int blk = blockIdx.x;
  int b = blk >> 2;
  int tq = blk & 3;
  int t0 = tq * 64;
  int tid = threadIdx.x;

  const short8 ZV = {0, 0, 0, 0, 0, 0, 0, 0};
  for (int idx = tid; idx < 2144; idx += 256) {
    int row = idx >> 5, cu = idx & 31;
    int t = t0 - 3 + row;
    short8 v = ZV;
    if (t >= 0) v = *(const short8*)(xz + ((size_t)b * 256 + t) * 512 + cu * 8);
    *(short8*)(xis + row * 264 + cu * 8) = v;
  }
  __syncthreads();

  int cu = tid & 31;
  int rb = tid >> 5;
  int c8 = cu * 8;
  float wl[4][8], bl[8];
#pragma unroll
  for (int j = 0; j < 8; ++j) {
    float4 w4 = *(const float4*)&cw[(c8 + j) * 4];
    wl[0][j] = w4.x; wl[1][j] = w4.y; wl[2][j] = w4.z; wl[3][j] = w4.w;
    bl[j] = cb[c8 + j];
  }

  short8 vv[4];
#pragma unroll
  for (int s = 0; s < 4; ++s) {
    int r = rb + s * 8;
    float acc[8];
#pragma unroll
    for (int j = 0; j < 8; ++j) acc[j] = bl[j];
#pragma unroll
    for (int k = 0; k < 4; ++k) {
      short8 u8 = *(const short8*)(xis + (r + k) * 264 + c8);
#pragma unroll
      for (int j = 0; j < 8; ++j) acc[j] += b2f((unsigned short)u8[j]) * wl[k][j];
    }
#pragma unroll
    for (int j = 0; j < 8; ++j)
      vv[s][j] = (short)f2b(acc[j] / (1.0f + __expf(-acc[j])));
    *(short8*)(xcg + ((size_t)b * 256 + t0 + r) * 256 + c8) = vv[s];
  }
  __syncthreads();
#pragma unroll
  for (int s = 0; s < 4; ++s)
    *(short8*)(xis + (rb + s * 8) * 264 + c8) = vv[s];

#pragma unroll
  for (int s = 0; s < 4; ++s) {
    int r = 32 + rb + s * 8;
    float acc[8];
#pragma unroll
    for (int j = 0; j < 8; ++j) acc[j] = bl[j];
#pragma unroll
    for (int k = 0; k < 4; ++k) {
      short8 u8 = *(const short8*)(xis + (r + k) * 264 + c8);
#pragma unroll
      for (int j = 0; j < 8; ++j) acc[j] += b2f((unsigned short)u8[j]) * wl[k][j];
    }
#pragma unroll
    for (int j = 0; j < 8; ++j)
      vv[s][j] = (short)f2b(acc[j] / (1.0f + __expf(-acc[j])));
    *(short8*)(xcg + ((size_t)b * 256 + t0 + r) * 256 + c8) = vv[s];
  }
  __syncthreads();
#pragma unroll
  for (int s = 0; s < 4; ++s)
    *(short8*)(xis + (32 + rb + s * 8) * 264 + c8) = vv[s];
  __syncthreads();

  int wv = tid >> 6, ln = tid & 15, q = (tid >> 4) & 3;
  int tl = wv * 16 + ln;
  short8 bfrag[8];
#pragma unroll
  for (int kc = 0; kc < 8; ++kc)
    bfrag[kc] = *(const short8*)(xis + tl * 264 + kc * 32 + q * 8);
  float4v acc[3];
#pragma unroll
  for (int et = 0; et < 3; ++et) acc[et] = (float4v){0.f, 0.f, 0.f, 0.f};
#pragma unroll
  for (int et = 0; et < 3; ++et) {
    const unsigned short* arow = xwbf + (size_t)(et * 16 + ln) * 256 + q * 8;
#pragma unroll
    for (int kc = 0; kc < 8; ++kc) {
      short8 af = *(const short8*)(arow + kc * 32);
      acc[et] = __builtin_amdgcn_mfma_f32_16x16x32_bf16(af, bfrag[kc], acc[et], 0, 0, 0);
    }
  }
  float* drow = dbl + ((size_t)b * 256 + t0 + tl) * 40;
#pragma unroll
  for (int et = 0; et < 3; ++et)
#pragma unroll
    for (int r = 0; r < 4; ++r) {
      int k = et * 16 + q * 4 + r;
      if (k < 40) drow[k] = acc[et][r];
    }
}

// ---------------- mamba: fused dt + selective scan + y-finalize ----------------
// 256 threads: parallel phases stride 256; serial scan keeps 128-thread mapping
__global__ __launch_bounds__(256) void k_scan2(const float* __restrict__ dbl,
                                               const unsigned short* __restrict__ xc,
                                               const unsigned short* __restrict__ xz,
                                               const float* __restrict__ Alog,
                                               const float* __restrict__ dtw, const float* __restrict__ dtbv,
                                               const float* __restrict__ Dp, unsigned short* __restrict__ y) {
  __shared__ float ds[32][40];
  __shared__ float dxs[32][32][4];
  __shared__ float yl[32][32];
  __shared__ float dtwL[32][8];
  __shared__ float dtbL[32];
  __shared__ float DpL[32];

  int b = blockIdx.x >> 3;
  int c0 = (blockIdx.x & 7) * 32;
  int tid = threadIdx.x;

  for (int idx = tid; idx < 256; idx += 256) dtwL[idx >> 3][idx & 7] = dtw[(c0 + (idx >> 3)) * 8 + (idx & 7)];
  if (tid < 32) { dtbL[tid] = dtbv[c0 + tid]; DpL[tid] = Dp[c0 + tid]; }

  int lane = tid & 63;
  int wv = tid >> 6;
  int c_loc = (wv & 1) * 16 + (lane >> 2);   // masked so tid>=128 stays in-bounds
  int c = c0 + c_loc;
  int sblk = (lane & 3) * 4;

  float4 Al = *(const float4*)&Alog[c * 16 + sblk];
  float A[4] = {-__expf(Al.x), -__expf(Al.y), -__expf(Al.z), -__expf(Al.w)};
  float h[4] = {0.f, 0.f, 0.f, 0.f};

  const float* dbp = dbl + (size_t)b * 10240;
  const unsigned short* xcp = xc + (size_t)b * 65536;
  const unsigned short* xzp = xz + (size_t)b * 131072;
  unsigned short* yp = y + (size_t)b * 65536;

  for (int chk = 0; chk < 8; ++chk) {
    int t0c = chk * 32;
    for (int idx = tid; idx < 1280; idx += 256) ((float*)ds)[idx] = dbp[t0c * 40 + idx];
    for (int idx = tid; idx < 512; idx += 256) {
      int t = idx >> 4, cc2 = (idx & 15) * 2;
      ushort2 xv = *(const ushort2*)&xcp[(size_t)(t0c + t) * 256 + c0 + cc2];
      ushort2 zv = *(const ushort2*)&xzp[(size_t)(t0c + t) * 512 + 256 + c0 + cc2];
      dxs[t][cc2][1] = b2f(xv.x);
      dxs[t][cc2 + 1][1] = b2f(xv.y);
      dxs[t][cc2][2] = b2f(zv.x);
      dxs[t][cc2 + 1][2] = b2f(zv.y);
    }
    __syncthreads();
    for (int idx = tid; idx < 1024; idx += 256) {
      int t = idx >> 5, cc = idx & 31;
      const float* dr = ds[t];
      const float* wr = dtwL[cc];
      float acc = dtbL[cc];
#pragma unroll
      for (int j = 0; j < 8; ++j) acc += wr[j] * dr[j];
      dxs[t][cc][0] = (acc > 20.0f) ? acc : __logf(1.0f + __expf(acc));
    }
    __syncthreads();
    if (tid < 128) {
#pragma unroll 4
      for (int t = 0; t < 32; ++t) {
        float4 dx = *(const float4*)&dxs[t][c_loc][0];
        float4 Bv = *(const float4*)&ds[t][8 + sblk];
        float4 Cv = *(const float4*)&ds[t][24 + sblk];
        float dtv = dx.x;
        float bx = dtv * dx.y;
        h[0] = __expf(dtv * A[0]) * h[0] + Bv.x * bx;
        h[1] = __expf(dtv * A[1]) * h[1] + Bv.y * bx;
        h[2] = __expf(dtv * A[2]) * h[2] + Bv.z * bx;
        h[3] = __expf(dtv * A[3]) * h[3] + Bv.w * bx;
        float p = h[0] * Cv.x;
        p = fmaf(h[1], Cv.y, p);
        p = fmaf(h[2], Cv.z, p);
        p = fmaf(h[3], Cv.w, p);
        p += qxor1(p);
        p += qxor2(p);
        if ((lane & 3) == 0) yl[t][c_loc] = p;
      }
    }
    __syncthreads();
    for (int idx = tid; idx < 512; idx += 256) {
      int t = idx >> 4, cc2 = (idx & 15) * 2;
      float p0 = yl[t][cc2], p1 = yl[t][cc2 + 1];
      float x0 = dxs[t][cc2][1], x1 = dxs[t][cc2 + 1][1];
      float z0 = dxs[t][cc2][2], z1 = dxs[t][cc2 + 1][2];
      float s0 = z0 / (1.0f + __expf(-z0));
      float s1 = z1 / (1.0f + __expf(-z1));
      ushort2 o = {f2b((p0 + DpL[cc2] * x0) * s0), f2b((p1 + DpL[cc2 + 1] * x1) * s1)};
      *(ushort2*)&yp[(size_t)(t0c + t) * 256 + c0 + cc2] = o;
    }
    __syncthreads();
  }
}

// ---------------- mamba: MFMA out-projection + residual + LayerNorm, zero-LDS ----------------
__global__ __launch_bounds__(128) void k_outln(const unsigned short* __restrict__ yb,
                                               const unsigned short* __restrict__ owbf,
                                               float* __restrict__ xe2, unsigned short* __restrict__ xe2bf,
                                               const float* __restrict__ g, const float* __restrict__ bb) {
  int blk = blockIdx.x;
  int b = blk >> 3;
  int t0 = (blk & 7) * 32;
  int tid = threadIdx.x;
  int wv = tid >> 6, ln = tid & 15, q = (tid >> 4) & 3;
  int t = t0 + wv * 16 + ln;

  const unsigned short* yrow = yb + ((size_t)b * 256 + t) * 256 + q * 8;
  short8 bfrag[8];
#pragma unroll
  for (int kc = 0; kc < 8; ++kc) bfrag[kc] = *(const short8*)(yrow + kc * 32);

  float4v acc[8];
#pragma unroll
  for (int et = 0; et < 8; ++et) acc[et] = (float4v){0.f, 0.f, 0.f, 0.f};
#pragma unroll
  for (int et = 0; et < 8; ++et) {
    const unsigned short* arow = owbf + (size_t)(et * 16 + ln) * 256 + q * 8;
#pragma unroll
    for (int kc = 0; kc < 8; ++kc) {
      short8 af = *(const short8*)(arow + kc * 32);
      acc[et] = __builtin_amdgcn_mfma_f32_16x16x32_bf16(af, bfrag[kc], acc[et], 0, 0, 0);
    }
  }

  float* xrow = xe2 + ((size_t)b * 256 + t) * 128;
  float vals[8][4];
  float s1 = 0.f, s2 = 0.f;
#pragma unroll
  for (int et = 0; et < 8; ++et) {
    float4 res = *(const float4*)(xrow + et * 16 + q * 4);
    float rv[4] = {res.x, res.y, res.z, res.w};
#pragma unroll
    for (int r = 0; r < 4; ++r) {
      float v = acc[et][r] + rv[r];
      vals[et][r] = v;
      s1 += v;
      s2 += v * v;
    }
  }
  s1 += __shfl_xor(s1, 16, 64);
  s1 += __shfl_xor(s1, 32, 64);
  s2 += __shfl_xor(s2, 16, 64);
  s2 += __shfl_xor(s2, 32, 64);
  float mu = s1 * (1.0f / 128.0f);
  float rs = rsqrtf(s2 * (1.0f / 128.0f) - mu * mu + 1e-5f);

  unsigned short* brow = xe2bf + ((size_t)b * 256 + t) * 128;
#pragma unroll
  for (int et = 0; et < 8; ++et) {
    int d = et * 16 + q * 4;
    float4 g4 = *(const float4*)(g + d);
    float4 b4 = *(const float4*)(bb + d);
    float o0 = (vals[et][0] - mu) * rs * g4.x + b4.x;
    float o1 = (vals[et][1] - mu) * rs * g4.y + b4.y;
    float o2 = (vals[et][2] - mu) * rs * g4.z + b4.z;
    float o3 = (vals[et][3] - mu) * rs * g4.w + b4.w;
    float4 of = {o0, o1, o2, o3};
    *(float4*)(xrow + d) = of;
    short4v ob = {(short)f2b(o0), (short)f2b(o1), (short)f2b(o2), (short)f2b(o3)};
    *(short4v*)(brow + d) = ob;
  }
}

// ---------------- xflat transpose + fused partial FC (replaces k_fc) ----------------
// block: (b, 32t x 32d tile). Writes xflat f32; accumulates pred[b][c] via
// wave-reduce + atomicAdd. pred pre-initialized with bias in k_cvt.
__global__ __launch_bounds__(256) void k_xflat(const float* __restrict__ xe2, float* __restrict__ out,
                                               const unsigned short* __restrict__ fwbf,
                                               float* __restrict__ pred) {
  int b = blockIdx.x >> 5;
  int blk = blockIdx.x & 31;
  int t0 = (blk >> 2) * 32, d0 = (blk & 3) * 32;
  __shared__ float tile[32][33];
  int tid = threadIdx.x;
#pragma unroll
  for (int q = 0; q < 4; ++q) {
    int t = (tid >> 5) + q * 8, dd = tid & 31;
    tile[t][dd] = xe2[(size_t)b * 32768 + (size_t)(t0 + t) * 128 + d0 + dd];
  }
  __syncthreads();
  float v4[4];
  int dd_r = tid >> 5;          // 0..7 base
  int t_r = tid & 31;
#pragma unroll
  for (int q = 0; q < 4; ++q) {
    int dd = dd_r + q * 8;
    float v = tile[t_r][dd];
    v4[q] = v;
    size_t o = (size_t)b * 32768 + (size_t)(d0 + dd) * 256 + t0 + t_r;
    out[o] = v;
  }
  // partial FC over this block's k-slice: k = (d0+dd)*256 + t0+t
#pragma unroll
  for (int c = 0; c < 18; ++c) {
    float s = 0.f;
#pragma unroll
    for (int q = 0; q < 4; ++q) {
      int dd = dd_r + q * 8;
      unsigned short w = fwbf[(size_t)c * 32768 + (size_t)(d0 + dd) * 256 + t0 + t_r];
      s += v4[q] * b2f(w);
    }
    s += __shfl_xor(s, 1, 64);
    s += __shfl_xor(s, 2, 64);
    s += __shfl_xor(s, 4, 64);
    s += __shfl_xor(s, 8, 64);
    s += __shfl_xor(s, 16, 64);
    s += __shfl_xor(s, 32, 64);
    if ((tid & 63) == 0) atomicAdd(&pred[b * 18 + c], s);
  }
}

extern "C" void kernel_launch(void* const* d_in, const int* in_sizes, int n_in,
                              void* d_out, int out_size, void* d_ws, size_t ws_size,
                              hipStream_t stream) {
  (void)in_sizes; (void)n_in; (void)out_size; (void)ws_size;
  const float* inp    = (const float*)d_in[0];
  const float* emb_w  = (const float*)d_in[1];
  const float* emb_b  = (const float*)d_in[2];
  const float* dw_w   = (const float*)d_in[3];
  const float* dw_b   = (const float*)d_in[4];
  const float* pw_w   = (const float*)d_in[5];
  const float* pw_b   = (const float*)d_in[6];
  const float* se_w1  = (const float*)d_in[7];
  const float* se_b1  = (const float*)d_in[8];
  const float* se_w2  = (const float*)d_in[9];
  const float* se_b2  = (const float*)d_in[10];
  const float* in_w   = (const float*)d_in[11];
  const float* conv_w = (const float*)d_in[12];
  const float* conv_b = (const float*)d_in[13];
  const float* xp_w   = (const float*)d_in[14];
  const float* dt_w   = (const float*)d_in[15];
  const float* dt_b   = (const float*)d_in[16];
  const float* Alog   = (const float*)d_in[17];
  const float* Dp     = (const float*)d_in[18];
  const float* out_w  = (const float*)d_in[19];
  const float* ln_g   = (const float*)d_in[20];
  const float* ln_b   = (const float*)d_in[21];
  const float* fc_w   = (const float*)d_in[22];
  const float* fc_b   = (const float*)d_in[23];

  char* ws = (char*)d_ws;
  unsigned short* U0 = (unsigned short*)(ws);
  unsigned short* xz = (unsigned short*)(ws);                 // after reduce2
  unsigned short* xc = (unsigned short*)(ws + 33554432);
  unsigned short* yb = (unsigned short*)(ws + 50331648);
  float* xe2 = (float*)(ws + 100663296);
  unsigned short* fwbf = (unsigned short*)(ws + 113246208);
  float* dbl = (float*)(ws + 150994944);
  unsigned short* xe2bf = (unsigned short*)(ws + 153616384);

  float* xflat = (float*)d_out;
  float* pred  = xflat + (size_t)64 * 32768;
  unsigned short* pwbf  = (unsigned short*)d_out;   // weight scratch until k_xflat
  unsigned short* inwbf = pwbf + 49152;
  unsigned short* owbf  = inwbf + 131072;
  unsigned short* xwbf  = owbf + 65536;
  unsigned short* ewbf  = xwbf + 24576;

  hipFuncSetAttribute((const void*)k_mega, hipFuncAttributeMaxDynamicSharedMemorySize, MEGA_LDS);

  k_cvt<<<5173, 256, 0, stream>>>(pw_w, in_w, out_w, xp_w, emb_w, fc_w, fc_b, pwbf, fwbf, pred);
  k_emb<<<768, 256, 0, stream>>>(inp, ewbf, emb_b, U0);

  k_mega<<<768, 512, MEGA_LDS, stream>>>(U0, dw_w, dw_b, pwbf, pw_b,
                                         se_w1, se_b1, se_w2, se_b2, U0);

  k_reduce2<<<1024, 256, 0, stream>>>(U0, xe2, xe2bf);

  for (int i = 0; i < 2; ++i) {
    k_inproj<<<512, 256, 0, stream>>>(xe2bf, inwbf + i * 65536, xz);
    k_xproj<<<256, 256, 0, stream>>>(xz, conv_w + i * 1024, conv_b + i * 256,
                                     xwbf + i * 12288, xc, dbl);
    k_scan2<<<512, 256, 0, stream>>>(dbl, xc, xz, Alog + i * 4096,
                                     dt_w + i * 2048, dt_b + i * 256, Dp + i * 256, yb);
    k_outln<<<512, 128, 0, stream>>>(yb, owbf + i * 32768, xe2, xe2bf,
                                     ln_g + i * 128, ln_b + i * 128);
  }

  k_xflat<<<2048, 256, 0, stream>>>(xe2, xflat, fwbf, pred);
}

// Round 9
// 546.495 us; speedup vs baseline: 1.1352x; 1.0391x over previous
//
#include <hip/hip_runtime.h>
#include <math.h>

#define LL 2048
#define MM 12
#define DD 128
#define TP 256   // T
#define MEGA_LDS 78464

typedef short short8 __attribute__((ext_vector_type(8)));
typedef short short4v __attribute__((ext_vector_type(4)));
typedef float float4v __attribute__((ext_vector_type(4)));

static __device__ __forceinline__ unsigned short f2b(float f) {
  union { float f; unsigned int u; } x; x.f = f;
  unsigned int r = x.u + 0x7fffu + ((x.u >> 16) & 1u);
  return (unsigned short)(r >> 16);
}
static __device__ __forceinline__ float b2f(unsigned short u) {
  union { unsigned int u; float f; } x; x.u = ((unsigned int)u) << 16;
  return x.f;
}
// branch-free erf (A&S 7.1.26, |err| <= ~5e-7): rcp + exp + 5 FMA
static __device__ __forceinline__ float fast_gelu(float x) {
  float xs = x * 0.70710678118654752f;
  float y = fabsf(xs);
  float t = __builtin_amdgcn_rcpf(fmaf(0.3275911f, y, 1.0f));
  float p = fmaf(fmaf(fmaf(fmaf(1.061405429f, t, -1.453152027f), t,
                           1.421413741f), t, -0.284496736f), t, 0.254829592f);
  p = p * t;
  float e = __expf(-y * y);
  float er = fmaf(-p, e, 1.0f);
  er = copysignf(er, xs);
  return 0.5f * x * (1.0f + er);
}
static __device__ __forceinline__ float qxor1(float x) {
  int r = __builtin_amdgcn_mov_dpp(__builtin_bit_cast(int, x), 0xB1, 0xF, 0xF, true);
  return __builtin_bit_cast(float, r);
}
static __device__ __forceinline__ float qxor2(float x) {
  int r = __builtin_amdgcn_mov_dpp(__builtin_bit_cast(int, x), 0x4E, 0xF, 0xF, true);
  return __builtin_bit_cast(float, r);
}

// ---------------- convert weights to bf16 (pw, in_w, out_w, padded xp_w, padded ew, padded fc_w) ----------------
// grid 5168x256: first 274432 ids = small weights; remaining 1048576 = fc_w -> fwbf [32][32768]
__global__ __launch_bounds__(256) void k_cvt(const float* __restrict__ pw_w, const float* __restrict__ in_w,
                                             const float* __restrict__ out_w, const float* __restrict__ xp_w,
                                             const float* __restrict__ ew, const float* __restrict__ fw,
                                             unsigned short* __restrict__ pwbf, unsigned short* __restrict__ fwbf) {
  int i = blockIdx.x * 256 + threadIdx.x;
  if (i >= 274432) {
    int j = i - 274432;
    int m = j >> 15, k = j & 32767;
    fwbf[j] = f2b((m < 18) ? fw[m * 32768 + k] : 0.0f);
    return;
  }
  if (i < 49152) { pwbf[i] = f2b(pw_w[i]); return; }
  int i2 = i - 49152;
  if (i2 < 131072) { pwbf[i] = f2b(in_w[i2]); return; }
  int i3 = i2 - 131072;
  if (i3 < 65536) { pwbf[i] = f2b(out_w[i3]); return; }
  int i4 = i3 - 65536;
  if (i4 < 24576) {
    int layer = (i4 < 12288) ? 0 : 1;
    int rem = i4 - layer * 12288;
    int k = rem >> 8, c = rem & 255;
    float v = (k < 40) ? xp_w[layer * 10240 + k * 256 + c] : 0.0f;
    pwbf[i] = f2b(v);
    return;
  }
  int i5 = i4 - 24576;
  if (i5 < 4096) {
    int d = i5 >> 5, k = i5 & 31;
    float v = (k < 16) ? ew[d * 16 + k] : 0.0f;
    pwbf[i] = f2b(v);
  }
}

// ---------------- embedding via MFMA ----------------
__global__ __launch_bounds__(256) void k_emb(const float* __restrict__ inp,
                                             const unsigned short* __restrict__ ewbf,
                                             const float* __restrict__ eb,
                                             unsigned short* __restrict__ xe) {
  int sig = blockIdx.x;
  int b = sig / MM, m = sig % MM;
  __shared__ float xs[LL];
  const float* ib = inp + (size_t)b * LL * MM + m;
  int tid = threadIdx.x;
  for (int i = tid; i < LL; i += 256) xs[i] = ib[(size_t)i * MM];
  __syncthreads();
  int wv = tid >> 6, ln = tid & 15, q = (tid >> 4) & 3;
  short8 af[8];
#pragma unroll
  for (int et = 0; et < 8; ++et)
    af[et] = *(const short8*)(ewbf + (et * 16 + ln) * 32 + q * 8);
#pragma unroll
  for (int pass = 0; pass < 4; ++pass) {
    int t = pass * 64 + wv * 16 + ln;
    int l0 = t * 8 - 4;
    short8 bfrag;
#pragma unroll
    for (int j = 0; j < 8; ++j) {
      int k = q * 8 + j;
      int l = l0 + k;
      float v = (k < 16 && l >= 0 && l < LL) ? xs[l] : 0.0f;
      bfrag[j] = (short)f2b(v);
    }
    float4v acc[8];
#pragma unroll
    for (int et = 0; et < 8; ++et) {
      acc[et] = (float4v){0.f, 0.f, 0.f, 0.f};
      acc[et] = __builtin_amdgcn_mfma_f32_16x16x32_bf16(af[et], bfrag, acc[et], 0, 0, 0);
    }
    unsigned short* orow = xe + (size_t)sig * 32768 + (size_t)t * 128;
#pragma unroll
    for (int et = 0; et < 8; ++et) {
      int e = et * 16 + q * 4;
      float4 pb = *(const float4*)&eb[e];
      short4v st = {(short)f2b(acc[et][0] + pb.x), (short)f2b(acc[et][1] + pb.y),
                    (short)f2b(acc[et][2] + pb.z), (short)f2b(acc[et][3] + pb.w)};
      *(short4v*)(orow + e) = st;
    }
  }
}

// ---------------- MEGA block stage: all 3 layers + SE, signal resident in LDS ----------------
// grid 768 x 512 threads; dynamic LDS 78464 B (round-6 verified 170us structure)
__global__ __launch_bounds__(512) void k_mega(const unsigned short* __restrict__ u0,
                                              const float* __restrict__ dww, const float* __restrict__ dwb,
                                              const unsigned short* __restrict__ pwbf,
                                              const float* __restrict__ pwb,
                                              const float* __restrict__ w1, const float* __restrict__ b1,
                                              const float* __restrict__ w2, const float* __restrict__ b2,
                                              unsigned short* __restrict__ uout) {
  extern __shared__ char smemraw[];
  unsigned short* us = (unsigned short*)smemraw;
  float* dwT  = (float*)(smemraw + 69632);
  float* dwbL = dwT + 640;
  float* pwbL = dwbL + 128;
  float* sred = pwbL + 128;
  float* smv  = sred + 1024;
  float* hh   = smv + 128;
  float* aL   = hh + 32;

  int sig = blockIdx.x;
  int tid = threadIdx.x;
  const size_t gbase = (size_t)sig * 32768;
  int cu = tid & 15;
  int r0 = tid >> 4;   // 0..31

#pragma unroll
  for (int p = 0; p < 8; ++p) {
    int t = p * 32 + r0;
    short8 v = *(const short8*)(u0 + gbase + (size_t)t * 128 + cu * 8);
    *(short8*)(us + t * 136 + cu * 8) = v;
  }

  int wv = tid >> 6;
  int ln = tid & 15;
  int q  = (tid >> 4) & 3;
  int tb = wv * 32;

  for (int layer = 0; layer < 3; ++layer) {
    __syncthreads();
    for (int i = tid; i < 640; i += 512) dwT[(i % 5) * 128 + (i / 5)] = dww[layer * 640 + i];
    if (tid < 128) { dwbL[tid] = dwb[layer * 128 + tid]; pwbL[tid] = pwb[layer * 128 + tid]; }
    __syncthreads();

    const unsigned short* pwL = pwbf + layer * 16384;
    float4v acc[2][8];
#pragma unroll
    for (int tl = 0; tl < 2; ++tl)
#pragma unroll
      for (int et = 0; et < 8; ++et) acc[tl][et] = (float4v){0.f, 0.f, 0.f, 0.f};

#pragma unroll
    for (int kc = 0; kc < 4; ++kc) {
      int dc = kc * 32 + q * 8;
      short8 af[8];
#pragma unroll
      for (int et = 0; et < 8; ++et)
        af[et] = *(const short8*)(pwL + (size_t)(et * 16 + ln) * 128 + dc);
      float wt[5][8], bl8[8];
#pragma unroll
      for (int k = 0; k < 5; ++k) {
        float4 wa = *(const float4*)&dwT[k * 128 + dc];
        float4 wb = *(const float4*)&dwT[k * 128 + dc + 4];
        wt[k][0] = wa.x; wt[k][1] = wa.y; wt[k][2] = wa.z; wt[k][3] = wa.w;
        wt[k][4] = wb.x; wt[k][5] = wb.y; wt[k][6] = wb.z; wt[k][7] = wb.w;
      }
      {
        float4 ba = *(const float4*)&dwbL[dc];
        float4 bb2 = *(const float4*)&dwbL[dc + 4];
        bl8[0] = ba.x; bl8[1] = ba.y; bl8[2] = ba.z; bl8[3] = ba.w;
        bl8[4] = bb2.x; bl8[5] = bb2.y; bl8[6] = bb2.z; bl8[7] = bb2.w;
      }
#pragma unroll
      for (int tl = 0; tl < 2; ++tl) {
        int t = tb + tl * 16 + ln;
        float a8[8];
#pragma unroll
        for (int j = 0; j < 8; ++j) a8[j] = bl8[j];
#pragma unroll
        for (int k = 0; k < 5; ++k) {
          int tt = t - 2 + k;
          if (tt >= 0 && tt < 256) {
            short8 u8 = *(const short8*)(us + tt * 136 + dc);
#pragma unroll
            for (int j = 0; j < 8; ++j) a8[j] += b2f((unsigned short)u8[j]) * wt[k][j];
          }
        }
        short8 bf;
#pragma unroll
        for (int j = 0; j < 8; ++j)
          bf[j] = (short)f2b(fast_gelu(a8[j]));
#pragma unroll
        for (int et = 0; et < 8; ++et)
          acc[tl][et] = __builtin_amdgcn_mfma_f32_16x16x32_bf16(af[et], bf, acc[tl][et], 0, 0, 0);
      }
    }
    __syncthreads();   // all us reads done; sred free

    // SE t-partial sums -> sred
#pragma unroll
    for (int et = 0; et < 8; ++et) {
      int e = et * 16 + q * 4;
      float4 pb = *(const float4*)&pwbL[e];
      float sv0 = acc[0][et][0] + acc[1][et][0] + 2.0f * pb.x;
      float sv1 = acc[0][et][1] + acc[1][et][1] + 2.0f * pb.y;
      float sv2 = acc[0][et][2] + acc[1][et][2] + 2.0f * pb.z;
      float sv3 = acc[0][et][3] + acc[1][et][3] + 2.0f * pb.w;
#pragma unroll
      for (int m = 1; m <= 8; m <<= 1) {
        sv0 += __shfl_xor(sv0, m, 64);
        sv1 += __shfl_xor(sv1, m, 64);
        sv2 += __shfl_xor(sv2, m, 64);
        sv3 += __shfl_xor(sv3, m, 64);
      }
      if (ln == 0) {
        float4 sv = {sv0, sv1, sv2, sv3};
        *(float4*)&sred[wv * 128 + e] = sv;
      }
    }
    __syncthreads();
    if (tid < 128) {
      float s = 0.f;
#pragma unroll
      for (int w = 0; w < 8; ++w) s += sred[w * 128 + tid];
      smv[tid] = s * (1.0f / 256.0f);
    }
    __syncthreads();
    // SE hidden layer: 256 threads, 8 lanes per output, shuffle-reduce
    if (tid < 256) {
      int o = tid >> 3, part = tid & 7;
      const float* wr = w1 + layer * 4096 + o * 128 + part * 16;
      const float* sv = smv + part * 16;
      float s = 0.f;
#pragma unroll
      for (int j = 0; j < 16; j += 4) {
        float4 w4 = *(const float4*)(wr + j);
        float4 v4 = *(const float4*)(sv + j);
        s += w4.x * v4.x + w4.y * v4.y + w4.z * v4.z + w4.w * v4.w;
      }
      s += __shfl_xor(s, 1, 64);
      s += __shfl_xor(s, 2, 64);
      s += __shfl_xor(s, 4, 64);
      if (part == 0) hh[o] = fmaxf(s + b1[layer * 32 + o], 0.0f);
    }
    __syncthreads();
    // SE gate: all 512 threads, 4 lanes per output
    {
      int o = tid >> 2, part = tid & 3;
      const float* wr = w2 + layer * 4096 + o * 32 + part * 8;
      float s = 0.f;
#pragma unroll
      for (int j = 0; j < 8; j += 4) {
        float4 w4 = *(const float4*)(wr + j);
        float4 h4 = *(const float4*)(hh + part * 8 + j);
        s += w4.x * h4.x + w4.y * h4.y + w4.z * h4.z + w4.w * h4.w;
      }
      s += __shfl_xor(s, 1, 64);
      s += __shfl_xor(s, 2, 64);
      if (part == 0) aL[o] = 1.0f / (1.0f + __expf(-(s + b2[layer * 128 + o])));
    }
    __syncthreads();

    // u += w * a  (in LDS, disjoint per lane)
#pragma unroll
    for (int tl = 0; tl < 2; ++tl) {
      int t = tb + tl * 16 + ln;
#pragma unroll
      for (int et = 0; et < 8; ++et) {
        int e = et * 16 + q * 4;
        float4 pb = *(const float4*)&pwbL[e];
        float4 ga = *(const float4*)&aL[e];
        short4v u4 = *(short4v*)(us + t * 136 + e);
        short4v r;
        r[0] = (short)f2b(b2f((unsigned short)u4[0]) + (acc[tl][et][0] + pb.x) * ga.x);
        r[1] = (short)f2b(b2f((unsigned short)u4[1]) + (acc[tl][et][1] + pb.y) * ga.y);
        r[2] = (short)f2b(b2f((unsigned short)u4[2]) + (acc[tl][et][2] + pb.z) * ga.z);
        r[3] = (short)f2b(b2f((unsigned short)u4[3]) + (acc[tl][et][3] + pb.w) * ga.w);
        *(short4v*)(us + t * 136 + e) = r;
      }
    }
  }
  __syncthreads();
#pragma unroll
  for (int p = 0; p < 8; ++p) {
    int t = p * 32 + r0;
    short8 v = *(short8*)(us + t * 136 + cu * 8);
    *(short8*)(uout + gbase + (size_t)t * 128 + cu * 8) = v;
  }
}

// ---------------- mean over M -> xe2 fp32 + xe2bf bf16 ----------------
__global__ __launch_bounds__(256) void k_reduce2(const unsigned short* __restrict__ u,
                                                 float* __restrict__ xe2,
                                                 unsigned short* __restrict__ xe2bf) {
  int i = blockIdx.x * 256 + threadIdx.x;
  int d0 = (i & 15) * 8;
  int t = (i >> 4) & 255;
  int b = i >> 12;
  float acc[8] = {0.f, 0.f, 0.f, 0.f, 0.f, 0.f, 0.f, 0.f};
#pragma unroll 4
  for (int m = 0; m < 12; ++m) {
    size_t base = ((size_t)(b * 12 + m) * 256 + t) * 128 + d0;
    short8 u8 = *(const short8*)(u + base);
#pragma unroll
    for (int j = 0; j < 8; ++j) acc[j] += b2f((unsigned short)u8[j]);
  }
  size_t off = (size_t)b * 32768 + (size_t)t * 128 + d0;
  float4 o0 = {acc[0] / 12.f, acc[1] / 12.f, acc[2] / 12.f, acc[3] / 12.f};
  float4 o1 = {acc[4] / 12.f, acc[5] / 12.f, acc[6] / 12.f, acc[7] / 12.f};
  *(float4*)(xe2 + off) = o0;
  *(float4*)(xe2 + off + 4) = o1;
  short8 ob;
#pragma unroll
  for (int j = 0; j < 8; ++j) ob[j] = (short)f2b(acc[j] / 12.f);
  *(short8*)(xe2bf + off) = ob;
}

// ---------------- mamba: in-projection via MFMA, zero-LDS -> bf16 xz[t][e] ----------------
__global__ __launch_bounds__(256) void k_inproj(const unsigned short* __restrict__ xe2bf,
                                                const unsigned short* __restrict__ inwbf,
                                                unsigned short* __restrict__ xz) {
  int blk = blockIdx.x;
  int b = blk >> 3;
  int tt = (blk >> 1) & 3;
  int eh = blk & 1;
  int t0 = tt * 64, e0 = eh * 256;
  int tid = threadIdx.x;
  int wv = tid >> 6, ln = tid & 15, q = (tid >> 4) & 3;
  int t = t0 + wv * 16 + ln;
  const unsigned short* xrow = xe2bf + ((size_t)b * 256 + t) * 128 + q * 8;
  short8 bfrag[4];
#pragma unroll
  for (int kc = 0; kc < 4; ++kc) bfrag[kc] = *(const short8*)(xrow + kc * 32);
  float4v acc[16];
#pragma unroll
  for (int et = 0; et < 16; ++et) acc[et] = (float4v){0.f, 0.f, 0.f, 0.f};
#pragma unroll
  for (int et = 0; et < 16; ++et) {
    const unsigned short* arow = inwbf + (size_t)(e0 + et * 16 + ln) * 128 + q * 8;
#pragma unroll
    for (int kc = 0; kc < 4; ++kc) {
      short8 af = *(const short8*)(arow + kc * 32);
      acc[et] = __builtin_amdgcn_mfma_f32_16x16x32_bf16(af, bfrag[kc], acc[et], 0, 0, 0);
    }
  }
  unsigned short* orow = xz + ((size_t)b * 256 + t) * 512 + e0 + q * 4;
#pragma unroll
  for (int et = 0; et < 16; ++et) {
    short4v st = {(short)f2b(acc[et][0]), (short)f2b(acc[et][1]),
                  (short)f2b(acc[et][2]), (short)f2b(acc[et][3])};
    *(short4v*)(orow + et * 16) = st;
  }
}

// ---------------- mamba: fused causal conv+SiLU -> x-projection MFMA; writes xc + dbl ----------------
__global__ __launch_bounds__(256) void k_xproj(const unsigned short* __restrict__ xz,
                                               const float* __restrict__ cw, const float* __restrict__ cb,
                                               const unsigned short* __restrict__ xwbf,
                                               unsigned short* __restrict__ xcg,
                                               float* __restrict__ dbl) {
  __shared__ unsigned short xis[67 * 264];
  int blk = blockIdx.x;
  int b = blk >> 2;
  int tq = blk & 3;
  int t0 = tq * 64;
  int tid = threadIdx.x;

  const short8 ZV = {0, 0, 0, 0, 0, 0, 0, 0};
  for (int idx = tid; idx < 2144; idx += 256) {
    int row = idx >> 5, cu = idx & 31;
    int t = t0 - 3 + row;
    short8 v = ZV;
    if (t >= 0) v = *(const short8*)(xz + ((size_t)b * 256 + t) * 512 + cu * 8);
    *(short8*)(xis + row * 264 + cu * 8) = v;
  }
  __syncthreads();

  int cu = tid & 31;
  int rb = tid >> 5;
  int c8 = cu * 8;
  float wl[4][8], bl[8];
#pragma unroll
  for (int j = 0; j < 8; ++j) {
    float4 w4 = *(const float4*)&cw[(c8 + j) * 4];
    wl[0][j] = w4.x; wl[1][j] = w4.y; wl[2][j] = w4.z; wl[3][j] = w4.w;
    bl[j] = cb[c8 + j];
  }

  short8 vv[4];
#pragma unroll
  for (int s = 0; s < 4; ++s) {
    int r = rb + s * 8;
    float acc[8];
#pragma unroll
    for (int j = 0; j < 8; ++j) acc[j] = bl[j];
#pragma unroll
    for (int k = 0; k < 4; ++k) {
      short8 u8 = *(const short8*)(xis + (r + k) * 264 + c8);
#pragma unroll
      for (int j = 0; j < 8; ++j) acc[j] += b2f((unsigned short)u8[j]) * wl[k][j];
    }
#pragma unroll
    for (int j = 0; j < 8; ++j)
      vv[s][j] = (short)f2b(acc[j] / (1.0f + __expf(-acc[j])));
    *(short8*)(xcg + ((size_t)b * 256 + t0 + r) * 256 + c8) = vv[s];
  }
  __syncthreads();
#pragma unroll
  for (int s = 0; s < 4; ++s)
    *(short8*)(xis + (rb + s * 8) * 264 + c8) = vv[s];

#pragma unroll
  for (int s = 0; s < 4; ++s) {
    int r = 32 + rb + s * 8;
    float acc[8];
#pragma unroll
    for (int j = 0; j < 8; ++j) acc[j] = bl[j];
#pragma unroll
    for (int k = 0; k < 4; ++k) {
      short8 u8 = *(const short8*)(xis + (r + k) * 264 + c8);
#pragma unroll
      for (int j = 0; j < 8; ++j) acc[j] += b2f((unsigned short)u8[j]) * wl[k][j];
    }
#pragma unroll
    for (int j = 0; j < 8; ++j)
      vv[s][j] = (short)f2b(acc[j] / (1.0f + __expf(-acc[j])));
    *(short8*)(xcg + ((size_t)b * 256 + t0 + r) * 256 + c8) = vv[s];
  }
  __syncthreads();
#pragma unroll
  for (int s = 0; s < 4; ++s)
    *(short8*)(xis + (32 + rb + s * 8) * 264 + c8) = vv[s];
  __syncthreads();

  int wv = tid >> 6, ln = tid & 15, q = (tid >> 4) & 3;
  int tl = wv * 16 + ln;
  short8 bfrag[8];
#pragma unroll
  for (int kc = 0; kc < 8; ++kc)
    bfrag[kc] = *(const short8*)(xis + tl * 264 + kc * 32 + q * 8);
  float4v acc[3];
#pragma unroll
  for (int et = 0; et < 3; ++et) acc[et] = (float4v){0.f, 0.f, 0.f, 0.f};
#pragma unroll
  for (int et = 0; et < 3; ++et) {
    const unsigned short* arow = xwbf + (size_t)(et * 16 + ln) * 256 + q * 8;
#pragma unroll
    for (int kc = 0; kc < 8; ++kc) {
      short8 af = *(const short8*)(arow + kc * 32);
      acc[et] = __builtin_amdgcn_mfma_f32_16x16x32_bf16(af, bfrag[kc], acc[et], 0, 0, 0);
    }
  }
  float* drow = dbl + ((size_t)b * 256 + t0 + tl) * 40;
#pragma unroll
  for (int et = 0; et < 3; ++et)
#pragma unroll
    for (int r = 0; r < 4; ++r) {
      int k = et * 16 + q * 4 + r;
      if (k < 40) drow[k] = acc[et][r];
    }
}

// ---------------- mamba: fused dt + selective scan + y-finalize ----------------
// 256 threads; serial scan now 2 states/thread across ALL 256 threads
// (channel = tid>>3, states = (tid&7)*2; reduce qxor1+qxor2+shfl_xor4)
__global__ __launch_bounds__(256) void k_scan2(const float* __restrict__ dbl,
                                               const unsigned short* __restrict__ xc,
                                               const unsigned short* __restrict__ xz,
                                               const float* __restrict__ Alog,
                                               const float* __restrict__ dtw, const float* __restrict__ dtbv,
                                               const float* __restrict__ Dp, unsigned short* __restrict__ y) {
  __shared__ float ds[32][40];
  __shared__ float dxs[32][32][4];
  __shared__ float yl[32][32];
  __shared__ float dtwL[32][8];
  __shared__ float dtbL[32];
  __shared__ float DpL[32];

  int b = blockIdx.x >> 3;
  int c0 = (blockIdx.x & 7) * 32;
  int tid = threadIdx.x;

  for (int idx = tid; idx < 256; idx += 256) dtwL[idx >> 3][idx & 7] = dtw[(c0 + (idx >> 3)) * 8 + (idx & 7)];
  if (tid < 32) { dtbL[tid] = dtbv[c0 + tid]; DpL[tid] = Dp[c0 + tid]; }

  int c_loc = tid >> 3;          // 0..31
  int c = c0 + c_loc;
  int sblk = (tid & 7) * 2;      // 0,2,..,14

  float2 Al = *(const float2*)&Alog[c * 16 + sblk];
  float A0 = -__expf(Al.x), A1 = -__expf(Al.y);
  float h0 = 0.f, h1 = 0.f;

  const float* dbp = dbl + (size_t)b * 10240;
  const unsigned short* xcp = xc + (size_t)b * 65536;
  const unsigned short* xzp = xz + (size_t)b * 131072;
  unsigned short* yp = y + (size_t)b * 65536;

  for (int chk = 0; chk < 8; ++chk) {
    int t0c = chk * 32;
    for (int idx = tid; idx < 1280; idx += 256) ((float*)ds)[idx] = dbp[t0c * 40 + idx];
    for (int idx = tid; idx < 512; idx += 256) {
      int t = idx >> 4, cc2 = (idx & 15) * 2;
      ushort2 xv = *(const ushort2*)&xcp[(size_t)(t0c + t) * 256 + c0 + cc2];
      ushort2 zv = *(const ushort2*)&xzp[(size_t)(t0c + t) * 512 + 256 + c0 + cc2];
      dxs[t][cc2][1] = b2f(xv.x);
      dxs[t][cc2 + 1][1] = b2f(xv.y);
      dxs[t][cc2][2] = b2f(zv.x);
      dxs[t][cc2 + 1][2] = b2f(zv.y);
    }
    __syncthreads();
    for (int idx = tid; idx < 1024; idx += 256) {
      int t = idx >> 5, cc = idx & 31;
      const float* dr = ds[t];
      const float* wr = dtwL[cc];
      float acc = dtbL[cc];
#pragma unroll
      for (int j = 0; j < 8; ++j) acc += wr[j] * dr[j];
      dxs[t][cc][0] = (acc > 20.0f) ? acc : __logf(1.0f + __expf(acc));
    }
    __syncthreads();
#pragma unroll 4
    for (int t = 0; t < 32; ++t) {
      float2 dx = *(const float2*)&dxs[t][c_loc][0];
      float2 Bv = *(const float2*)&ds[t][8 + sblk];
      float2 Cv = *(const float2*)&ds[t][24 + sblk];
      float dtv = dx.x;
      float bx = dtv * dx.y;
      h0 = __expf(dtv * A0) * h0 + Bv.x * bx;
      h1 = __expf(dtv * A1) * h1 + Bv.y * bx;
      float p = h0 * Cv.x;
      p = fmaf(h1, Cv.y, p);
      p += qxor1(p);
      p += qxor2(p);
      p += __shfl_xor(p, 4, 64);
      if ((tid & 7) == 0) yl[t][c_loc] = p;
    }
    __syncthreads();
    for (int idx = tid; idx < 512; idx += 256) {
      int t = idx >> 4, cc2 = (idx & 15) * 2;
      float p0 = yl[t][cc2], p1 = yl[t][cc2 + 1];
      float x0 = dxs[t][cc2][1], x1 = dxs[t][cc2 + 1][1];
      float z0 = dxs[t][cc2][2], z1 = dxs[t][cc2 + 1][2];
      float s0 = z0 / (1.0f + __expf(-z0));
      float s1 = z1 / (1.0f + __expf(-z1));
      ushort2 o = {f2b((p0 + DpL[cc2] * x0) * s0), f2b((p1 + DpL[cc2 + 1] * x1) * s1)};
      *(ushort2*)&yp[(size_t)(t0c + t) * 256 + c0 + cc2] = o;
    }
    __syncthreads();
  }
}

// ---------------- mamba: MFMA out-projection + residual + LayerNorm, zero-LDS ----------------
__global__ __launch_bounds__(128) void k_outln(const unsigned short* __restrict__ yb,
                                               const unsigned short* __restrict__ owbf,
                                               float* __restrict__ xe2, unsigned short* __restrict__ xe2bf,
                                               const float* __restrict__ g, const float* __restrict__ bb) {
  int blk = blockIdx.x;
  int b = blk >> 3;
  int t0 = (blk & 7) * 32;
  int tid = threadIdx.x;
  int wv = tid >> 6, ln = tid & 15, q = (tid >> 4) & 3;
  int t = t0 + wv * 16 + ln;

  const unsigned short* yrow = yb + ((size_t)b * 256 + t) * 256 + q * 8;
  short8 bfrag[8];
#pragma unroll
  for (int kc = 0; kc < 8; ++kc) bfrag[kc] = *(const short8*)(yrow + kc * 32);

  float4v acc[8];
#pragma unroll
  for (int et = 0; et < 8; ++et) acc[et] = (float4v){0.f, 0.f, 0.f, 0.f};
#pragma unroll
  for (int et = 0; et < 8; ++et) {
    const unsigned short* arow = owbf + (size_t)(et * 16 + ln) * 256 + q * 8;
#pragma unroll
    for (int kc = 0; kc < 8; ++kc) {
      short8 af = *(const short8*)(arow + kc * 32);
      acc[et] = __builtin_amdgcn_mfma_f32_16x16x32_bf16(af, bfrag[kc], acc[et], 0, 0, 0);
    }
  }

  float* xrow = xe2 + ((size_t)b * 256 + t) * 128;
  float vals[8][4];
  float s1 = 0.f, s2 = 0.f;
#pragma unroll
  for (int et = 0; et < 8; ++et) {
    float4 res = *(const float4*)(xrow + et * 16 + q * 4);
    float rv[4] = {res.x, res.y, res.z, res.w};
#pragma unroll
    for (int r = 0; r < 4; ++r) {
      float v = acc[et][r] + rv[r];
      vals[et][r] = v;
      s1 += v;
      s2 += v * v;
    }
  }
  s1 += __shfl_xor(s1, 16, 64);
  s1 += __shfl_xor(s1, 32, 64);
  s2 += __shfl_xor(s2, 16, 64);
  s2 += __shfl_xor(s2, 32, 64);
  float mu = s1 * (1.0f / 128.0f);
  float rs = rsqrtf(s2 * (1.0f / 128.0f) - mu * mu + 1e-5f);

  unsigned short* brow = xe2bf + ((size_t)b * 256 + t) * 128;
#pragma unroll
  for (int et = 0; et < 8; ++et) {
    int d = et * 16 + q * 4;
    float4 g4 = *(const float4*)(g + d);
    float4 b4 = *(const float4*)(bb + d);
    float o0 = (vals[et][0] - mu) * rs * g4.x + b4.x;
    float o1 = (vals[et][1] - mu) * rs * g4.y + b4.y;
    float o2 = (vals[et][2] - mu) * rs * g4.z + b4.z;
    float o3 = (vals[et][3] - mu) * rs * g4.w + b4.w;
    float4 of = {o0, o1, o2, o3};
    *(float4*)(xrow + d) = of;
    short4v ob = {(short)f2b(o0), (short)f2b(o1), (short)f2b(o2), (short)f2b(o3)};
    *(short4v*)(brow + d) = ob;
  }
}

// ---------------- xflat transpose (+bf16 copy, + pred bias init) ----------------
__global__ __launch_bounds__(256) void k_xflat(const float* __restrict__ xe2, float* __restrict__ out,
                                               unsigned short* __restrict__ outbf,
                                               const float* __restrict__ fcb, float* __restrict__ pred) {
  int b = blockIdx.x >> 5;
  int blk = blockIdx.x & 31;
  int t0 = (blk >> 2) * 32, d0 = (blk & 3) * 32;
  __shared__ float tile[32][33];
  int tid = threadIdx.x;
  if (blockIdx.x == 0) {
    for (int i = tid; i < 1152; i += 256) pred[i] = fcb[i % 18];
  }
#pragma unroll
  for (int q = 0; q < 4; ++q) {
    int t = (tid >> 5) + q * 8, dd = tid & 31;
    tile[t][dd] = xe2[(size_t)b * 32768 + (size_t)(t0 + t) * 128 + d0 + dd];
  }
  __syncthreads();
#pragma unroll
  for (int q = 0; q < 4; ++q) {
    int dd = (tid >> 5) + q * 8, t = tid & 31;
    float v = tile[t][dd];
    size_t o = (size_t)b * 32768 + (size_t)(d0 + dd) * 256 + t0 + t;
    out[o] = v;
    outbf[o] = f2b(v);
  }
}

// ---------------- final FC via MFMA ----------------
__global__ __launch_bounds__(256) void k_fc(const unsigned short* __restrict__ xflatbf,
                                            const unsigned short* __restrict__ fwbf,
                                            float* __restrict__ pred) {
  int kb = blockIdx.x;
  int k0 = kb * 256;
  int tid = threadIdx.x;
  int wv = tid >> 6, ln = tid & 15, q = (tid >> 4) & 3;
  int b = wv * 16 + ln;
  const unsigned short* xrow = xflatbf + (size_t)b * 32768 + k0 + q * 8;
  float4v acc[2];
  acc[0] = (float4v){0.f, 0.f, 0.f, 0.f};
  acc[1] = (float4v){0.f, 0.f, 0.f, 0.f};
#pragma unroll
  for (int kc = 0; kc < 8; ++kc) {
    short8 bfrag = *(const short8*)(xrow + kc * 32);
#pragma unroll
    for (int et = 0; et < 2; ++et) {
      short8 af = *(const short8*)(fwbf + (size_t)(et * 16 + ln) * 32768 + k0 + kc * 32 + q * 8);
      acc[et] = __builtin_amdgcn_mfma_f32_16x16x32_bf16(af, bfrag, acc[et], 0, 0, 0);
    }
  }
#pragma unroll
  for (int et = 0; et < 2; ++et)
#pragma unroll
    for (int r = 0; r < 4; ++r) {
      int c = et * 16 + q * 4 + r;
      if (c < 18) atomicAdd(&pred[b * 18 + c], acc[et][r]);
    }
}

extern "C" void kernel_launch(void* const* d_in, const int* in_sizes, int n_in,
                              void* d_out, int out_size, void* d_ws, size_t ws_size,
                              hipStream_t stream) {
  (void)in_sizes; (void)n_in; (void)out_size; (void)ws_size;
  const float* inp    = (const float*)d_in[0];
  const float* emb_w  = (const float*)d_in[1];
  const float* emb_b  = (const float*)d_in[2];
  const float* dw_w   = (const float*)d_in[3];
  const float* dw_b   = (const float*)d_in[4];
  const float* pw_w   = (const float*)d_in[5];
  const float* pw_b   = (const float*)d_in[6];
  const float* se_w1  = (const float*)d_in[7];
  const float* se_b1  = (const float*)d_in[8];
  const float* se_w2  = (const float*)d_in[9];
  const float* se_b2  = (const float*)d_in[10];
  const float* in_w   = (const float*)d_in[11];
  const float* conv_w = (const float*)d_in[12];
  const float* conv_b = (const float*)d_in[13];
  const float* xp_w   = (const float*)d_in[14];
  const float* dt_w   = (const float*)d_in[15];
  const float* dt_b   = (const float*)d_in[16];
  const float* Alog   = (const float*)d_in[17];
  const float* Dp     = (const float*)d_in[18];
  const float* out_w  = (const float*)d_in[19];
  const float* ln_g   = (const float*)d_in[20];
  const float* ln_b   = (const float*)d_in[21];
  const float* fc_w   = (const float*)d_in[22];
  const float* fc_b   = (const float*)d_in[23];

  char* ws = (char*)d_ws;
  unsigned short* U0 = (unsigned short*)(ws);
  unsigned short* xz = (unsigned short*)(ws);                 // after reduce2
  unsigned short* xc = (unsigned short*)(ws + 33554432);
  unsigned short* yb = (unsigned short*)(ws + 50331648);
  float* xe2 = (float*)(ws + 100663296);
  unsigned short* xflatbf = (unsigned short*)(ws + 109051904);
  unsigned short* fwbf = (unsigned short*)(ws + 113246208);
  float* dbl = (float*)(ws + 150994944);
  unsigned short* xe2bf = (unsigned short*)(ws + 153616384);

  float* xflat = (float*)d_out;
  float* pred  = xflat + (size_t)64 * 32768;
  unsigned short* pwbf  = (unsigned short*)d_out;   // weight scratch until k_xflat
  unsigned short* inwbf = pwbf + 49152;
  unsigned short* owbf  = inwbf + 131072;
  unsigned short* xwbf  = owbf + 65536;
  unsigned short* ewbf  = xwbf + 24576;

  hipFuncSetAttribute((const void*)k_mega, hipFuncAttributeMaxDynamicSharedMemorySize, MEGA_LDS);

  k_cvt<<<5168, 256, 0, stream>>>(pw_w, in_w, out_w, xp_w, emb_w, fc_w, pwbf, fwbf);
  k_emb<<<768, 256, 0, stream>>>(inp, ewbf, emb_b, U0);

  k_mega<<<768, 512, MEGA_LDS, stream>>>(U0, dw_w, dw_b, pwbf, pw_b,
                                         se_w1, se_b1, se_w2, se_b2, U0);

  k_reduce2<<<1024, 256, 0, stream>>>(U0, xe2, xe2bf);

  for (int i = 0; i < 2; ++i) {
    k_inproj<<<512, 256, 0, stream>>>(xe2bf, inwbf + i * 65536, xz);
    k_xproj<<<256, 256, 0, stream>>>(xz, conv_w + i * 1024, conv_b + i * 256,
                                     xwbf + i * 12288, xc, dbl);
    k_scan2<<<512, 256, 0, stream>>>(dbl, xc, xz, Alog + i * 4096,
                                     dt_w + i * 2048, dt_b + i * 256, Dp + i * 256, yb);
    k_outln<<<512, 128, 0, stream>>>(yb, owbf + i * 32768, xe2, xe2bf,
                                     ln_g + i * 128, ln_b + i * 128);
  }

  k_xflat<<<2048, 256, 0, stream>>>(xe2, xflat, xflatbf, fc_b, pred);
  k_fc<<<128, 256, 0, stream>>>(xflatbf, fwbf, pred);
}

// Round 10
// 546.360 us; speedup vs baseline: 1.1355x; 1.0002x over previous
//
#include <hip/hip_runtime.h>
#include <math.h>

#define LL 2048
#define MM 12
#define DD 128
#define TP 256   // T
#define MEGA_LDS 78464

typedef short short8 __attribute__((ext_vector_type(8)));
typedef short short4v __attribute__((ext_vector_type(4)));
typedef float float4v __attribute__((ext_vector_type(4)));

static __device__ __forceinline__ unsigned short f2b(float f) {
  union { float f; unsigned int u; } x; x.f = f;
  unsigned int r = x.u + 0x7fffu + ((x.u >> 16) & 1u);
  return (unsigned short)(r >> 16);
}
static __device__ __forceinline__ float b2f(unsigned short u) {
  union { unsigned int u; float f; } x; x.u = ((unsigned int)u) << 16;
  return x.f;
}
// branch-free erf (A&S 7.1.26, |err| <= ~5e-7): rcp + exp + 5 FMA
static __device__ __forceinline__ float fast_gelu(float x) {
  float xs = x * 0.70710678118654752f;
  float y = fabsf(xs);
  float t = __builtin_amdgcn_rcpf(fmaf(0.3275911f, y, 1.0f));
  float p = fmaf(fmaf(fmaf(fmaf(1.061405429f, t, -1.453152027f), t,
                           1.421413741f), t, -0.284496736f), t, 0.254829592f);
  p = p * t;
  float e = __expf(-y * y);
  float er = fmaf(-p, e, 1.0f);
  er = copysignf(er, xs);
  return 0.5f * x * (1.0f + er);
}
static __device__ __forceinline__ float qxor1(float x) {
  int r = __builtin_amdgcn_mov_dpp(__builtin_bit_cast(int, x), 0xB1, 0xF, 0xF, true);
  return __builtin_bit_cast(float, r);
}
static __device__ __forceinline__ float qxor2(float x) {
  int r = __builtin_amdgcn_mov_dpp(__builtin_bit_cast(int, x), 0x4E, 0xF, 0xF, true);
  return __builtin_bit_cast(float, r);
}

// ---------------- convert weights to bf16 (pw, in_w, out_w, padded xp_w, padded ew, permuted fc_w) ----------------
// grid 5168x256: first 274432 ids = small weights; remaining 1048576 = fc_w -> fwbf [32][t*128+d]
// fwbf is PERMUTED so k_fc can consume xe2bf ([t][d]-contiguous) directly: fwbf[c][t*128+d]=fc_w[c][d*256+t]
__global__ __launch_bounds__(256) void k_cvt(const float* __restrict__ pw_w, const float* __restrict__ in_w,
                                             const float* __restrict__ out_w, const float* __restrict__ xp_w,
                                             const float* __restrict__ ew, const float* __restrict__ fw,
                                             unsigned short* __restrict__ pwbf, unsigned short* __restrict__ fwbf) {
  int i = blockIdx.x * 256 + threadIdx.x;
  if (i >= 274432) {
    int j = i - 274432;
    int m = j >> 15, k = j & 32767;
    int t = k >> 7, d = k & 127;
    fwbf[j] = f2b((m < 18) ? fw[m * 32768 + d * 256 + t] : 0.0f);
    return;
  }
  if (i < 49152) { pwbf[i] = f2b(pw_w[i]); return; }
  int i2 = i - 49152;
  if (i2 < 131072) { pwbf[i] = f2b(in_w[i2]); return; }
  int i3 = i2 - 131072;
  if (i3 < 65536) { pwbf[i] = f2b(out_w[i3]); return; }
  int i4 = i3 - 65536;
  if (i4 < 24576) {
    int layer = (i4 < 12288) ? 0 : 1;
    int rem = i4 - layer * 12288;
    int k = rem >> 8, c = rem & 255;
    float v = (k < 40) ? xp_w[layer * 10240 + k * 256 + c] : 0.0f;
    pwbf[i] = f2b(v);
    return;
  }
  int i5 = i4 - 24576;
  if (i5 < 4096) {
    int d = i5 >> 5, k = i5 & 31;
    float v = (k < 16) ? ew[d * 16 + k] : 0.0f;
    pwbf[i] = f2b(v);
  }
}

// ---------------- embedding via MFMA ----------------
__global__ __launch_bounds__(256) void k_emb(const float* __restrict__ inp,
                                             const unsigned short* __restrict__ ewbf,
                                             const float* __restrict__ eb,
                                             unsigned short* __restrict__ xe) {
  int sig = blockIdx.x;
  int b = sig / MM, m = sig % MM;
  __shared__ float xs[LL];
  const float* ib = inp + (size_t)b * LL * MM + m;
  int tid = threadIdx.x;
  for (int i = tid; i < LL; i += 256) xs[i] = ib[(size_t)i * MM];
  __syncthreads();
  int wv = tid >> 6, ln = tid & 15, q = (tid >> 4) & 3;
  short8 af[8];
#pragma unroll
  for (int et = 0; et < 8; ++et)
    af[et] = *(const short8*)(ewbf + (et * 16 + ln) * 32 + q * 8);
#pragma unroll
  for (int pass = 0; pass < 4; ++pass) {
    int t = pass * 64 + wv * 16 + ln;
    int l0 = t * 8 - 4;
    short8 bfrag;
#pragma unroll
    for (int j = 0; j < 8; ++j) {
      int k = q * 8 + j;
      int l = l0 + k;
      float v = (k < 16 && l >= 0 && l < LL) ? xs[l] : 0.0f;
      bfrag[j] = (short)f2b(v);
    }
    float4v acc[8];
#pragma unroll
    for (int et = 0; et < 8; ++et) {
      acc[et] = (float4v){0.f, 0.f, 0.f, 0.f};
      acc[et] = __builtin_amdgcn_mfma_f32_16x16x32_bf16(af[et], bfrag, acc[et], 0, 0, 0);
    }
    unsigned short* orow = xe + (size_t)sig * 32768 + (size_t)t * 128;
#pragma unroll
    for (int et = 0; et < 8; ++et) {
      int e = et * 16 + q * 4;
      float4 pb = *(const float4*)&eb[e];
      short4v st = {(short)f2b(acc[et][0] + pb.x), (short)f2b(acc[et][1] + pb.y),
                    (short)f2b(acc[et][2] + pb.z), (short)f2b(acc[et][3] + pb.w)};
      *(short4v*)(orow + e) = st;
    }
  }
}

// ---------------- MEGA block stage: all 3 layers + SE, signal resident in LDS ----------------
// grid 768 x 512 threads; dynamic LDS 78464 B (round-6 verified 170us structure)
__global__ __launch_bounds__(512) void k_mega(const unsigned short* __restrict__ u0,
                                              const float* __restrict__ dww, const float* __restrict__ dwb,
                                              const unsigned short* __restrict__ pwbf,
                                              const float* __restrict__ pwb,
                                              const float* __restrict__ w1, const float* __restrict__ b1,
                                              const float* __restrict__ w2, const float* __restrict__ b2,
                                              unsigned short* __restrict__ uout) {
  extern __shared__ char smemraw[];
  unsigned short* us = (unsigned short*)smemraw;
  float* dwT  = (float*)(smemraw + 69632);
  float* dwbL = dwT + 640;
  float* pwbL = dwbL + 128;
  float* sred = pwbL + 128;
  float* smv  = sred + 1024;
  float* hh   = smv + 128;
  float* aL   = hh + 32;

  int sig = blockIdx.x;
  int tid = threadIdx.x;
  const size_t gbase = (size_t)sig * 32768;
  int cu = tid & 15;
  int r0 = tid >> 4;   // 0..31

#pragma unroll
  for (int p = 0; p < 8; ++p) {
    int t = p * 32 + r0;
    short8 v = *(const short8*)(u0 + gbase + (size_t)t * 128 + cu * 8);
    *(short8*)(us + t * 136 + cu * 8) = v;
  }

  int wv = tid >> 6;
  int ln = tid & 15;
  int q  = (tid >> 4) & 3;
  int tb = wv * 32;

  for (int layer = 0; layer < 3; ++layer) {
    __syncthreads();
    for (int i = tid; i < 640; i += 512) dwT[(i % 5) * 128 + (i / 5)] = dww[layer * 640 + i];
    if (tid < 128) { dwbL[tid] = dwb[layer * 128 + tid]; pwbL[tid] = pwb[layer * 128 + tid]; }
    __syncthreads();

    const unsigned short* pwL = pwbf + layer * 16384;
    float4v acc[2][8];
#pragma unroll
    for (int tl = 0; tl < 2; ++tl)
#pragma unroll
      for (int et = 0; et < 8; ++et) acc[tl][et] = (float4v){0.f, 0.f, 0.f, 0.f};

#pragma unroll
    for (int kc = 0; kc < 4; ++kc) {
      int dc = kc * 32 + q * 8;
      short8 af[8];
#pragma unroll
      for (int et = 0; et < 8; ++et)
        af[et] = *(const short8*)(pwL + (size_t)(et * 16 + ln) * 128 + dc);
      float wt[5][8], bl8[8];
#pragma unroll
      for (int k = 0; k < 5; ++k) {
        float4 wa = *(const float4*)&dwT[k * 128 + dc];
        float4 wb = *(const float4*)&dwT[k * 128 + dc + 4];
        wt[k][0] = wa.x; wt[k][1] = wa.y; wt[k][2] = wa.z; wt[k][3] = wa.w;
        wt[k][4] = wb.x; wt[k][5] = wb.y; wt[k][6] = wb.z; wt[k][7] = wb.w;
      }
      {
        float4 ba = *(const float4*)&dwbL[dc];
        float4 bb2 = *(const float4*)&dwbL[dc + 4];
        bl8[0] = ba.x; bl8[1] = ba.y; bl8[2] = ba.z; bl8[3] = ba.w;
        bl8[4] = bb2.x; bl8[5] = bb2.y; bl8[6] = bb2.z; bl8[7] = bb2.w;
      }
#pragma unroll
      for (int tl = 0; tl < 2; ++tl) {
        int t = tb + tl * 16 + ln;
        float a8[8];
#pragma unroll
        for (int j = 0; j < 8; ++j) a8[j] = bl8[j];
#pragma unroll
        for (int k = 0; k < 5; ++k) {
          int tt = t - 2 + k;
          if (tt >= 0 && tt < 256) {
            short8 u8 = *(const short8*)(us + tt * 136 + dc);
#pragma unroll
            for (int j = 0; j < 8; ++j) a8[j] += b2f((unsigned short)u8[j]) * wt[k][j];
          }
        }
        short8 bf;
#pragma unroll
        for (int j = 0; j < 8; ++j)
          bf[j] = (short)f2b(fast_gelu(a8[j]));
#pragma unroll
        for (int et = 0; et < 8; ++et)
          acc[tl][et] = __builtin_amdgcn_mfma_f32_16x16x32_bf16(af[et], bf, acc[tl][et], 0, 0, 0);
      }
    }
    __syncthreads();   // all us reads done; sred free

    // SE t-partial sums -> sred
#pragma unroll
    for (int et = 0; et < 8; ++et) {
      int e = et * 16 + q * 4;
      float4 pb = *(const float4*)&pwbL[e];
      float sv0 = acc[0][et][0] + acc[1][et][0] + 2.0f * pb.x;
      float sv1 = acc[0][et][1] + acc[1][et][1] + 2.0f * pb.y;
      float sv2 = acc[0][et][2] + acc[1][et][2] + 2.0f * pb.z;
      float sv3 = acc[0][et][3] + acc[1][et][3] + 2.0f * pb.w;
#pragma unroll
      for (int m = 1; m <= 8; m <<= 1) {
        sv0 += __shfl_xor(sv0, m, 64);
        sv1 += __shfl_xor(sv1, m, 64);
        sv2 += __shfl_xor(sv2, m, 64);
        sv3 += __shfl_xor(sv3, m, 64);
      }
      if (ln == 0) {
        float4 sv = {sv0, sv1, sv2, sv3};
        *(float4*)&sred[wv * 128 + e] = sv;
      }
    }
    __syncthreads();
    if (tid < 128) {
      float s = 0.f;
#pragma unroll
      for (int w = 0; w < 8; ++w) s += sred[w * 128 + tid];
      smv[tid] = s * (1.0f / 256.0f);
    }
    __syncthreads();
    // SE hidden layer: 256 threads, 8 lanes per output, shuffle-reduce
    if (tid < 256) {
      int o = tid >> 3, part = tid & 7;
      const float* wr = w1 + layer * 4096 + o * 128 + part * 16;
      const float* sv = smv + part * 16;
      float s = 0.f;
#pragma unroll
      for (int j = 0; j < 16; j += 4) {
        float4 w4 = *(const float4*)(wr + j);
        float4 v4 = *(const float4*)(sv + j);
        s += w4.x * v4.x + w4.y * v4.y + w4.z * v4.z + w4.w * v4.w;
      }
      s += __shfl_xor(s, 1, 64);
      s += __shfl_xor(s, 2, 64);
      s += __shfl_xor(s, 4, 64);
      if (part == 0) hh[o] = fmaxf(s + b1[layer * 32 + o], 0.0f);
    }
    __syncthreads();
    // SE gate: all 512 threads, 4 lanes per output
    {
      int o = tid >> 2, part = tid & 3;
      const float* wr = w2 + layer * 4096 + o * 32 + part * 8;
      float s = 0.f;
#pragma unroll
      for (int j = 0; j < 8; j += 4) {
        float4 w4 = *(const float4*)(wr + j);
        float4 h4 = *(const float4*)(hh + part * 8 + j);
        s += w4.x * h4.x + w4.y * h4.y + w4.z * h4.z + w4.w * h4.w;
      }
      s += __shfl_xor(s, 1, 64);
      s += __shfl_xor(s, 2, 64);
      if (part == 0) aL[o] = 1.0f / (1.0f + __expf(-(s + b2[layer * 128 + o])));
    }
    __syncthreads();

    // u += w * a  (in LDS, disjoint per lane)
#pragma unroll
    for (int tl = 0; tl < 2; ++tl) {
      int t = tb + tl * 16 + ln;
#pragma unroll
      for (int et = 0; et < 8; ++et) {
        int e = et * 16 + q * 4;
        float4 pb = *(const float4*)&pwbL[e];
        float4 ga = *(const float4*)&aL[e];
        short4v u4 = *(short4v*)(us + t * 136 + e);
        short4v r;
        r[0] = (short)f2b(b2f((unsigned short)u4[0]) + (acc[tl][et][0] + pb.x) * ga.x);
        r[1] = (short)f2b(b2f((unsigned short)u4[1]) + (acc[tl][et][1] + pb.y) * ga.y);
        r[2] = (short)f2b(b2f((unsigned short)u4[2]) + (acc[tl][et][2] + pb.z) * ga.z);
        r[3] = (short)f2b(b2f((unsigned short)u4[3]) + (acc[tl][et][3] + pb.w) * ga.w);
        *(short4v*)(us + t * 136 + e) = r;
      }
    }
  }
  __syncthreads();
#pragma unroll
  for (int p = 0; p < 8; ++p) {
    int t = p * 32 + r0;
    short8 v = *(short8*)(us + t * 136 + cu * 8);
    *(short8*)(uout + gbase + (size_t)t * 128 + cu * 8) = v;
  }
}

// ---------------- mean over M -> xe2bf bf16 (residual stream is bf16-only) ----------------
__global__ __launch_bounds__(256) void k_reduce2(const unsigned short* __restrict__ u,
                                                 unsigned short* __restrict__ xe2bf) {
  int i = blockIdx.x * 256 + threadIdx.x;
  int d0 = (i & 15) * 8;
  int t = (i >> 4) & 255;
  int b = i >> 12;
  float acc[8] = {0.f, 0.f, 0.f, 0.f, 0.f, 0.f, 0.f, 0.f};
#pragma unroll 4
  for (int m = 0; m < 12; ++m) {
    size_t base = ((size_t)(b * 12 + m) * 256 + t) * 128 + d0;
    short8 u8 = *(const short8*)(u + base);
#pragma unroll
    for (int j = 0; j < 8; ++j) acc[j] += b2f((unsigned short)u8[j]);
  }
  size_t off = (size_t)b * 32768 + (size_t)t * 128 + d0;
  short8 ob;
#pragma unroll
  for (int j = 0; j < 8; ++j) ob[j] = (short)f2b(acc[j] / 12.f);
  *(short8*)(xe2bf + off) = ob;
}

// ---------------- mamba: in-projection via MFMA, zero-LDS -> bf16 xz[t][e] ----------------
__global__ __launch_bounds__(256) void k_inproj(const unsigned short* __restrict__ xe2bf,
                                                const unsigned short* __restrict__ inwbf,
                                                unsigned short* __restrict__ xz) {
  int blk = blockIdx.x;
  int b = blk >> 3;
  int tt = (blk >> 1) & 3;
  int eh = blk & 1;
  int t0 = tt * 64, e0 = eh * 256;
  int tid = threadIdx.x;
  int wv = tid >> 6, ln = tid & 15, q = (tid >> 4) & 3;
  int t = t0 + wv * 16 + ln;
  const unsigned short* xrow = xe2bf + ((size_t)b * 256 + t) * 128 + q * 8;
  short8 bfrag[4];
#pragma unroll
  for (int kc = 0; kc < 4; ++kc) bfrag[kc] = *(const short8*)(xrow + kc * 32);
  float4v acc[16];
#pragma unroll
  for (int et = 0; et < 16; ++et) acc[et] = (float4v){0.f, 0.f, 0.f, 0.f};
#pragma unroll
  for (int et = 0; et < 16; ++et) {
    const unsigned short* arow = inwbf + (size_t)(e0 + et * 16 + ln) * 128 + q * 8;
#pragma unroll
    for (int kc = 0; kc < 4; ++kc) {
      short8 af = *(const short8*)(arow + kc * 32);
      acc[et] = __builtin_amdgcn_mfma_f32_16x16x32_bf16(af, bfrag[kc], acc[et], 0, 0, 0);
    }
  }
  unsigned short* orow = xz + ((size_t)b * 256 + t) * 512 + e0 + q * 4;
#pragma unroll
  for (int et = 0; et < 16; ++et) {
    short4v st = {(short)f2b(acc[et][0]), (short)f2b(acc[et][1]),
                  (short)f2b(acc[et][2]), (short)f2b(acc[et][3])};
    *(short4v*)(orow + et * 16) = st;
  }
}

// ---------------- mamba: fused causal conv+SiLU -> x-projection MFMA; writes xc + dbl ----------------
__global__ __launch_bounds__(256) void k_xproj(const unsigned short* __restrict__ xz,
                                               const float* __restrict__ cw, const float* __restrict__ cb,
                                               const unsigned short* __restrict__ xwbf,
                                               unsigned short* __restrict__ xcg,
                                               float* __restrict__ dbl) {
  __shared__ unsigned short xis[67 * 264];
  int blk = blockIdx.x;
  int b = blk >> 2;
  int tq = blk & 3;
  int t0 = tq * 64;
  int tid = threadIdx.x;

  const short8 ZV = {0, 0, 0, 0, 0, 0, 0, 0};
  for (int idx = tid; idx < 2144; idx += 256) {
    int row = idx >> 5, cu = idx & 31;
    int t = t0 - 3 + row;
    short8 v = ZV;
    if (t >= 0) v = *(const short8*)(xz + ((size_t)b * 256 + t) * 512 + cu * 8);
    *(short8*)(xis + row * 264 + cu * 8) = v;
  }
  __syncthreads();

  int cu = tid & 31;
  int rb = tid >> 5;
  int c8 = cu * 8;
  float wl[4][8], bl[8];
#pragma unroll
  for (int j = 0; j < 8; ++j) {
    float4 w4 = *(const float4*)&cw[(c8 + j) * 4];
    wl[0][j] = w4.x; wl[1][j] = w4.y; wl[2][j] = w4.z; wl[3][j] = w4.w;
    bl[j] = cb[c8 + j];
  }

  short8 vv[4];
#pragma unroll
  for (int s = 0; s < 4; ++s) {
    int r = rb + s * 8;
    float acc[8];
#pragma unroll
    for (int j = 0; j < 8; ++j) acc[j] = bl[j];
#pragma unroll
    for (int k = 0; k < 4; ++k) {
      short8 u8 = *(const short8*)(xis + (r + k) * 264 + c8);
#pragma unroll
      for (int j = 0; j < 8; ++j) acc[j] += b2f((unsigned short)u8[j]) * wl[k][j];
    }
#pragma unroll
    for (int j = 0; j < 8; ++j)
      vv[s][j] = (short)f2b(acc[j] / (1.0f + __expf(-acc[j])));
    *(short8*)(xcg + ((size_t)b * 256 + t0 + r) * 256 + c8) = vv[s];
  }
  __syncthreads();
#pragma unroll
  for (int s = 0; s < 4; ++s)
    *(short8*)(xis + (rb + s * 8) * 264 + c8) = vv[s];

#pragma unroll
  for (int s = 0; s < 4; ++s) {
    int r = 32 + rb + s * 8;
    float acc[8];
#pragma unroll
    for (int j = 0; j < 8; ++j) acc[j] = bl[j];
#pragma unroll
    for (int k = 0; k < 4; ++k) {
      short8 u8 = *(const short8*)(xis + (r + k) * 264 + c8);
#pragma unroll
      for (int j = 0; j < 8; ++j) acc[j] += b2f((unsigned short)u8[j]) * wl[k][j];
    }
#pragma unroll
    for (int j = 0; j < 8; ++j)
      vv[s][j] = (short)f2b(acc[j] / (1.0f + __expf(-acc[j])));
    *(short8*)(xcg + ((size_t)b * 256 + t0 + r) * 256 + c8) = vv[s];
  }
  __syncthreads();
#pragma unroll
  for (int s = 0; s < 4; ++s)
    *(short8*)(xis + (32 + rb + s * 8) * 264 + c8) = vv[s];
  __syncthreads();

  int wv = tid >> 6, ln = tid & 15, q = (tid >> 4) & 3;
  int tl = wv * 16 + ln;
  short8 bfrag[8];
#pragma unroll
  for (int kc = 0; kc < 8; ++kc)
    bfrag[kc] = *(const short8*)(xis + tl * 264 + kc * 32 + q * 8);
  float4v acc[3];
#pragma unroll
  for (int et = 0; et < 3; ++et) acc[et] = (float4v){0.f, 0.f, 0.f, 0.f};
#pragma unroll
  for (int et = 0; et < 3; ++et) {
    const unsigned short* arow = xwbf + (size_t)(et * 16 + ln) * 256 + q * 8;
#pragma unroll
    for (int kc = 0; kc < 8; ++kc) {
      short8 af = *(const short8*)(arow + kc * 32);
      acc[et] = __builtin_amdgcn_mfma_f32_16x16x32_bf16(af, bfrag[kc], acc[et], 0, 0, 0);
    }
  }
  float* drow = dbl + ((size_t)b * 256 + t0 + tl) * 40;
#pragma unroll
  for (int et = 0; et < 3; ++et)
#pragma unroll
    for (int r = 0; r < 4; ++r) {
      int k = et * 16 + q * 4 + r;
      if (k < 40) drow[k] = acc[et][r];
    }
}

// ---------------- mamba: fused dt + selective scan + y-finalize ----------------
// 256 threads; serial scan 2 states/thread across ALL 256 threads
__global__ __launch_bounds__(256) void k_scan2(const float* __restrict__ dbl,
                                               const unsigned short* __restrict__ xc,
                                               const unsigned short* __restrict__ xz,
                                               const float* __restrict__ Alog,
                                               const float* __restrict__ dtw, const float* __restrict__ dtbv,
                                               const float* __restrict__ Dp, unsigned short* __restrict__ y) {
  __shared__ float ds[32][40];
  __shared__ float dxs[32][32][4];
  __shared__ float yl[32][32];
  __shared__ float dtwL[32][8];
  __shared__ float dtbL[32];
  __shared__ float DpL[32];

  int b = blockIdx.x >> 3;
  int c0 = (blockIdx.x & 7) * 32;
  int tid = threadIdx.x;

  for (int idx = tid; idx < 256; idx += 256) dtwL[idx >> 3][idx & 7] = dtw[(c0 + (idx >> 3)) * 8 + (idx & 7)];
  if (tid < 32) { dtbL[tid] = dtbv[c0 + tid]; DpL[tid] = Dp[c0 + tid]; }

  int c_loc = tid >> 3;          // 0..31
  int c = c0 + c_loc;
  int sblk = (tid & 7) * 2;      // 0,2,..,14

  float2 Al = *(const float2*)&Alog[c * 16 + sblk];
  float A0 = -__expf(Al.x), A1 = -__expf(Al.y);
  float h0 = 0.f, h1 = 0.f;

  const float* dbp = dbl + (size_t)b * 10240;
  const unsigned short* xcp = xc + (size_t)b * 65536;
  const unsigned short* xzp = xz + (size_t)b * 131072;
  unsigned short* yp = y + (size_t)b * 65536;

  for (int chk = 0; chk < 8; ++chk) {
    int t0c = chk * 32;
    for (int idx = tid; idx < 1280; idx += 256) ((float*)ds)[idx] = dbp[t0c * 40 + idx];
    for (int idx = tid; idx < 512; idx += 256) {
      int t = idx >> 4, cc2 = (idx & 15) * 2;
      ushort2 xv = *(const ushort2*)&xcp[(size_t)(t0c + t) * 256 + c0 + cc2];
      ushort2 zv = *(const ushort2*)&xzp[(size_t)(t0c + t) * 512 + 256 + c0 + cc2];
      dxs[t][cc2][1] = b2f(xv.x);
      dxs[t][cc2 + 1][1] = b2f(xv.y);
      dxs[t][cc2][2] = b2f(zv.x);
      dxs[t][cc2 + 1][2] = b2f(zv.y);
    }
    __syncthreads();
    for (int idx = tid; idx < 1024; idx += 256) {
      int t = idx >> 5, cc = idx & 31;
      const float* dr = ds[t];
      const float* wr = dtwL[cc];
      float acc = dtbL[cc];
#pragma unroll
      for (int j = 0; j < 8; ++j) acc += wr[j] * dr[j];
      dxs[t][cc][0] = (acc > 20.0f) ? acc : __logf(1.0f + __expf(acc));
    }
    __syncthreads();
#pragma unroll 4
    for (int t = 0; t < 32; ++t) {
      float2 dx = *(const float2*)&dxs[t][c_loc][0];
      float2 Bv = *(const float2*)&ds[t][8 + sblk];
      float2 Cv = *(const float2*)&ds[t][24 + sblk];
      float dtv = dx.x;
      float bx = dtv * dx.y;
      h0 = __expf(dtv * A0) * h0 + Bv.x * bx;
      h1 = __expf(dtv * A1) * h1 + Bv.y * bx;
      float p = h0 * Cv.x;
      p = fmaf(h1, Cv.y, p);
      p += qxor1(p);
      p += qxor2(p);
      p += __shfl_xor(p, 4, 64);
      if ((tid & 7) == 0) yl[t][c_loc] = p;
    }
    __syncthreads();
    for (int idx = tid; idx < 512; idx += 256) {
      int t = idx >> 4, cc2 = (idx & 15) * 2;
      float p0 = yl[t][cc2], p1 = yl[t][cc2 + 1];
      float x0 = dxs[t][cc2][1], x1 = dxs[t][cc2 + 1][1];
      float z0 = dxs[t][cc2][2], z1 = dxs[t][cc2 + 1][2];
      float s0 = z0 / (1.0f + __expf(-z0));
      float s1 = z1 / (1.0f + __expf(-z1));
      ushort2 o = {f2b((p0 + DpL[cc2] * x0) * s0), f2b((p1 + DpL[cc2 + 1] * x1) * s1)};
      *(ushort2*)&yp[(size_t)(t0c + t) * 256 + c0 + cc2] = o;
    }
    __syncthreads();
  }
}

// ---------------- mamba: MFMA out-projection + residual(bf16) + LayerNorm, zero-LDS ----------------
__global__ __launch_bounds__(128) void k_outln(const unsigned short* __restrict__ yb,
                                               const unsigned short* __restrict__ owbf,
                                               unsigned short* __restrict__ xe2bf,
                                               const float* __restrict__ g, const float* __restrict__ bb) {
  int blk = blockIdx.x;
  int b = blk >> 3;
  int t0 = (blk & 7) * 32;
  int tid = threadIdx.x;
  int wv = tid >> 6, ln = tid & 15, q = (tid >> 4) & 3;
  int t = t0 + wv * 16 + ln;

  const unsigned short* yrow = yb + ((size_t)b * 256 + t) * 256 + q * 8;
  short8 bfrag[8];
#pragma unroll
  for (int kc = 0; kc < 8; ++kc) bfrag[kc] = *(const short8*)(yrow + kc * 32);

  float4v acc[8];
#pragma unroll
  for (int et = 0; et < 8; ++et) acc[et] = (float4v){0.f, 0.f, 0.f, 0.f};
#pragma unroll
  for (int et = 0; et < 8; ++et) {
    const unsigned short* arow = owbf + (size_t)(et * 16 + ln) * 256 + q * 8;
#pragma unroll
    for (int kc = 0; kc < 8; ++kc) {
      short8 af = *(const short8*)(arow + kc * 32);
      acc[et] = __builtin_amdgcn_mfma_f32_16x16x32_bf16(af, bfrag[kc], acc[et], 0, 0, 0);
    }
  }

  unsigned short* xrow = xe2bf + ((size_t)b * 256 + t) * 128;
  float vals[8][4];
  float s1 = 0.f, s2 = 0.f;
#pragma unroll
  for (int et = 0; et < 8; ++et) {
    short4v res = *(const short4v*)(xrow + et * 16 + q * 4);
#pragma unroll
    for (int r = 0; r < 4; ++r) {
      float v = acc[et][r] + b2f((unsigned short)res[r]);
      vals[et][r] = v;
      s1 += v;
      s2 += v * v;
    }
  }
  s1 += __shfl_xor(s1, 16, 64);
  s1 += __shfl_xor(s1, 32, 64);
  s2 += __shfl_xor(s2, 16, 64);
  s2 += __shfl_xor(s2, 32, 64);
  float mu = s1 * (1.0f / 128.0f);
  float rs = rsqrtf(s2 * (1.0f / 128.0f) - mu * mu + 1e-5f);

#pragma unroll
  for (int et = 0; et < 8; ++et) {
    int d = et * 16 + q * 4;
    float4 g4 = *(const float4*)(g + d);
    float4 b4 = *(const float4*)(bb + d);
    float o0 = (vals[et][0] - mu) * rs * g4.x + b4.x;
    float o1 = (vals[et][1] - mu) * rs * g4.y + b4.y;
    float o2 = (vals[et][2] - mu) * rs * g4.z + b4.z;
    float o3 = (vals[et][3] - mu) * rs * g4.w + b4.w;
    short4v ob = {(short)f2b(o0), (short)f2b(o1), (short)f2b(o2), (short)f2b(o3)};
    *(short4v*)(xrow + d) = ob;
  }
}

// ---------------- xflat transpose from bf16 residual (+ pred bias init) ----------------
__global__ __launch_bounds__(256) void k_xflat(const unsigned short* __restrict__ xe2bf,
                                               float* __restrict__ out,
                                               const float* __restrict__ fcb, float* __restrict__ pred) {
  int b = blockIdx.x >> 5;
  int blk = blockIdx.x & 31;
  int t0 = (blk >> 2) * 32, d0 = (blk & 3) * 32;
  __shared__ float tile[32][33];
  int tid = threadIdx.x;
  if (blockIdx.x == 0) {
    for (int i = tid; i < 1152; i += 256) pred[i] = fcb[i % 18];
  }
#pragma unroll
  for (int q = 0; q < 4; ++q) {
    int t = (tid >> 5) + q * 8, dd = tid & 31;
    tile[t][dd] = b2f(xe2bf[(size_t)b * 32768 + (size_t)(t0 + t) * 128 + d0 + dd]);
  }
  __syncthreads();
#pragma unroll
  for (int q = 0; q < 4; ++q) {
    int dd = (tid >> 5) + q * 8, t = tid & 31;
    float v = tile[t][dd];
    size_t o = (size_t)b * 32768 + (size_t)(d0 + dd) * 256 + t0 + t;
    out[o] = v;
  }
}

// ---------------- final FC via MFMA: consumes xe2bf directly (fwbf is t-major permuted) ----------------
__global__ __launch_bounds__(256) void k_fc(const unsigned short* __restrict__ xe2bf,
                                            const unsigned short* __restrict__ fwbf,
                                            float* __restrict__ pred) {
  int kb = blockIdx.x;
  int k0 = kb * 256;
  int tid = threadIdx.x;
  int wv = tid >> 6, ln = tid & 15, q = (tid >> 4) & 3;
  int b = wv * 16 + ln;
  const unsigned short* xrow = xe2bf + (size_t)b * 32768 + k0 + q * 8;
  float4v acc[2];
  acc[0] = (float4v){0.f, 0.f, 0.f, 0.f};
  acc[1] = (float4v){0.f, 0.f, 0.f, 0.f};
#pragma unroll
  for (int kc = 0; kc < 8; ++kc) {
    short8 bfrag = *(const short8*)(xrow + kc * 32);
#pragma unroll
    for (int et = 0; et < 2; ++et) {
      short8 af = *(const short8*)(fwbf + (size_t)(et * 16 + ln) * 32768 + k0 + kc * 32 + q * 8);
      acc[et] = __builtin_amdgcn_mfma_f32_16x16x32_bf16(af, bfrag, acc[et], 0, 0, 0);
    }
  }
#pragma unroll
  for (int et = 0; et < 2; ++et)
#pragma unroll
    for (int r = 0; r < 4; ++r) {
      int c = et * 16 + q * 4 + r;
      if (c < 18) atomicAdd(&pred[b * 18 + c], acc[et][r]);
    }
}

extern "C" void kernel_launch(void* const* d_in, const int* in_sizes, int n_in,
                              void* d_out, int out_size, void* d_ws, size_t ws_size,
                              hipStream_t stream) {
  (void)in_sizes; (void)n_in; (void)out_size; (void)ws_size;
  const float* inp    = (const float*)d_in[0];
  const float* emb_w  = (const float*)d_in[1];
  const float* emb_b  = (const float*)d_in[2];
  const float* dw_w   = (const float*)d_in[3];
  const float* dw_b   = (const float*)d_in[4];
  const float* pw_w   = (const float*)d_in[5];
  const float* pw_b   = (const float*)d_in[6];
  const float* se_w1  = (const float*)d_in[7];
  const float* se_b1  = (const float*)d_in[8];
  const float* se_w2  = (const float*)d_in[9];
  const float* se_b2  = (const float*)d_in[10];
  const float* in_w   = (const float*)d_in[11];
  const float* conv_w = (const float*)d_in[12];
  const float* conv_b = (const float*)d_in[13];
  const float* xp_w   = (const float*)d_in[14];
  const float* dt_w   = (const float*)d_in[15];
  const float* dt_b   = (const float*)d_in[16];
  const float* Alog   = (const float*)d_in[17];
  const float* Dp     = (const float*)d_in[18];
  const float* out_w  = (const float*)d_in[19];
  const float* ln_g   = (const float*)d_in[20];
  const float* ln_b   = (const float*)d_in[21];
  const float* fc_w   = (const float*)d_in[22];
  const float* fc_b   = (const float*)d_in[23];

  char* ws = (char*)d_ws;
  unsigned short* U0 = (unsigned short*)(ws);
  unsigned short* xz = (unsigned short*)(ws);                 // after reduce2
  unsigned short* xc = (unsigned short*)(ws + 33554432);
  unsigned short* yb = (unsigned short*)(ws + 50331648);
  unsigned short* fwbf = (unsigned short*)(ws + 113246208);
  float* dbl = (float*)(ws + 150994944);
  unsigned short* xe2bf = (unsigned short*)(ws + 153616384);

  float* xflat = (float*)d_out;
  float* pred  = xflat + (size_t)64 * 32768;
  unsigned short* pwbf  = (unsigned short*)d_out;   // weight scratch until k_xflat
  unsigned short* inwbf = pwbf + 49152;
  unsigned short* owbf  = inwbf + 131072;
  unsigned short* xwbf  = owbf + 65536;
  unsigned short* ewbf  = xwbf + 24576;

  hipFuncSetAttribute((const void*)k_mega, hipFuncAttributeMaxDynamicSharedMemorySize, MEGA_LDS);

  k_cvt<<<5168, 256, 0, stream>>>(pw_w, in_w, out_w, xp_w, emb_w, fc_w, pwbf, fwbf);
  k_emb<<<768, 256, 0, stream>>>(inp, ewbf, emb_b, U0);

  k_mega<<<768, 512, MEGA_LDS, stream>>>(U0, dw_w, dw_b, pwbf, pw_b,
                                         se_w1, se_b1, se_w2, se_b2, U0);

  k_reduce2<<<1024, 256, 0, stream>>>(U0, xe2bf);

  for (int i = 0; i < 2; ++i) {
    k_inproj<<<512, 256, 0, stream>>>(xe2bf, inwbf + i * 65536, xz);
    k_xproj<<<256, 256, 0, stream>>>(xz, conv_w + i * 1024, conv_b + i * 256,
                                     xwbf + i * 12288, xc, dbl);
    k_scan2<<<512, 256, 0, stream>>>(dbl, xc, xz, Alog + i * 4096,
                                     dt_w + i * 2048, dt_b + i * 256, Dp + i * 256, yb);
    k_outln<<<512, 128, 0, stream>>>(yb, owbf + i * 32768, xe2bf,
                                     ln_g + i * 128, ln_b + i * 128);
  }

  k_xflat<<<2048, 256, 0, stream>>>(xe2bf, xflat, fc_b, pred);
  k_fc<<<128, 256, 0, stream>>>(xe2bf, fwbf, pred);
}

// Round 11
// 540.174 us; speedup vs baseline: 1.1485x; 1.0115x over previous
//
#include <hip/hip_runtime.h>
#include <math.h>

#define LL 2048
#define MM 12
#define DD 128
#define TP 256   // T
#define MEGA_LDS 78464

typedef short short8 __attribute__((ext_vector_type(8)));
typedef short short4v __attribute__((ext_vector_type(4)));
typedef float float4v __attribute__((ext_vector_type(4)));

static __device__ __forceinline__ unsigned short f2b(float f) {
  union { float f; unsigned int u; } x; x.f = f;
  unsigned int r = x.u + 0x7fffu + ((x.u >> 16) & 1u);
  return (unsigned short)(r >> 16);
}
static __device__ __forceinline__ float b2f(unsigned short u) {
  union { unsigned int u; float f; } x; x.u = ((unsigned int)u) << 16;
  return x.f;
}
// branch-free erf (A&S 7.1.26, |err| <= ~5e-7): rcp + exp + 5 FMA
static __device__ __forceinline__ float fast_gelu(float x) {
  float xs = x * 0.70710678118654752f;
  float y = fabsf(xs);
  float t = __builtin_amdgcn_rcpf(fmaf(0.3275911f, y, 1.0f));
  float p = fmaf(fmaf(fmaf(fmaf(1.061405429f, t, -1.453152027f), t,
                           1.421413741f), t, -0.284496736f), t, 0.254829592f);
  p = p * t;
  float e = __expf(-y * y);
  float er = fmaf(-p, e, 1.0f);
  er = copysignf(er, xs);
  return 0.5f * x * (1.0f + er);
}
static __device__ __forceinline__ float qxor1(float x) {
  int r = __builtin_amdgcn_mov_dpp(__builtin_bit_cast(int, x), 0xB1, 0xF, 0xF, true);
  return __builtin_bit_cast(float, r);
}
static __device__ __forceinline__ float qxor2(float x) {
  int r = __builtin_amdgcn_mov_dpp(__builtin_bit_cast(int, x), 0x4E, 0xF, 0xF, true);
  return __builtin_bit_cast(float, r);
}

// ---------------- convert weights to bf16 (pw, in_w, out_w, padded xp_w, padded ew, permuted fc_w) ----------------
__global__ __launch_bounds__(256) void k_cvt(const float* __restrict__ pw_w, const float* __restrict__ in_w,
                                             const float* __restrict__ out_w, const float* __restrict__ xp_w,
                                             const float* __restrict__ ew, const float* __restrict__ fw,
                                             unsigned short* __restrict__ pwbf, unsigned short* __restrict__ fwbf) {
  int i = blockIdx.x * 256 + threadIdx.x;
  if (i >= 274432) {
    int j = i - 274432;
    int m = j >> 15, k = j & 32767;
    int t = k >> 7, d = k & 127;
    fwbf[j] = f2b((m < 18) ? fw[m * 32768 + d * 256 + t] : 0.0f);
    return;
  }
  if (i < 49152) { pwbf[i] = f2b(pw_w[i]); return; }
  int i2 = i - 49152;
  if (i2 < 131072) { pwbf[i] = f2b(in_w[i2]); return; }
  int i3 = i2 - 131072;
  if (i3 < 65536) { pwbf[i] = f2b(out_w[i3]); return; }
  int i4 = i3 - 65536;
  if (i4 < 24576) {
    int layer = (i4 < 12288) ? 0 : 1;
    int rem = i4 - layer * 12288;
    int k = rem >> 8, c = rem & 255;
    float v = (k < 40) ? xp_w[layer * 10240 + k * 256 + c] : 0.0f;
    pwbf[i] = f2b(v);
    return;
  }
  int i5 = i4 - 24576;
  if (i5 < 4096) {
    int d = i5 >> 5, k = i5 & 31;
    float v = (k < 16) ? ew[d * 16 + k] : 0.0f;
    pwbf[i] = f2b(v);
  }
}

// ---------------- embedding via MFMA ----------------
__global__ __launch_bounds__(256) void k_emb(const float* __restrict__ inp,
                                             const unsigned short* __restrict__ ewbf,
                                             const float* __restrict__ eb,
                                             unsigned short* __restrict__ xe) {
  int sig = blockIdx.x;
  int b = sig / MM, m = sig % MM;
  __shared__ float xs[LL];
  const float* ib = inp + (size_t)b * LL * MM + m;
  int tid = threadIdx.x;
  for (int i = tid; i < LL; i += 256) xs[i] = ib[(size_t)i * MM];
  __syncthreads();
  int wv = tid >> 6, ln = tid & 15, q = (tid >> 4) & 3;
  short8 af[8];
#pragma unroll
  for (int et = 0; et < 8; ++et)
    af[et] = *(const short8*)(ewbf + (et * 16 + ln) * 32 + q * 8);
#pragma unroll
  for (int pass = 0; pass < 4; ++pass) {
    int t = pass * 64 + wv * 16 + ln;
    int l0 = t * 8 - 4;
    short8 bfrag;
#pragma unroll
    for (int j = 0; j < 8; ++j) {
      int k = q * 8 + j;
      int l = l0 + k;
      float v = (k < 16 && l >= 0 && l < LL) ? xs[l] : 0.0f;
      bfrag[j] = (short)f2b(v);
    }
    float4v acc[8];
#pragma unroll
    for (int et = 0; et < 8; ++et) {
      acc[et] = (float4v){0.f, 0.f, 0.f, 0.f};
      acc[et] = __builtin_amdgcn_mfma_f32_16x16x32_bf16(af[et], bfrag, acc[et], 0, 0, 0);
    }
    unsigned short* orow = xe + (size_t)sig * 32768 + (size_t)t * 128;
#pragma unroll
    for (int et = 0; et < 8; ++et) {
      int e = et * 16 + q * 4;
      float4 pb = *(const float4*)&eb[e];
      short4v st = {(short)f2b(acc[et][0] + pb.x), (short)f2b(acc[et][1] + pb.y),
                    (short)f2b(acc[et][2] + pb.z), (short)f2b(acc[et][3] + pb.w)};
      *(short4v*)(orow + e) = st;
    }
  }
}

// ---------------- MEGA block stage: all 3 layers + SE, signal resident in LDS ----------------
// grid 768 x 512 threads; dynamic LDS 78464 B (round-6 verified 170us structure)
__global__ __launch_bounds__(512) void k_mega(const unsigned short* __restrict__ u0,
                                              const float* __restrict__ dww, const float* __restrict__ dwb,
                                              const unsigned short* __restrict__ pwbf,
                                              const float* __restrict__ pwb,
                                              const float* __restrict__ w1, const float* __restrict__ b1,
                                              const float* __restrict__ w2, const float* __restrict__ b2,
                                              unsigned short* __restrict__ uout) {
  extern __shared__ char smemraw[];
  unsigned short* us = (unsigned short*)smemraw;
  float* dwT  = (float*)(smemraw + 69632);
  float* dwbL = dwT + 640;
  float* pwbL = dwbL + 128;
  float* sred = pwbL + 128;
  float* smv  = sred + 1024;
  float* hh   = smv + 128;
  float* aL   = hh + 32;

  int sig = blockIdx.x;
  int tid = threadIdx.x;
  const size_t gbase = (size_t)sig * 32768;
  int cu = tid & 15;
  int r0 = tid >> 4;   // 0..31

#pragma unroll
  for (int p = 0; p < 8; ++p) {
    int t = p * 32 + r0;
    short8 v = *(const short8*)(u0 + gbase + (size_t)t * 128 + cu * 8);
    *(short8*)(us + t * 136 + cu * 8) = v;
  }

  int wv = tid >> 6;
  int ln = tid & 15;
  int q  = (tid >> 4) & 3;
  int tb = wv * 32;

  for (int layer = 0; layer < 3; ++layer) {
    __syncthreads();
    for (int i = tid; i < 640; i += 512) dwT[(i % 5) * 128 + (i / 5)] = dww[layer * 640 + i];
    if (tid < 128) { dwbL[tid] = dwb[layer * 128 + tid]; pwbL[tid] = pwb[layer * 128 + tid]; }
    __syncthreads();

    const unsigned short* pwL = pwbf + layer * 16384;
    float4v acc[2][8];
#pragma unroll
    for (int tl = 0; tl < 2; ++tl)
#pragma unroll
      for (int et = 0; et < 8; ++et) acc[tl][et] = (float4v){0.f, 0.f, 0.f, 0.f};

#pragma unroll
    for (int kc = 0; kc < 4; ++kc) {
      int dc = kc * 32 + q * 8;
      short8 af[8];
#pragma unroll
      for (int et = 0; et < 8; ++et)
        af[et] = *(const short8*)(pwL + (size_t)(et * 16 + ln) * 128 + dc);
      float wt[5][8], bl8[8];
#pragma unroll
      for (int k = 0; k < 5; ++k) {
        float4 wa = *(const float4*)&dwT[k * 128 + dc];
        float4 wb = *(const float4*)&dwT[k * 128 + dc + 4];
        wt[k][0] = wa.x; wt[k][1] = wa.y; wt[k][2] = wa.z; wt[k][3] = wa.w;
        wt[k][4] = wb.x; wt[k][5] = wb.y; wt[k][6] = wb.z; wt[k][7] = wb.w;
      }
      {
        float4 ba = *(const float4*)&dwbL[dc];
        float4 bb2 = *(const float4*)&dwbL[dc + 4];
        bl8[0] = ba.x; bl8[1] = ba.y; bl8[2] = ba.z; bl8[3] = ba.w;
        bl8[4] = bb2.x; bl8[5] = bb2.y; bl8[6] = bb2.z; bl8[7] = bb2.w;
      }
#pragma unroll
      for (int tl = 0; tl < 2; ++tl) {
        int t = tb + tl * 16 + ln;
        float a8[8];
#pragma unroll
        for (int j = 0; j < 8; ++j) a8[j] = bl8[j];
#pragma unroll
        for (int k = 0; k < 5; ++k) {
          int tt = t - 2 + k;
          if (tt >= 0 && tt < 256) {
            short8 u8 = *(const short8*)(us + tt * 136 + dc);
#pragma unroll
            for (int j = 0; j < 8; ++j) a8[j] += b2f((unsigned short)u8[j]) * wt[k][j];
          }
        }
        short8 bf;
#pragma unroll
        for (int j = 0; j < 8; ++j)
          bf[j] = (short)f2b(fast_gelu(a8[j]));
#pragma unroll
        for (int et = 0; et < 8; ++et)
          acc[tl][et] = __builtin_amdgcn_mfma_f32_16x16x32_bf16(af[et], bf, acc[tl][et], 0, 0, 0);
      }
    }
    __syncthreads();   // all us reads done; sred free

    // SE t-partial sums -> sred
#pragma unroll
    for (int et = 0; et < 8; ++et) {
      int e = et * 16 + q * 4;
      float4 pb = *(const float4*)&pwbL[e];
      float sv0 = acc[0][et][0] + acc[1][et][0] + 2.0f * pb.x;
      float sv1 = acc[0][et][1] + acc[1][et][1] + 2.0f * pb.y;
      float sv2 = acc[0][et][2] + acc[1][et][2] + 2.0f * pb.z;
      float sv3 = acc[0][et][3] + acc[1][et][3] + 2.0f * pb.w;
#pragma unroll
      for (int m = 1; m <= 8; m <<= 1) {
        sv0 += __shfl_xor(sv0, m, 64);
        sv1 += __shfl_xor(sv1, m, 64);
        sv2 += __shfl_xor(sv2, m, 64);
        sv3 += __shfl_xor(sv3, m, 64);
      }
      if (ln == 0) {
        float4 sv = {sv0, sv1, sv2, sv3};
        *(float4*)&sred[wv * 128 + e] = sv;
      }
    }
    __syncthreads();
    if (tid < 128) {
      float s = 0.f;
#pragma unroll
      for (int w = 0; w < 8; ++w) s += sred[w * 128 + tid];
      smv[tid] = s * (1.0f / 256.0f);
    }
    __syncthreads();
    // SE hidden layer: 256 threads, 8 lanes per output, shuffle-reduce
    if (tid < 256) {
      int o = tid >> 3, part = tid & 7;
      const float* wr = w1 + layer * 4096 + o * 128 + part * 16;
      const float* sv = smv + part * 16;
      float s = 0.f;
#pragma unroll
      for (int j = 0; j < 16; j += 4) {
        float4 w4 = *(const float4*)(wr + j);
        float4 v4 = *(const float4*)(sv + j);
        s += w4.x * v4.x + w4.y * v4.y + w4.z * v4.z + w4.w * v4.w;
      }
      s += __shfl_xor(s, 1, 64);
      s += __shfl_xor(s, 2, 64);
      s += __shfl_xor(s, 4, 64);
      if (part == 0) hh[o] = fmaxf(s + b1[layer * 32 + o], 0.0f);
    }
    __syncthreads();
    // SE gate: all 512 threads, 4 lanes per output
    {
      int o = tid >> 2, part = tid & 3;
      const float* wr = w2 + layer * 4096 + o * 32 + part * 8;
      float s = 0.f;
#pragma unroll
      for (int j = 0; j < 8; j += 4) {
        float4 w4 = *(const float4*)(wr + j);
        float4 h4 = *(const float4*)(hh + part * 8 + j);
        s += w4.x * h4.x + w4.y * h4.y + w4.z * h4.z + w4.w * h4.w;
      }
      s += __shfl_xor(s, 1, 64);
      s += __shfl_xor(s, 2, 64);
      if (part == 0) aL[o] = 1.0f / (1.0f + __expf(-(s + b2[layer * 128 + o])));
    }
    __syncthreads();

    // u += w * a  (in LDS, disjoint per lane)
#pragma unroll
    for (int tl = 0; tl < 2; ++tl) {
      int t = tb + tl * 16 + ln;
#pragma unroll
      for (int et = 0; et < 8; ++et) {
        int e = et * 16 + q * 4;
        float4 pb = *(const float4*)&pwbL[e];
        float4 ga = *(const float4*)&aL[e];
        short4v u4 = *(short4v*)(us + t * 136 + e);
        short4v r;
        r[0] = (short)f2b(b2f((unsigned short)u4[0]) + (acc[tl][et][0] + pb.x) * ga.x);
        r[1] = (short)f2b(b2f((unsigned short)u4[1]) + (acc[tl][et][1] + pb.y) * ga.y);
        r[2] = (short)f2b(b2f((unsigned short)u4[2]) + (acc[tl][et][2] + pb.z) * ga.z);
        r[3] = (short)f2b(b2f((unsigned short)u4[3]) + (acc[tl][et][3] + pb.w) * ga.w);
        *(short4v*)(us + t * 136 + e) = r;
      }
    }
  }
  __syncthreads();
#pragma unroll
  for (int p = 0; p < 8; ++p) {
    int t = p * 32 + r0;
    short8 v = *(short8*)(us + t * 136 + cu * 8);
    *(short8*)(uout + gbase + (size_t)t * 128 + cu * 8) = v;
  }
}

// ---------------- mean over M -> xe2bf bf16 (residual stream is bf16-only) ----------------
__global__ __launch_bounds__(256) void k_reduce2(const unsigned short* __restrict__ u,
                                                 unsigned short* __restrict__ xe2bf) {
  int i = blockIdx.x * 256 + threadIdx.x;
  int d0 = (i & 15) * 8;
  int t = (i >> 4) & 255;
  int b = i >> 12;
  float acc[8] = {0.f, 0.f, 0.f, 0.f, 0.f, 0.f, 0.f, 0.f};
#pragma unroll 4
  for (int m = 0; m < 12; ++m) {
    size_t base = ((size_t)(b * 12 + m) * 256 + t) * 128 + d0;
    short8 u8 = *(const short8*)(u + base);
#pragma unroll
    for (int j = 0; j < 8; ++j) acc[j] += b2f((unsigned short)u8[j]);
  }
  size_t off = (size_t)b * 32768 + (size_t)t * 128 + d0;
  short8 ob;
#pragma unroll
  for (int j = 0; j < 8; ++j) ob[j] = (short)f2b(acc[j] / 12.f);
  *(short8*)(xe2bf + off) = ob;
}

// ---------------- mamba: in-projection via MFMA, zero-LDS -> bf16 xz[t][e] ----------------
__global__ __launch_bounds__(256) void k_inproj(const unsigned short* __restrict__ xe2bf,
                                                const unsigned short* __restrict__ inwbf,
                                                unsigned short* __restrict__ xz) {
  int blk = blockIdx.x;
  int b = blk >> 3;
  int tt = (blk >> 1) & 3;
  int eh = blk & 1;
  int t0 = tt * 64, e0 = eh * 256;
  int tid = threadIdx.x;
  int wv = tid >> 6, ln = tid & 15, q = (tid >> 4) & 3;
  int t = t0 + wv * 16 + ln;
  const unsigned short* xrow = xe2bf + ((size_t)b * 256 + t) * 128 + q * 8;
  short8 bfrag[4];
#pragma unroll
  for (int kc = 0; kc < 4; ++kc) bfrag[kc] = *(const short8*)(xrow + kc * 32);
  float4v acc[16];
#pragma unroll
  for (int et = 0; et < 16; ++et) acc[et] = (float4v){0.f, 0.f, 0.f, 0.f};
#pragma unroll
  for (int et = 0; et < 16; ++et) {
    const unsigned short* arow = inwbf + (size_t)(e0 + et * 16 + ln) * 128 + q * 8;
#pragma unroll
    for (int kc = 0; kc < 4; ++kc) {
      short8 af = *(const short8*)(arow + kc * 32);
      acc[et] = __builtin_amdgcn_mfma_f32_16x16x32_bf16(af, bfrag[kc], acc[et], 0, 0, 0);
    }
  }
  unsigned short* orow = xz + ((size_t)b * 256 + t) * 512 + e0 + q * 4;
#pragma unroll
  for (int et = 0; et < 16; ++et) {
    short4v st = {(short)f2b(acc[et][0]), (short)f2b(acc[et][1]),
                  (short)f2b(acc[et][2]), (short)f2b(acc[et][3])};
    *(short4v*)(orow + et * 16) = st;
  }
}

// ---------------- mamba: fused causal conv+SiLU -> x-projection MFMA; writes xc + dbl ----------------
// 32-row tiles (tq 0..7), 512 blocks -> 2+ blocks/CU (was 1 wave/SIMD at 256 blocks)
__global__ __launch_bounds__(256) void k_xproj(const unsigned short* __restrict__ xz,
                                               const float* __restrict__ cw, const float* __restrict__ cb,
                                               const unsigned short* __restrict__ xwbf,
                                               unsigned short* __restrict__ xcg,
                                               float* __restrict__ dbl) {
  __shared__ unsigned short xis[35 * 264];
  int blk = blockIdx.x;
  int b = blk >> 3;
  int tq = blk & 7;
  int t0 = tq * 32;
  int tid = threadIdx.x;

  const short8 ZV = {0, 0, 0, 0, 0, 0, 0, 0};
  for (int idx = tid; idx < 1120; idx += 256) {
    int row = idx >> 5, cu = idx & 31;
    int t = t0 - 3 + row;
    short8 v = ZV;
    if (t >= 0) v = *(const short8*)(xz + ((size_t)b * 256 + t) * 512 + cu * 8);
    *(short8*)(xis + row * 264 + cu * 8) = v;
  }
  __syncthreads();

  int cu = tid & 31;
  int rb = tid >> 5;
  int c8 = cu * 8;
  float wl[4][8], bl[8];
#pragma unroll
  for (int j = 0; j < 8; ++j) {
    float4 w4 = *(const float4*)&cw[(c8 + j) * 4];
    wl[0][j] = w4.x; wl[1][j] = w4.y; wl[2][j] = w4.z; wl[3][j] = w4.w;
    bl[j] = cb[c8 + j];
  }

  short8 vv[4];
#pragma unroll
  for (int s = 0; s < 4; ++s) {
    int r = rb + s * 8;   // 0..31
    float acc[8];
#pragma unroll
    for (int j = 0; j < 8; ++j) acc[j] = bl[j];
#pragma unroll
    for (int k = 0; k < 4; ++k) {
      short8 u8 = *(const short8*)(xis + (r + k) * 264 + c8);
#pragma unroll
      for (int j = 0; j < 8; ++j) acc[j] += b2f((unsigned short)u8[j]) * wl[k][j];
    }
#pragma unroll
    for (int j = 0; j < 8; ++j)
      vv[s][j] = (short)f2b(acc[j] / (1.0f + __expf(-acc[j])));
    *(short8*)(xcg + ((size_t)b * 256 + t0 + r) * 256 + c8) = vv[s];
  }
  __syncthreads();
#pragma unroll
  for (int s = 0; s < 4; ++s)
    *(short8*)(xis + (rb + s * 8) * 264 + c8) = vv[s];
  __syncthreads();

  // xproj MFMA: 32 rows across wave-pairs; et split across halves
  int wv = tid >> 6, ln = tid & 15, q = (tid >> 4) & 3;
  int tl = (wv & 1) * 16 + ln;    // 0..31
  int eh = wv >> 1;               // 0: et 0,1 ; 1: et 2
  short8 bfrag[8];
#pragma unroll
  for (int kc = 0; kc < 8; ++kc)
    bfrag[kc] = *(const short8*)(xis + tl * 264 + kc * 32 + q * 8);
  float* drow = dbl + ((size_t)b * 256 + t0 + tl) * 40;
  if (eh == 0) {
    float4v acc[2];
    acc[0] = (float4v){0.f, 0.f, 0.f, 0.f};
    acc[1] = (float4v){0.f, 0.f, 0.f, 0.f};
#pragma unroll
    for (int et = 0; et < 2; ++et) {
      const unsigned short* arow = xwbf + (size_t)(et * 16 + ln) * 256 + q * 8;
#pragma unroll
      for (int kc = 0; kc < 8; ++kc) {
        short8 af = *(const short8*)(arow + kc * 32);
        acc[et] = __builtin_amdgcn_mfma_f32_16x16x32_bf16(af, bfrag[kc], acc[et], 0, 0, 0);
      }
    }
#pragma unroll
    for (int et = 0; et < 2; ++et)
#pragma unroll
      for (int r = 0; r < 4; ++r)
        drow[et * 16 + q * 4 + r] = acc[et][r];
  } else {
    float4v acc = (float4v){0.f, 0.f, 0.f, 0.f};
    const unsigned short* arow = xwbf + (size_t)(2 * 16 + ln) * 256 + q * 8;
#pragma unroll
    for (int kc = 0; kc < 8; ++kc) {
      short8 af = *(const short8*)(arow + kc * 32);
      acc = __builtin_amdgcn_mfma_f32_16x16x32_bf16(af, bfrag[kc], acc, 0, 0, 0);
    }
#pragma unroll
    for (int r = 0; r < 4; ++r) {
      int k = 32 + q * 4 + r;
      if (k < 40) drow[k] = acc[r];
    }
  }
}

// ---------------- mamba: fused dt + selective scan + y-finalize ----------------
// 256 threads; serial scan 2 states/thread across ALL 256 threads
__global__ __launch_bounds__(256) void k_scan2(const float* __restrict__ dbl,
                                               const unsigned short* __restrict__ xc,
                                               const unsigned short* __restrict__ xz,
                                               const float* __restrict__ Alog,
                                               const float* __restrict__ dtw, const float* __restrict__ dtbv,
                                               const float* __restrict__ Dp, unsigned short* __restrict__ y) {
  __shared__ float ds[32][40];
  __shared__ float dxs[32][32][4];
  __shared__ float yl[32][32];
  __shared__ float dtwL[32][8];
  __shared__ float dtbL[32];
  __shared__ float DpL[32];

  int b = blockIdx.x >> 3;
  int c0 = (blockIdx.x & 7) * 32;
  int tid = threadIdx.x;

  for (int idx = tid; idx < 256; idx += 256) dtwL[idx >> 3][idx & 7] = dtw[(c0 + (idx >> 3)) * 8 + (idx & 7)];
  if (tid < 32) { dtbL[tid] = dtbv[c0 + tid]; DpL[tid] = Dp[c0 + tid]; }

  int c_loc = tid >> 3;          // 0..31
  int c = c0 + c_loc;
  int sblk = (tid & 7) * 2;      // 0,2,..,14

  float2 Al = *(const float2*)&Alog[c * 16 + sblk];
  float A0 = -__expf(Al.x), A1 = -__expf(Al.y);
  float h0 = 0.f, h1 = 0.f;

  const float* dbp = dbl + (size_t)b * 10240;
  const unsigned short* xcp = xc + (size_t)b * 65536;
  const unsigned short* xzp = xz + (size_t)b * 131072;
  unsigned short* yp = y + (size_t)b * 65536;

  for (int chk = 0; chk < 8; ++chk) {
    int t0c = chk * 32;
    for (int idx = tid; idx < 1280; idx += 256) ((float*)ds)[idx] = dbp[t0c * 40 + idx];
    for (int idx = tid; idx < 512; idx += 256) {
      int t = idx >> 4, cc2 = (idx & 15) * 2;
      ushort2 xv = *(const ushort2*)&xcp[(size_t)(t0c + t) * 256 + c0 + cc2];
      ushort2 zv = *(const ushort2*)&xzp[(size_t)(t0c + t) * 512 + 256 + c0 + cc2];
      dxs[t][cc2][1] = b2f(xv.x);
      dxs[t][cc2 + 1][1] = b2f(xv.y);
      dxs[t][cc2][2] = b2f(zv.x);
      dxs[t][cc2 + 1][2] = b2f(zv.y);
    }
    __syncthreads();
    for (int idx = tid; idx < 1024; idx += 256) {
      int t = idx >> 5, cc = idx & 31;
      const float* dr = ds[t];
      const float* wr = dtwL[cc];
      float acc = dtbL[cc];
#pragma unroll
      for (int j = 0; j < 8; ++j) acc += wr[j] * dr[j];
      dxs[t][cc][0] = (acc > 20.0f) ? acc : __logf(1.0f + __expf(acc));
    }
    __syncthreads();
#pragma unroll 4
    for (int t = 0; t < 32; ++t) {
      float2 dx = *(const float2*)&dxs[t][c_loc][0];
      float2 Bv = *(const float2*)&ds[t][8 + sblk];
      float2 Cv = *(const float2*)&ds[t][24 + sblk];
      float dtv = dx.x;
      float bx = dtv * dx.y;
      h0 = __expf(dtv * A0) * h0 + Bv.x * bx;
      h1 = __expf(dtv * A1) * h1 + Bv.y * bx;
      float p = h0 * Cv.x;
      p = fmaf(h1, Cv.y, p);
      p += qxor1(p);
      p += qxor2(p);
      p += __shfl_xor(p, 4, 64);
      if ((tid & 7) == 0) yl[t][c_loc] = p;
    }
    __syncthreads();
    for (int idx = tid; idx < 512; idx += 256) {
      int t = idx >> 4, cc2 = (idx & 15) * 2;
      float p0 = yl[t][cc2], p1 = yl[t][cc2 + 1];
      float x0 = dxs[t][cc2][1], x1 = dxs[t][cc2 + 1][1];
      float z0 = dxs[t][cc2][2], z1 = dxs[t][cc2 + 1][2];
      float s0 = z0 / (1.0f + __expf(-z0));
      float s1 = z1 / (1.0f + __expf(-z1));
      ushort2 o = {f2b((p0 + DpL[cc2] * x0) * s0), f2b((p1 + DpL[cc2 + 1] * x1) * s1)};
      *(ushort2*)&yp[(size_t)(t0c + t) * 256 + c0 + cc2] = o;
    }
    __syncthreads();
  }
}

// ---------------- mamba: MFMA out-projection + residual(bf16) + LayerNorm ----------------
// 256 threads (was 128): waves split rows (wv&1) x et-halves (wv>>1); LN sums
// combined across et-halves via LDS -> 8 waves/CU (was 4)
__global__ __launch_bounds__(256) void k_outln(const unsigned short* __restrict__ yb,
                                               const unsigned short* __restrict__ owbf,
                                               unsigned short* __restrict__ xe2bf,
                                               const float* __restrict__ g, const float* __restrict__ bb) {
  __shared__ float sp1[2][32];
  __shared__ float sp2[2][32];
  int blk = blockIdx.x;
  int b = blk >> 3;
  int t0 = (blk & 7) * 32;
  int tid = threadIdx.x;
  int wv = tid >> 6, ln = tid & 15, q = (tid >> 4) & 3;
  int rh = wv & 1;
  int eh = wv >> 1;
  int trow = rh * 16 + ln;        // 0..31 local row
  int t = t0 + trow;

  const unsigned short* yrow = yb + ((size_t)b * 256 + t) * 256 + q * 8;
  short8 bfrag[8];
#pragma unroll
  for (int kc = 0; kc < 8; ++kc) bfrag[kc] = *(const short8*)(yrow + kc * 32);

  float4v acc[4];
#pragma unroll
  for (int e2 = 0; e2 < 4; ++e2) {
    int et = eh * 4 + e2;
    acc[e2] = (float4v){0.f, 0.f, 0.f, 0.f};
    const unsigned short* arow = owbf + (size_t)(et * 16 + ln) * 256 + q * 8;
#pragma unroll
    for (int kc = 0; kc < 8; ++kc) {
      short8 af = *(const short8*)(arow + kc * 32);
      acc[e2] = __builtin_amdgcn_mfma_f32_16x16x32_bf16(af, bfrag[kc], acc[e2], 0, 0, 0);
    }
  }

  unsigned short* xrow = xe2bf + ((size_t)b * 256 + t) * 128;
  float vals[4][4];
  float s1 = 0.f, s2 = 0.f;
#pragma unroll
  for (int e2 = 0; e2 < 4; ++e2) {
    int d = (eh * 4 + e2) * 16 + q * 4;
    short4v res = *(const short4v*)(xrow + d);
#pragma unroll
    for (int r = 0; r < 4; ++r) {
      float v = acc[e2][r] + b2f((unsigned short)res[r]);
      vals[e2][r] = v;
      s1 += v;
      s2 += v * v;
    }
  }
  // reduce across q within wave
  s1 += __shfl_xor(s1, 16, 64);
  s1 += __shfl_xor(s1, 32, 64);
  s2 += __shfl_xor(s2, 16, 64);
  s2 += __shfl_xor(s2, 32, 64);
  if ((tid & 63) < 16) { sp1[eh][trow] = s1; sp2[eh][trow] = s2; }
  __syncthreads();
  float S1 = sp1[0][trow] + sp1[1][trow];
  float S2 = sp2[0][trow] + sp2[1][trow];
  float mu = S1 * (1.0f / 128.0f);
  float rs = rsqrtf(S2 * (1.0f / 128.0f) - mu * mu + 1e-5f);

#pragma unroll
  for (int e2 = 0; e2 < 4; ++e2) {
    int d = (eh * 4 + e2) * 16 + q * 4;
    float4 g4 = *(const float4*)(g + d);
    float4 b4 = *(const float4*)(bb + d);
    float o0 = (vals[e2][0] - mu) * rs * g4.x + b4.x;
    float o1 = (vals[e2][1] - mu) * rs * g4.y + b4.y;
    float o2 = (vals[e2][2] - mu) * rs * g4.z + b4.z;
    float o3 = (vals[e2][3] - mu) * rs * g4.w + b4.w;
    short4v ob = {(short)f2b(o0), (short)f2b(o1), (short)f2b(o2), (short)f2b(o3)};
    *(short4v*)(xrow + d) = ob;
  }
}

// ---------------- xflat transpose from bf16 residual (+ pred bias init) ----------------
__global__ __launch_bounds__(256) void k_xflat(const unsigned short* __restrict__ xe2bf,
                                               float* __restrict__ out,
                                               const float* __restrict__ fcb, float* __restrict__ pred) {
  int b = blockIdx.x >> 5;
  int blk = blockIdx.x & 31;
  int t0 = (blk >> 2) * 32, d0 = (blk & 3) * 32;
  __shared__ float tile[32][33];
  int tid = threadIdx.x;
  if (blockIdx.x == 0) {
    for (int i = tid; i < 1152; i += 256) pred[i] = fcb[i % 18];
  }
#pragma unroll
  for (int q = 0; q < 4; ++q) {
    int t = (tid >> 5) + q * 8, dd = tid & 31;
    tile[t][dd] = b2f(xe2bf[(size_t)b * 32768 + (size_t)(t0 + t) * 128 + d0 + dd]);
  }
  __syncthreads();
#pragma unroll
  for (int q = 0; q < 4; ++q) {
    int dd = (tid >> 5) + q * 8, t = tid & 31;
    float v = tile[t][dd];
    size_t o = (size_t)b * 32768 + (size_t)(d0 + dd) * 256 + t0 + t;
    out[o] = v;
  }
}

// ---------------- final FC via MFMA: consumes xe2bf directly (fwbf is t-major permuted) ----------------
__global__ __launch_bounds__(256) void k_fc(const unsigned short* __restrict__ xe2bf,
                                            const unsigned short* __restrict__ fwbf,
                                            float* __restrict__ pred) {
  int kb = blockIdx.x;
  int k0 = kb * 256;
  int tid = threadIdx.x;
  int wv = tid >> 6, ln = tid & 15, q = (tid >> 4) & 3;
  int b = wv * 16 + ln;
  const unsigned short* xrow = xe2bf + (size_t)b * 32768 + k0 + q * 8;
  float4v acc[2];
  acc[0] = (float4v){0.f, 0.f, 0.f, 0.f};
  acc[1] = (float4v){0.f, 0.f, 0.f, 0.f};
#pragma unroll
  for (int kc = 0; kc < 8; ++kc) {
    short8 bfrag = *(const short8*)(xrow + kc * 32);
#pragma unroll
    for (int et = 0; et < 2; ++et) {
      short8 af = *(const short8*)(fwbf + (size_t)(et * 16 + ln) * 32768 + k0 + kc * 32 + q * 8);
      acc[et] = __builtin_amdgcn_mfma_f32_16x16x32_bf16(af, bfrag, acc[et], 0, 0, 0);
    }
  }
#pragma unroll
  for (int et = 0; et < 2; ++et)
#pragma unroll
    for (int r = 0; r < 4; ++r) {
      int c = et * 16 + q * 4 + r;
      if (c < 18) atomicAdd(&pred[b * 18 + c], acc[et][r]);
    }
}

extern "C" void kernel_launch(void* const* d_in, const int* in_sizes, int n_in,
                              void* d_out, int out_size, void* d_ws, size_t ws_size,
                              hipStream_t stream) {
  (void)in_sizes; (void)n_in; (void)out_size; (void)ws_size;
  const float* inp    = (const float*)d_in[0];
  const float* emb_w  = (const float*)d_in[1];
  const float* emb_b  = (const float*)d_in[2];
  const float* dw_w   = (const float*)d_in[3];
  const float* dw_b   = (const float*)d_in[4];
  const float* pw_w   = (const float*)d_in[5];
  const float* pw_b   = (const float*)d_in[6];
  const float* se_w1  = (const float*)d_in[7];
  const float* se_b1  = (const float*)d_in[8];
  const float* se_w2  = (const float*)d_in[9];
  const float* se_b2  = (const float*)d_in[10];
  const float* in_w   = (const float*)d_in[11];
  const float* conv_w = (const float*)d_in[12];
  const float* conv_b = (const float*)d_in[13];
  const float* xp_w   = (const float*)d_in[14];
  const float* dt_w   = (const float*)d_in[15];
  const float* dt_b   = (const float*)d_in[16];
  const float* Alog   = (const float*)d_in[17];
  const float* Dp     = (const float*)d_in[18];
  const float* out_w  = (const float*)d_in[19];
  const float* ln_g   = (const float*)d_in[20];
  const float* ln_b   = (const float*)d_in[21];
  const float* fc_w   = (const float*)d_in[22];
  const float* fc_b   = (const float*)d_in[23];

  char* ws = (char*)d_ws;
  unsigned short* U0 = (unsigned short*)(ws);
  unsigned short* xz = (unsigned short*)(ws);                 // after reduce2
  unsigned short* xc = (unsigned short*)(ws + 33554432);
  unsigned short* yb = (unsigned short*)(ws + 50331648);
  unsigned short* fwbf = (unsigned short*)(ws + 113246208);
  float* dbl = (float*)(ws + 150994944);
  unsigned short* xe2bf = (unsigned short*)(ws + 153616384);

  float* xflat = (float*)d_out;
  float* pred  = xflat + (size_t)64 * 32768;
  unsigned short* pwbf  = (unsigned short*)d_out;   // weight scratch until k_xflat
  unsigned short* inwbf = pwbf + 49152;
  unsigned short* owbf  = inwbf + 131072;
  unsigned short* xwbf  = owbf + 65536;
  unsigned short* ewbf  = xwbf + 24576;

  hipFuncSetAttribute((const void*)k_mega, hipFuncAttributeMaxDynamicSharedMemorySize, MEGA_LDS);

  k_cvt<<<5168, 256, 0, stream>>>(pw_w, in_w, out_w, xp_w, emb_w, fc_w, pwbf, fwbf);
  k_emb<<<768, 256, 0, stream>>>(inp, ewbf, emb_b, U0);

  k_mega<<<768, 512, MEGA_LDS, stream>>>(U0, dw_w, dw_b, pwbf, pw_b,
                                         se_w1, se_b1, se_w2, se_b2, U0);

  k_reduce2<<<1024, 256, 0, stream>>>(U0, xe2bf);

  for (int i = 0; i < 2; ++i) {
    k_inproj<<<512, 256, 0, stream>>>(xe2bf, inwbf + i * 65536, xz);
    k_xproj<<<512, 256, 0, stream>>>(xz, conv_w + i * 1024, conv_b + i * 256,
                                     xwbf + i * 12288, xc, dbl);
    k_scan2<<<512, 256, 0, stream>>>(dbl, xc, xz, Alog + i * 4096,
                                     dt_w + i * 2048, dt_b + i * 256, Dp + i * 256, yb);
    k_outln<<<512, 256, 0, stream>>>(yb, owbf + i * 32768, xe2bf,
                                     ln_g + i * 128, ln_b + i * 128);
  }

  k_xflat<<<2048, 256, 0, stream>>>(xe2bf, xflat, fc_b, pred);
  k_fc<<<128, 256, 0, stream>>>(xe2bf, fwbf, pred);
}

// Round 12
// 532.455 us; speedup vs baseline: 1.1651x; 1.0145x over previous
//
#include <hip/hip_runtime.h>
#include <math.h>

#define LL 2048
#define MM 12
#define DD 128
#define TP 256   // T
#define MEGA_LDS 78464

typedef short short8 __attribute__((ext_vector_type(8)));
typedef short short4v __attribute__((ext_vector_type(4)));
typedef float float4v __attribute__((ext_vector_type(4)));

static __device__ __forceinline__ unsigned short f2b(float f) {
  union { float f; unsigned int u; } x; x.f = f;
  unsigned int r = x.u + 0x7fffu + ((x.u >> 16) & 1u);
  return (unsigned short)(r >> 16);
}
static __device__ __forceinline__ float b2f(unsigned short u) {
  union { unsigned int u; float f; } x; x.u = ((unsigned int)u) << 16;
  return x.f;
}
// branch-free erf (A&S 7.1.26, |err| <= ~5e-7): rcp + exp + 5 FMA
static __device__ __forceinline__ float fast_gelu(float x) {
  float xs = x * 0.70710678118654752f;
  float y = fabsf(xs);
  float t = __builtin_amdgcn_rcpf(fmaf(0.3275911f, y, 1.0f));
  float p = fmaf(fmaf(fmaf(fmaf(1.061405429f, t, -1.453152027f), t,
                           1.421413741f), t, -0.284496736f), t, 0.254829592f);
  p = p * t;
  float e = __expf(-y * y);
  float er = fmaf(-p, e, 1.0f);
  er = copysignf(er, xs);
  return 0.5f * x * (1.0f + er);
}
static __device__ __forceinline__ float qxor1(float x) {
  int r = __builtin_amdgcn_mov_dpp(__builtin_bit_cast(int, x), 0xB1, 0xF, 0xF, true);
  return __builtin_bit_cast(float, r);
}
static __device__ __forceinline__ float qxor2(float x) {
  int r = __builtin_amdgcn_mov_dpp(__builtin_bit_cast(int, x), 0x4E, 0xF, 0xF, true);
  return __builtin_bit_cast(float, r);
}

// ---------------- convert weights to bf16; coalesced fc_w transpose; pred bias init ----------------
// grid 3445x256:
//   [0,1072)    : small weights (linear, 274432 elems)
//   [1072,1648) : fc_w transpose via 32x32 LDS tiles (18m x 4dt x 8tt = 576 tiles)
//   [1648,3440) : fwbf zero-pad for m in [18,32) (458752 elems)
//   [3440,3445) : pred init = fcb
__global__ __launch_bounds__(256) void k_cvt(const float* __restrict__ pw_w, const float* __restrict__ in_w,
                                             const float* __restrict__ out_w, const float* __restrict__ xp_w,
                                             const float* __restrict__ ew, const float* __restrict__ fw,
                                             const float* __restrict__ fcb,
                                             unsigned short* __restrict__ pwbf, unsigned short* __restrict__ fwbf,
                                             float* __restrict__ pred) {
  __shared__ float tile[32][33];
  int blk = blockIdx.x;
  int tid = threadIdx.x;
  if (blk >= 3440) {
    int j2 = (blk - 3440) * 256 + tid;
    if (j2 < 1152) pred[j2] = fcb[j2 % 18];
    return;
  }
  if (blk >= 1648) {
    int j = 589824 + (blk - 1648) * 256 + tid;
    fwbf[j] = 0;
    return;
  }
  if (blk >= 1072) {
    // fc_w transpose tile: fwbf[m][t*128+d] = f2b(fc_w[m][d*256+t]), coalesced both sides
    int rel = blk - 1072;
    int m = rel >> 5;               // 0..17
    int sub = rel & 31;
    int d0 = (sub >> 3) * 32, t0 = (sub & 7) * 32;
#pragma unroll
    for (int q = 0; q < 4; ++q) {
      int dd = (tid >> 5) + q * 8, tt = tid & 31;
      tile[dd][tt] = fw[(size_t)m * 32768 + (size_t)(d0 + dd) * 256 + t0 + tt];
    }
    __syncthreads();
#pragma unroll
    for (int q = 0; q < 4; ++q) {
      int tt = (tid >> 5) + q * 8, dd = tid & 31;
      fwbf[(size_t)m * 32768 + (size_t)(t0 + tt) * 128 + d0 + dd] = f2b(tile[dd][tt]);
    }
    return;
  }
  int i = blk * 256 + tid;
  if (i < 49152) { pwbf[i] = f2b(pw_w[i]); return; }
  int i2 = i - 49152;
  if (i2 < 131072) { pwbf[i] = f2b(in_w[i2]); return; }
  int i3 = i2 - 131072;
  if (i3 < 65536) { pwbf[i] = f2b(out_w[i3]); return; }
  int i4 = i3 - 65536;
  if (i4 < 24576) {
    int layer = (i4 < 12288) ? 0 : 1;
    int rem = i4 - layer * 12288;
    int k = rem >> 8, c = rem & 255;
    float v = (k < 40) ? xp_w[layer * 10240 + k * 256 + c] : 0.0f;
    pwbf[i] = f2b(v);
    return;
  }
  int i5 = i4 - 24576;
  if (i5 < 4096) {
    int d = i5 >> 5, k = i5 & 31;
    float v = (k < 16) ? ew[d * 16 + k] : 0.0f;
    pwbf[i] = f2b(v);
  }
}

// ---------------- embedding via MFMA ----------------
__global__ __launch_bounds__(256) void k_emb(const float* __restrict__ inp,
                                             const unsigned short* __restrict__ ewbf,
                                             const float* __restrict__ eb,
                                             unsigned short* __restrict__ xe) {
  int sig = blockIdx.x;
  int b = sig / MM, m = sig % MM;
  __shared__ float xs[LL];
  const float* ib = inp + (size_t)b * LL * MM + m;
  int tid = threadIdx.x;
  for (int i = tid; i < LL; i += 256) xs[i] = ib[(size_t)i * MM];
  __syncthreads();
  int wv = tid >> 6, ln = tid & 15, q = (tid >> 4) & 3;
  short8 af[8];
#pragma unroll
  for (int et = 0; et < 8; ++et)
    af[et] = *(const short8*)(ewbf + (et * 16 + ln) * 32 + q * 8);
#pragma unroll
  for (int pass = 0; pass < 4; ++pass) {
    int t = pass * 64 + wv * 16 + ln;
    int l0 = t * 8 - 4;
    short8 bfrag;
#pragma unroll
    for (int j = 0; j < 8; ++j) {
      int k = q * 8 + j;
      int l = l0 + k;
      float v = (k < 16 && l >= 0 && l < LL) ? xs[l] : 0.0f;
      bfrag[j] = (short)f2b(v);
    }
    float4v acc[8];
#pragma unroll
    for (int et = 0; et < 8; ++et) {
      acc[et] = (float4v){0.f, 0.f, 0.f, 0.f};
      acc[et] = __builtin_amdgcn_mfma_f32_16x16x32_bf16(af[et], bfrag, acc[et], 0, 0, 0);
    }
    unsigned short* orow = xe + (size_t)sig * 32768 + (size_t)t * 128;
#pragma unroll
    for (int et = 0; et < 8; ++et) {
      int e = et * 16 + q * 4;
      float4 pb = *(const float4*)&eb[e];
      short4v st = {(short)f2b(acc[et][0] + pb.x), (short)f2b(acc[et][1] + pb.y),
                    (short)f2b(acc[et][2] + pb.z), (short)f2b(acc[et][3] + pb.w)};
      *(short4v*)(orow + e) = st;
    }
  }
}

// ---------------- MEGA block stage: all 3 layers + SE, signal resident in LDS ----------------
// grid 768 x 512 threads; dynamic LDS 78464 B (round-6 verified 170us structure)
__global__ __launch_bounds__(512) void k_mega(const unsigned short* __restrict__ u0,
                                              const float* __restrict__ dww, const float* __restrict__ dwb,
                                              const unsigned short* __restrict__ pwbf,
                                              const float* __restrict__ pwb,
                                              const float* __restrict__ w1, const float* __restrict__ b1,
                                              const float* __restrict__ w2, const float* __restrict__ b2,
                                              unsigned short* __restrict__ uout) {
  extern __shared__ char smemraw[];
  unsigned short* us = (unsigned short*)smemraw;
  float* dwT  = (float*)(smemraw + 69632);
  float* dwbL = dwT + 640;
  float* pwbL = dwbL + 128;
  float* sred = pwbL + 128;
  float* smv  = sred + 1024;
  float* hh   = smv + 128;
  float* aL   = hh + 32;

  int sig = blockIdx.x;
  int tid = threadIdx.x;
  const size_t gbase = (size_t)sig * 32768;
  int cu = tid & 15;
  int r0 = tid >> 4;   // 0..31

#pragma unroll
  for (int p = 0; p < 8; ++p) {
    int t = p * 32 + r0;
    short8 v = *(const short8*)(u0 + gbase + (size_t)t * 128 + cu * 8);
    *(short8*)(us + t * 136 + cu * 8) = v;
  }

  int wv = tid >> 6;
  int ln = tid & 15;
  int q  = (tid >> 4) & 3;
  int tb = wv * 32;

  for (int layer = 0; layer < 3; ++layer) {
    __syncthreads();
    for (int i = tid; i < 640; i += 512) dwT[(i % 5) * 128 + (i / 5)] = dww[layer * 640 + i];
    if (tid < 128) { dwbL[tid] = dwb[layer * 128 + tid]; pwbL[tid] = pwb[layer * 128 + tid]; }
    __syncthreads();

    const unsigned short* pwL = pwbf + layer * 16384;
    float4v acc[2][8];
#pragma unroll
    for (int tl = 0; tl < 2; ++tl)
#pragma unroll
      for (int et = 0; et < 8; ++et) acc[tl][et] = (float4v){0.f, 0.f, 0.f, 0.f};

#pragma unroll
    for (int kc = 0; kc < 4; ++kc) {
      int dc = kc * 32 + q * 8;
      short8 af[8];
#pragma unroll
      for (int et = 0; et < 8; ++et)
        af[et] = *(const short8*)(pwL + (size_t)(et * 16 + ln) * 128 + dc);
      float wt[5][8], bl8[8];
#pragma unroll
      for (int k = 0; k < 5; ++k) {
        float4 wa = *(const float4*)&dwT[k * 128 + dc];
        float4 wb = *(const float4*)&dwT[k * 128 + dc + 4];
        wt[k][0] = wa.x; wt[k][1] = wa.y; wt[k][2] = wa.z; wt[k][3] = wa.w;
        wt[k][4] = wb.x; wt[k][5] = wb.y; wt[k][6] = wb.z; wt[k][7] = wb.w;
      }
      {
        float4 ba = *(const float4*)&dwbL[dc];
        float4 bb2 = *(const float4*)&dwbL[dc + 4];
        bl8[0] = ba.x; bl8[1] = ba.y; bl8[2] = ba.z; bl8[3] = ba.w;
        bl8[4] = bb2.x; bl8[5] = bb2.y; bl8[6] = bb2.z; bl8[7] = bb2.w;
      }
#pragma unroll
      for (int tl = 0; tl < 2; ++tl) {
        int t = tb + tl * 16 + ln;
        float a8[8];
#pragma unroll
        for (int j = 0; j < 8; ++j) a8[j] = bl8[j];
#pragma unroll
        for (int k = 0; k < 5; ++k) {
          int tt = t - 2 + k;
          if (tt >= 0 && tt < 256) {
            short8 u8 = *(const short8*)(us + tt * 136 + dc);
#pragma unroll
            for (int j = 0; j < 8; ++j) a8[j] += b2f((unsigned short)u8[j]) * wt[k][j];
          }
        }
        short8 bf;
#pragma unroll
        for (int j = 0; j < 8; ++j)
          bf[j] = (short)f2b(fast_gelu(a8[j]));
#pragma unroll
        for (int et = 0; et < 8; ++et)
          acc[tl][et] = __builtin_amdgcn_mfma_f32_16x16x32_bf16(af[et], bf, acc[tl][et], 0, 0, 0);
      }
    }
    __syncthreads();   // all us reads done; sred free

    // SE t-partial sums -> sred
#pragma unroll
    for (int et = 0; et < 8; ++et) {
      int e = et * 16 + q * 4;
      float4 pb = *(const float4*)&pwbL[e];
      float sv0 = acc[0][et][0] + acc[1][et][0] + 2.0f * pb.x;
      float sv1 = acc[0][et][1] + acc[1][et][1] + 2.0f * pb.y;
      float sv2 = acc[0][et][2] + acc[1][et][2] + 2.0f * pb.z;
      float sv3 = acc[0][et][3] + acc[1][et][3] + 2.0f * pb.w;
#pragma unroll
      for (int m = 1; m <= 8; m <<= 1) {
        sv0 += __shfl_xor(sv0, m, 64);
        sv1 += __shfl_xor(sv1, m, 64);
        sv2 += __shfl_xor(sv2, m, 64);
        sv3 += __shfl_xor(sv3, m, 64);
      }
      if (ln == 0) {
        float4 sv = {sv0, sv1, sv2, sv3};
        *(float4*)&sred[wv * 128 + e] = sv;
      }
    }
    __syncthreads();
    if (tid < 128) {
      float s = 0.f;
#pragma unroll
      for (int w = 0; w < 8; ++w) s += sred[w * 128 + tid];
      smv[tid] = s * (1.0f / 256.0f);
    }
    __syncthreads();
    // SE hidden layer: 256 threads, 8 lanes per output, shuffle-reduce
    if (tid < 256) {
      int o = tid >> 3, part = tid & 7;
      const float* wr = w1 + layer * 4096 + o * 128 + part * 16;
      const float* sv = smv + part * 16;
      float s = 0.f;
#pragma unroll
      for (int j = 0; j < 16; j += 4) {
        float4 w4 = *(const float4*)(wr + j);
        float4 v4 = *(const float4*)(sv + j);
        s += w4.x * v4.x + w4.y * v4.y + w4.z * v4.z + w4.w * v4.w;
      }
      s += __shfl_xor(s, 1, 64);
      s += __shfl_xor(s, 2, 64);
      s += __shfl_xor(s, 4, 64);
      if (part == 0) hh[o] = fmaxf(s + b1[layer * 32 + o], 0.0f);
    }
    __syncthreads();
    // SE gate: all 512 threads, 4 lanes per output
    {
      int o = tid >> 2, part = tid & 3;
      const float* wr = w2 + layer * 4096 + o * 32 + part * 8;
      float s = 0.f;
#pragma unroll
      for (int j = 0; j < 8; j += 4) {
        float4 w4 = *(const float4*)(wr + j);
        float4 h4 = *(const float4*)(hh + part * 8 + j);
        s += w4.x * h4.x + w4.y * h4.y + w4.z * h4.z + w4.w * h4.w;
      }
      s += __shfl_xor(s, 1, 64);
      s += __shfl_xor(s, 2, 64);
      if (part == 0) aL[o] = 1.0f / (1.0f + __expf(-(s + b2[layer * 128 + o])));
    }
    __syncthreads();

    // u += w * a  (in LDS, disjoint per lane)
#pragma unroll
    for (int tl = 0; tl < 2; ++tl) {
      int t = tb + tl * 16 + ln;
#pragma unroll
      for (int et = 0; et < 8; ++et) {
        int e = et * 16 + q * 4;
        float4 pb = *(const float4*)&pwbL[e];
        float4 ga = *(const float4*)&aL[e];
        short4v u4 = *(short4v*)(us + t * 136 + e);
        short4v r;
        r[0] = (short)f2b(b2f((unsigned short)u4[0]) + (acc[tl][et][0] + pb.x) * ga.x);
        r[1] = (short)f2b(b2f((unsigned short)u4[1]) + (acc[tl][et][1] + pb.y) * ga.y);
        r[2] = (short)f2b(b2f((unsigned short)u4[2]) + (acc[tl][et][2] + pb.z) * ga.z);
        r[3] = (short)f2b(b2f((unsigned short)u4[3]) + (acc[tl][et][3] + pb.w) * ga.w);
        *(short4v*)(us + t * 136 + e) = r;
      }
    }
  }
  __syncthreads();
#pragma unroll
  for (int p = 0; p < 8; ++p) {
    int t = p * 32 + r0;
    short8 v = *(short8*)(us + t * 136 + cu * 8);
    *(short8*)(uout + gbase + (size_t)t * 128 + cu * 8) = v;
  }
}

// ---------------- mean over M -> xe2bf bf16 (residual stream is bf16-only) ----------------
__global__ __launch_bounds__(256) void k_reduce2(const unsigned short* __restrict__ u,
                                                 unsigned short* __restrict__ xe2bf) {
  int i = blockIdx.x * 256 + threadIdx.x;
  int d0 = (i & 15) * 8;
  int t = (i >> 4) & 255;
  int b = i >> 12;
  float acc[8] = {0.f, 0.f, 0.f, 0.f, 0.f, 0.f, 0.f, 0.f};
#pragma unroll 4
  for (int m = 0; m < 12; ++m) {
    size_t base = ((size_t)(b * 12 + m) * 256 + t) * 128 + d0;
    short8 u8 = *(const short8*)(u + base);
#pragma unroll
    for (int j = 0; j < 8; ++j) acc[j] += b2f((unsigned short)u8[j]);
  }
  size_t off = (size_t)b * 32768 + (size_t)t * 128 + d0;
  short8 ob;
#pragma unroll
  for (int j = 0; j < 8; ++j) ob[j] = (short)f2b(acc[j] / 12.f);
  *(short8*)(xe2bf + off) = ob;
}

// ---------------- mamba: in-projection via MFMA, zero-LDS -> bf16 xz[t][e] ----------------
__global__ __launch_bounds__(256) void k_inproj(const unsigned short* __restrict__ xe2bf,
                                                const unsigned short* __restrict__ inwbf,
                                                unsigned short* __restrict__ xz) {
  int blk = blockIdx.x;
  int b = blk >> 3;
  int tt = (blk >> 1) & 3;
  int eh = blk & 1;
  int t0 = tt * 64, e0 = eh * 256;
  int tid = threadIdx.x;
  int wv = tid >> 6, ln = tid & 15, q = (tid >> 4) & 3;
  int t = t0 + wv * 16 + ln;
  const unsigned short* xrow = xe2bf + ((size_t)b * 256 + t) * 128 + q * 8;
  short8 bfrag[4];
#pragma unroll
  for (int kc = 0; kc < 4; ++kc) bfrag[kc] = *(const short8*)(xrow + kc * 32);
  float4v acc[16];
#pragma unroll
  for (int et = 0; et < 16; ++et) acc[et] = (float4v){0.f, 0.f, 0.f, 0.f};
#pragma unroll
  for (int et = 0; et < 16; ++et) {
    const unsigned short* arow = inwbf + (size_t)(e0 + et * 16 + ln) * 128 + q * 8;
#pragma unroll
    for (int kc = 0; kc < 4; ++kc) {
      short8 af = *(const short8*)(arow + kc * 32);
      acc[et] = __builtin_amdgcn_mfma_f32_16x16x32_bf16(af, bfrag[kc], acc[et], 0, 0, 0);
    }
  }
  unsigned short* orow = xz + ((size_t)b * 256 + t) * 512 + e0 + q * 4;
#pragma unroll
  for (int et = 0; et < 16; ++et) {
    short4v st = {(short)f2b(acc[et][0]), (short)f2b(acc[et][1]),
                  (short)f2b(acc[et][2]), (short)f2b(acc[et][3])};
    *(short4v*)(orow + et * 16) = st;
  }
}

// ---------------- mamba: fused causal conv+SiLU -> x-projection MFMA; writes xc + dbl ----------------
// 32-row tiles (tq 0..7), 512 blocks -> 2+ blocks/CU
__global__ __launch_bounds__(256) void k_xproj(const unsigned short* __restrict__ xz,
                                               const float* __restrict__ cw, const float* __restrict__ cb,
                                               const unsigned short* __restrict__ xwbf,
                                               unsigned short* __restrict__ xcg,
                                               float* __restrict__ dbl) {
  __shared__ unsigned short xis[35 * 264];
  int blk = blockIdx.x;
  int b = blk >> 3;
  int tq = blk & 7;
  int t0 = tq * 32;
  int tid = threadIdx.x;

  const short8 ZV = {0, 0, 0, 0, 0, 0, 0, 0};
  for (int idx = tid; idx < 1120; idx += 256) {
    int row = idx >> 5, cu = idx & 31;
    int t = t0 - 3 + row;
    short8 v = ZV;
    if (t >= 0) v = *(const short8*)(xz + ((size_t)b * 256 + t) * 512 + cu * 8);
    *(short8*)(xis + row * 264 + cu * 8) = v;
  }
  __syncthreads();

  int cu = tid & 31;
  int rb = tid >> 5;
  int c8 = cu * 8;
  float wl[4][8], bl[8];
#pragma unroll
  for (int j = 0; j < 8; ++j) {
    float4 w4 = *(const float4*)&cw[(c8 + j) * 4];
    wl[0][j] = w4.x; wl[1][j] = w4.y; wl[2][j] = w4.z; wl[3][j] = w4.w;
    bl[j] = cb[c8 + j];
  }

  short8 vv[4];
#pragma unroll
  for (int s = 0; s < 4; ++s) {
    int r = rb + s * 8;   // 0..31
    float acc[8];
#pragma unroll
    for (int j = 0; j < 8; ++j) acc[j] = bl[j];
#pragma unroll
    for (int k = 0; k < 4; ++k) {
      short8 u8 = *(const short8*)(xis + (r + k) * 264 + c8);
#pragma unroll
      for (int j = 0; j < 8; ++j) acc[j] += b2f((unsigned short)u8[j]) * wl[k][j];
    }
#pragma unroll
    for (int j = 0; j < 8; ++j)
      vv[s][j] = (short)f2b(acc[j] / (1.0f + __expf(-acc[j])));
    *(short8*)(xcg + ((size_t)b * 256 + t0 + r) * 256 + c8) = vv[s];
  }
  __syncthreads();
#pragma unroll
  for (int s = 0; s < 4; ++s)
    *(short8*)(xis + (rb + s * 8) * 264 + c8) = vv[s];
  __syncthreads();

  // xproj MFMA: 32 rows across wave-pairs; et split across halves
  int wv = tid >> 6, ln = tid & 15, q = (tid >> 4) & 3;
  int tl = (wv & 1) * 16 + ln;    // 0..31
  int eh = wv >> 1;               // 0: et 0,1 ; 1: et 2
  short8 bfrag[8];
#pragma unroll
  for (int kc = 0; kc < 8; ++kc)
    bfrag[kc] = *(const short8*)(xis + tl * 264 + kc * 32 + q * 8);
  float* drow = dbl + ((size_t)b * 256 + t0 + tl) * 40;
  if (eh == 0) {
    float4v acc[2];
    acc[0] = (float4v){0.f, 0.f, 0.f, 0.f};
    acc[1] = (float4v){0.f, 0.f, 0.f, 0.f};
#pragma unroll
    for (int et = 0; et < 2; ++et) {
      const unsigned short* arow = xwbf + (size_t)(et * 16 + ln) * 256 + q * 8;
#pragma unroll
      for (int kc = 0; kc < 8; ++kc) {
        short8 af = *(const short8*)(arow + kc * 32);
        acc[et] = __builtin_amdgcn_mfma_f32_16x16x32_bf16(af, bfrag[kc], acc[et], 0, 0, 0);
      }
    }
#pragma unroll
    for (int et = 0; et < 2; ++et)
#pragma unroll
      for (int r = 0; r < 4; ++r)
        drow[et * 16 + q * 4 + r] = acc[et][r];
  } else {
    float4v acc = (float4v){0.f, 0.f, 0.f, 0.f};
    const unsigned short* arow = xwbf + (size_t)(2 * 16 + ln) * 256 + q * 8;
#pragma unroll
    for (int kc = 0; kc < 8; ++kc) {
      short8 af = *(const short8*)(arow + kc * 32);
      acc = __builtin_amdgcn_mfma_f32_16x16x32_bf16(af, bfrag[kc], acc, 0, 0, 0);
    }
#pragma unroll
    for (int r = 0; r < 4; ++r) {
      int k = 32 + q * 4 + r;
      if (k < 40) drow[k] = acc[r];
    }
  }
}

// ---------------- mamba: fused dt + selective scan + y-finalize ----------------
// 256 threads; serial scan 2 states/thread across ALL 256 threads
__global__ __launch_bounds__(256) void k_scan2(const float* __restrict__ dbl,
                                               const unsigned short* __restrict__ xc,
                                               const unsigned short* __restrict__ xz,
                                               const float* __restrict__ Alog,
                                               const float* __restrict__ dtw, const float* __restrict__ dtbv,
                                               const float* __restrict__ Dp, unsigned short* __restrict__ y) {
  __shared__ float ds[32][40];
  __shared__ float dxs[32][32][4];
  __shared__ float yl[32][32];
  __shared__ float dtwL[32][8];
  __shared__ float dtbL[32];
  __shared__ float DpL[32];

  int b = blockIdx.x >> 3;
  int c0 = (blockIdx.x & 7) * 32;
  int tid = threadIdx.x;

  for (int idx = tid; idx < 256; idx += 256) dtwL[idx >> 3][idx & 7] = dtw[(c0 + (idx >> 3)) * 8 + (idx & 7)];
  if (tid < 32) { dtbL[tid] = dtbv[c0 + tid]; DpL[tid] = Dp[c0 + tid]; }

  int c_loc = tid >> 3;          // 0..31
  int c = c0 + c_loc;
  int sblk = (tid & 7) * 2;      // 0,2,..,14

  float2 Al = *(const float2*)&Alog[c * 16 + sblk];
  float A0 = -__expf(Al.x), A1 = -__expf(Al.y);
  float h0 = 0.f, h1 = 0.f;

  const float* dbp = dbl + (size_t)b * 10240;
  const unsigned short* xcp = xc + (size_t)b * 65536;
  const unsigned short* xzp = xz + (size_t)b * 131072;
  unsigned short* yp = y + (size_t)b * 65536;

  for (int chk = 0; chk < 8; ++chk) {
    int t0c = chk * 32;
    for (int idx = tid; idx < 1280; idx += 256) ((float*)ds)[idx] = dbp[t0c * 40 + idx];
    for (int idx = tid; idx < 512; idx += 256) {
      int t = idx >> 4, cc2 = (idx & 15) * 2;
      ushort2 xv = *(const ushort2*)&xcp[(size_t)(t0c + t) * 256 + c0 + cc2];
      ushort2 zv = *(const ushort2*)&xzp[(size_t)(t0c + t) * 512 + 256 + c0 + cc2];
      dxs[t][cc2][1] = b2f(xv.x);
      dxs[t][cc2 + 1][1] = b2f(xv.y);
      dxs[t][cc2][2] = b2f(zv.x);
      dxs[t][cc2 + 1][2] = b2f(zv.y);
    }
    __syncthreads();
    for (int idx = tid; idx < 1024; idx += 256) {
      int t = idx >> 5, cc = idx & 31;
      const float* dr = ds[t];
      const float* wr = dtwL[cc];
      float acc = dtbL[cc];
#pragma unroll
      for (int j = 0; j < 8; ++j) acc += wr[j] * dr[j];
      dxs[t][cc][0] = (acc > 20.0f) ? acc : __logf(1.0f + __expf(acc));
    }
    __syncthreads();
#pragma unroll 4
    for (int t = 0; t < 32; ++t) {
      float2 dx = *(const float2*)&dxs[t][c_loc][0];
      float2 Bv = *(const float2*)&ds[t][8 + sblk];
      float2 Cv = *(const float2*)&ds[t][24 + sblk];
      float dtv = dx.x;
      float bx = dtv * dx.y;
      h0 = __expf(dtv * A0) * h0 + Bv.x * bx;
      h1 = __expf(dtv * A1) * h1 + Bv.y * bx;
      float p = h0 * Cv.x;
      p = fmaf(h1, Cv.y, p);
      p += qxor1(p);
      p += qxor2(p);
      p += __shfl_xor(p, 4, 64);
      if ((tid & 7) == 0) yl[t][c_loc] = p;
    }
    __syncthreads();
    for (int idx = tid; idx < 512; idx += 256) {
      int t = idx >> 4, cc2 = (idx & 15) * 2;
      float p0 = yl[t][cc2], p1 = yl[t][cc2 + 1];
      float x0 = dxs[t][cc2][1], x1 = dxs[t][cc2 + 1][1];
      float z0 = dxs[t][cc2][2], z1 = dxs[t][cc2 + 1][2];
      float s0 = z0 / (1.0f + __expf(-z0));
      float s1 = z1 / (1.0f + __expf(-z1));
      ushort2 o = {f2b((p0 + DpL[cc2] * x0) * s0), f2b((p1 + DpL[cc2 + 1] * x1) * s1)};
      *(ushort2*)&yp[(size_t)(t0c + t) * 256 + c0 + cc2] = o;
    }
    __syncthreads();
  }
}

// ---------------- mamba: MFMA out-projection + residual(bf16) + LayerNorm ----------------
// 256 threads: waves split rows (wv&1) x et-halves (wv>>1); LN sums via LDS
__global__ __launch_bounds__(256) void k_outln(const unsigned short* __restrict__ yb,
                                               const unsigned short* __restrict__ owbf,
                                               unsigned short* __restrict__ xe2bf,
                                               const float* __restrict__ g, const float* __restrict__ bb) {
  __shared__ float sp1[2][32];
  __shared__ float sp2[2][32];
  int blk = blockIdx.x;
  int b = blk >> 3;
  int t0 = (blk & 7) * 32;
  int tid = threadIdx.x;
  int wv = tid >> 6, ln = tid & 15, q = (tid >> 4) & 3;
  int rh = wv & 1;
  int eh = wv >> 1;
  int trow = rh * 16 + ln;        // 0..31 local row
  int t = t0 + trow;

  const unsigned short* yrow = yb + ((size_t)b * 256 + t) * 256 + q * 8;
  short8 bfrag[8];
#pragma unroll
  for (int kc = 0; kc < 8; ++kc) bfrag[kc] = *(const short8*)(yrow + kc * 32);

  float4v acc[4];
#pragma unroll
  for (int e2 = 0; e2 < 4; ++e2) {
    int et = eh * 4 + e2;
    acc[e2] = (float4v){0.f, 0.f, 0.f, 0.f};
    const unsigned short* arow = owbf + (size_t)(et * 16 + ln) * 256 + q * 8;
#pragma unroll
    for (int kc = 0; kc < 8; ++kc) {
      short8 af = *(const short8*)(arow + kc * 32);
      acc[e2] = __builtin_amdgcn_mfma_f32_16x16x32_bf16(af, bfrag[kc], acc[e2], 0, 0, 0);
    }
  }

  unsigned short* xrow = xe2bf + ((size_t)b * 256 + t) * 128;
  float vals[4][4];
  float s1 = 0.f, s2 = 0.f;
#pragma unroll
  for (int e2 = 0; e2 < 4; ++e2) {
    int d = (eh * 4 + e2) * 16 + q * 4;
    short4v res = *(const short4v*)(xrow + d);
#pragma unroll
    for (int r = 0; r < 4; ++r) {
      float v = acc[e2][r] + b2f((unsigned short)res[r]);
      vals[e2][r] = v;
      s1 += v;
      s2 += v * v;
    }
  }
  // reduce across q within wave
  s1 += __shfl_xor(s1, 16, 64);
  s1 += __shfl_xor(s1, 32, 64);
  s2 += __shfl_xor(s2, 16, 64);
  s2 += __shfl_xor(s2, 32, 64);
  if ((tid & 63) < 16) { sp1[eh][trow] = s1; sp2[eh][trow] = s2; }
  __syncthreads();
  float S1 = sp1[0][trow] + sp1[1][trow];
  float S2 = sp2[0][trow] + sp2[1][trow];
  float mu = S1 * (1.0f / 128.0f);
  float rs = rsqrtf(S2 * (1.0f / 128.0f) - mu * mu + 1e-5f);

#pragma unroll
  for (int e2 = 0; e2 < 4; ++e2) {
    int d = (eh * 4 + e2) * 16 + q * 4;
    float4 g4 = *(const float4*)(g + d);
    float4 b4 = *(const float4*)(bb + d);
    float o0 = (vals[e2][0] - mu) * rs * g4.x + b4.x;
    float o1 = (vals[e2][1] - mu) * rs * g4.y + b4.y;
    float o2 = (vals[e2][2] - mu) * rs * g4.z + b4.z;
    float o3 = (vals[e2][3] - mu) * rs * g4.w + b4.w;
    short4v ob = {(short)f2b(o0), (short)f2b(o1), (short)f2b(o2), (short)f2b(o3)};
    *(short4v*)(xrow + d) = ob;
  }
}

// ---------------- merged tail: xflat transpose (blocks <2048) + final FC (blocks >=2048) ----------------
__global__ __launch_bounds__(256) void k_tail(const unsigned short* __restrict__ xe2bf,
                                              float* __restrict__ out,
                                              const unsigned short* __restrict__ fwbf,
                                              float* __restrict__ pred) {
  __shared__ float tile[32][33];
  int tid = threadIdx.x;
  if (blockIdx.x < 2048) {
    int b = blockIdx.x >> 5;
    int blk = blockIdx.x & 31;
    int t0 = (blk >> 2) * 32, d0 = (blk & 3) * 32;
#pragma unroll
    for (int q = 0; q < 4; ++q) {
      int t = (tid >> 5) + q * 8, dd = tid & 31;
      tile[t][dd] = b2f(xe2bf[(size_t)b * 32768 + (size_t)(t0 + t) * 128 + d0 + dd]);
    }
    __syncthreads();
#pragma unroll
    for (int q = 0; q < 4; ++q) {
      int dd = (tid >> 5) + q * 8, t = tid & 31;
      float v = tile[t][dd];
      size_t o = (size_t)b * 32768 + (size_t)(d0 + dd) * 256 + t0 + t;
      out[o] = v;
    }
    return;
  }
  // FC role
  int kb = blockIdx.x - 2048;
  int k0 = kb * 256;
  int wv = tid >> 6, ln = tid & 15, q = (tid >> 4) & 3;
  int b = wv * 16 + ln;
  const unsigned short* xrow = xe2bf + (size_t)b * 32768 + k0 + q * 8;
  float4v acc[2];
  acc[0] = (float4v){0.f, 0.f, 0.f, 0.f};
  acc[1] = (float4v){0.f, 0.f, 0.f, 0.f};
#pragma unroll
  for (int kc = 0; kc < 8; ++kc) {
    short8 bfrag = *(const short8*)(xrow + kc * 32);
#pragma unroll
    for (int et = 0; et < 2; ++et) {
      short8 af = *(const short8*)(fwbf + (size_t)(et * 16 + ln) * 32768 + k0 + kc * 32 + q * 8);
      acc[et] = __builtin_amdgcn_mfma_f32_16x16x32_bf16(af, bfrag, acc[et], 0, 0, 0);
    }
  }
#pragma unroll
  for (int et = 0; et < 2; ++et)
#pragma unroll
    for (int r = 0; r < 4; ++r) {
      int c = et * 16 + q * 4 + r;
      if (c < 18) atomicAdd(&pred[b * 18 + c], acc[et][r]);
    }
}

extern "C" void kernel_launch(void* const* d_in, const int* in_sizes, int n_in,
                              void* d_out, int out_size, void* d_ws, size_t ws_size,
                              hipStream_t stream) {
  (void)in_sizes; (void)n_in; (void)out_size; (void)ws_size;
  const float* inp    = (const float*)d_in[0];
  const float* emb_w  = (const float*)d_in[1];
  const float* emb_b  = (const float*)d_in[2];
  const float* dw_w   = (const float*)d_in[3];
  const float* dw_b   = (const float*)d_in[4];
  const float* pw_w   = (const float*)d_in[5];
  const float* pw_b   = (const float*)d_in[6];
  const float* se_w1  = (const float*)d_in[7];
  const float* se_b1  = (const float*)d_in[8];
  const float* se_w2  = (const float*)d_in[9];
  const float* se_b2  = (const float*)d_in[10];
  const float* in_w   = (const float*)d_in[11];
  const float* conv_w = (const float*)d_in[12];
  const float* conv_b = (const float*)d_in[13];
  const float* xp_w   = (const float*)d_in[14];
  const float* dt_w   = (const float*)d_in[15];
  const float* dt_b   = (const float*)d_in[16];
  const float* Alog   = (const float*)d_in[17];
  const float* Dp     = (const float*)d_in[18];
  const float* out_w  = (const float*)d_in[19];
  const float* ln_g   = (const float*)d_in[20];
  const float* ln_b   = (const float*)d_in[21];
  const float* fc_w   = (const float*)d_in[22];
  const float* fc_b   = (const float*)d_in[23];

  char* ws = (char*)d_ws;
  unsigned short* U0 = (unsigned short*)(ws);
  unsigned short* xz = (unsigned short*)(ws);                 // after reduce2
  unsigned short* xc = (unsigned short*)(ws + 33554432);
  unsigned short* yb = (unsigned short*)(ws + 50331648);
  unsigned short* fwbf = (unsigned short*)(ws + 113246208);
  float* dbl = (float*)(ws + 150994944);
  unsigned short* xe2bf = (unsigned short*)(ws + 153616384);

  float* xflat = (float*)d_out;
  float* pred  = xflat + (size_t)64 * 32768;
  unsigned short* pwbf  = (unsigned short*)d_out;   // weight scratch until k_tail
  unsigned short* inwbf = pwbf + 49152;
  unsigned short* owbf  = inwbf + 131072;
  unsigned short* xwbf  = owbf + 65536;
  unsigned short* ewbf  = xwbf + 24576;

  hipFuncSetAttribute((const void*)k_mega, hipFuncAttributeMaxDynamicSharedMemorySize, MEGA_LDS);

  k_cvt<<<3445, 256, 0, stream>>>(pw_w, in_w, out_w, xp_w, emb_w, fc_w, fc_b, pwbf, fwbf, pred);
  k_emb<<<768, 256, 0, stream>>>(inp, ewbf, emb_b, U0);

  k_mega<<<768, 512, MEGA_LDS, stream>>>(U0, dw_w, dw_b, pwbf, pw_b,
                                         se_w1, se_b1, se_w2, se_b2, U0);

  k_reduce2<<<1024, 256, 0, stream>>>(U0, xe2bf);

  for (int i = 0; i < 2; ++i) {
    k_inproj<<<512, 256, 0, stream>>>(xe2bf, inwbf + i * 65536, xz);
    k_xproj<<<512, 256, 0, stream>>>(xz, conv_w + i * 1024, conv_b + i * 256,
                                     xwbf + i * 12288, xc, dbl);
    k_scan2<<<512, 256, 0, stream>>>(dbl, xc, xz, Alog + i * 4096,
                                     dt_w + i * 2048, dt_b + i * 256, Dp + i * 256, yb);
    k_outln<<<512, 256, 0, stream>>>(yb, owbf + i * 32768, xe2bf,
                                     ln_g + i * 128, ln_b + i * 128);
  }

  k_tail<<<2176, 256, 0, stream>>>(xe2bf, xflat, fwbf, pred);
}

// Round 13
// 513.555 us; speedup vs baseline: 1.2080x; 1.0368x over previous
//
#include <hip/hip_runtime.h>
#include <math.h>

#define LL 2048
#define MM 12
#define DD 128
#define TP 256   // T
#define MEGA_LDS 78464

typedef short short8 __attribute__((ext_vector_type(8)));
typedef short short4v __attribute__((ext_vector_type(4)));
typedef float float4v __attribute__((ext_vector_type(4)));

static __device__ __forceinline__ unsigned short f2b(float f) {
  union { float f; unsigned int u; } x; x.f = f;
  unsigned int r = x.u + 0x7fffu + ((x.u >> 16) & 1u);
  return (unsigned short)(r >> 16);
}
static __device__ __forceinline__ float b2f(unsigned short u) {
  union { unsigned int u; float f; } x; x.u = ((unsigned int)u) << 16;
  return x.f;
}
// branch-free erf (A&S 7.1.26, |err| <= ~5e-7): rcp + exp + 5 FMA
static __device__ __forceinline__ float fast_gelu(float x) {
  float xs = x * 0.70710678118654752f;
  float y = fabsf(xs);
  float t = __builtin_amdgcn_rcpf(fmaf(0.3275911f, y, 1.0f));
  float p = fmaf(fmaf(fmaf(fmaf(1.061405429f, t, -1.453152027f), t,
                           1.421413741f), t, -0.284496736f), t, 0.254829592f);
  p = p * t;
  float e = __expf(-y * y);
  float er = fmaf(-p, e, 1.0f);
  er = copysignf(er, xs);
  return 0.5f * x * (1.0f + er);
}
static __device__ __forceinline__ float qxor1(float x) {
  int r = __builtin_amdgcn_mov_dpp(__builtin_bit_cast(int, x), 0xB1, 0xF, 0xF, true);
  return __builtin_bit_cast(float, r);
}
static __device__ __forceinline__ float qxor2(float x) {
  int r = __builtin_amdgcn_mov_dpp(__builtin_bit_cast(int, x), 0x4E, 0xF, 0xF, true);
  return __builtin_bit_cast(float, r);
}

// ---------------- convert weights to bf16; coalesced fc_w transpose; pred bias init ----------------
// grid 3445x256:
//   [0,1072)    : small weights (linear, 274432 elems)
//   [1072,1648) : fc_w transpose via 32x32 LDS tiles (18m x 4dt x 8tt = 576 tiles)
//   [1648,3440) : fwbf zero-pad for m in [18,32) (458752 elems)
//   [3440,3445) : pred init = fcb
__global__ __launch_bounds__(256) void k_cvt(const float* __restrict__ pw_w, const float* __restrict__ in_w,
                                             const float* __restrict__ out_w, const float* __restrict__ xp_w,
                                             const float* __restrict__ ew, const float* __restrict__ fw,
                                             const float* __restrict__ fcb,
                                             unsigned short* __restrict__ pwbf, unsigned short* __restrict__ fwbf,
                                             float* __restrict__ pred) {
  __shared__ float tile[32][33];
  int blk = blockIdx.x;
  int tid = threadIdx.x;
  if (blk >= 3440) {
    int j2 = (blk - 3440) * 256 + tid;
    if (j2 < 1152) pred[j2] = fcb[j2 % 18];
    return;
  }
  if (blk >= 1648) {
    int j = 589824 + (blk - 1648) * 256 + tid;
    fwbf[j] = 0;
    return;
  }
  if (blk >= 1072) {
    // fc_w transpose tile: fwbf[m][t*128+d] = f2b(fc_w[m][d*256+t]), coalesced both sides
    int rel = blk - 1072;
    int m = rel >> 5;               // 0..17
    int sub = rel & 31;
    int d0 = (sub >> 3) * 32, t0 = (sub & 7) * 32;
#pragma unroll
    for (int q = 0; q < 4; ++q) {
      int dd = (tid >> 5) + q * 8, tt = tid & 31;
      tile[dd][tt] = fw[(size_t)m * 32768 + (size_t)(d0 + dd) * 256 + t0 + tt];
    }
    __syncthreads();
#pragma unroll
    for (int q = 0; q < 4; ++q) {
      int tt = (tid >> 5) + q * 8, dd = tid & 31;
      fwbf[(size_t)m * 32768 + (size_t)(t0 + tt) * 128 + d0 + dd] = f2b(tile[dd][tt]);
    }
    return;
  }
  int i = blk * 256 + tid;
  if (i < 49152) { pwbf[i] = f2b(pw_w[i]); return; }
  int i2 = i - 49152;
  if (i2 < 131072) { pwbf[i] = f2b(in_w[i2]); return; }
  int i3 = i2 - 131072;
  if (i3 < 65536) { pwbf[i] = f2b(out_w[i3]); return; }
  int i4 = i3 - 65536;
  if (i4 < 24576) {
    int layer = (i4 < 12288) ? 0 : 1;
    int rem = i4 - layer * 12288;
    int k = rem >> 8, c = rem & 255;
    float v = (k < 40) ? xp_w[layer * 10240 + k * 256 + c] : 0.0f;
    pwbf[i] = f2b(v);
    return;
  }
  int i5 = i4 - 24576;
  if (i5 < 4096) {
    int d = i5 >> 5, k = i5 & 31;
    float v = (k < 16) ? ew[d * 16 + k] : 0.0f;
    pwbf[i] = f2b(v);
  }
}

// ---------------- MEGA block stage: embedding + all 3 layers + SE, signal resident in LDS ----------------
// grid 768 x 512 threads; dynamic LDS 78464 B. Embedding computed in-kernel
// (xs[2048] f32 lives in the scratch region above us, dead before dwT load).
__global__ __launch_bounds__(512) void k_mega(const float* __restrict__ inp,
                                              const unsigned short* __restrict__ ewbf,
                                              const float* __restrict__ eb,
                                              const float* __restrict__ dww, const float* __restrict__ dwb,
                                              const unsigned short* __restrict__ pwbf,
                                              const float* __restrict__ pwb,
                                              const float* __restrict__ w1, const float* __restrict__ b1,
                                              const float* __restrict__ w2, const float* __restrict__ b2,
                                              unsigned short* __restrict__ uout) {
  extern __shared__ char smemraw[];
  unsigned short* us = (unsigned short*)smemraw;
  float* dwT  = (float*)(smemraw + 69632);
  float* dwbL = dwT + 640;
  float* pwbL = dwbL + 128;
  float* sred = pwbL + 128;
  float* smv  = sred + 1024;
  float* hh   = smv + 128;
  float* aL   = hh + 32;

  int sig = blockIdx.x;
  int tid = threadIdx.x;
  const size_t gbase = (size_t)sig * 32768;
  int cu = tid & 15;
  int r0 = tid >> 4;   // 0..31

  int wv = tid >> 6;   // 0..7
  int ln = tid & 15;
  int q  = (tid >> 4) & 3;
  int tb = wv * 32;

  // ---- embedding phase: compute u0 rows directly into us (was k_emb) ----
  {
    float* xs = (float*)(smemraw + 69632);   // 2048 f32, overlaps dwT scratch (dead before layer loop)
    int b = sig / MM, m = sig % MM;
    const float* ib = inp + (size_t)b * LL * MM + m;
    for (int i = tid; i < LL; i += 512) xs[i] = ib[(size_t)i * MM];
    __syncthreads();
    short8 eaf[8];
#pragma unroll
    for (int et = 0; et < 8; ++et)
      eaf[et] = *(const short8*)(ewbf + (et * 16 + ln) * 32 + q * 8);
#pragma unroll
    for (int pass = 0; pass < 2; ++pass) {
      int t = pass * 128 + wv * 16 + ln;
      int l0 = t * 8 - 4;
      short8 bfrag;
#pragma unroll
      for (int j = 0; j < 8; ++j) {
        int k = q * 8 + j;
        int l = l0 + k;
        float v = (k < 16 && l >= 0 && l < LL) ? xs[l] : 0.0f;
        bfrag[j] = (short)f2b(v);
      }
      float4v eacc[8];
#pragma unroll
      for (int et = 0; et < 8; ++et) {
        eacc[et] = (float4v){0.f, 0.f, 0.f, 0.f};
        eacc[et] = __builtin_amdgcn_mfma_f32_16x16x32_bf16(eaf[et], bfrag, eacc[et], 0, 0, 0);
      }
#pragma unroll
      for (int et = 0; et < 8; ++et) {
        int e = et * 16 + q * 4;
        float4 pb = *(const float4*)&eb[e];
        short4v st = {(short)f2b(eacc[et][0] + pb.x), (short)f2b(eacc[et][1] + pb.y),
                      (short)f2b(eacc[et][2] + pb.z), (short)f2b(eacc[et][3] + pb.w)};
        *(short4v*)(us + t * 136 + e) = st;
      }
    }
  }

  for (int layer = 0; layer < 3; ++layer) {
    __syncthreads();
    for (int i = tid; i < 640; i += 512) dwT[(i % 5) * 128 + (i / 5)] = dww[layer * 640 + i];
    if (tid < 128) { dwbL[tid] = dwb[layer * 128 + tid]; pwbL[tid] = pwb[layer * 128 + tid]; }
    __syncthreads();

    const unsigned short* pwL = pwbf + layer * 16384;
    float4v acc[2][8];
#pragma unroll
    for (int tl = 0; tl < 2; ++tl)
#pragma unroll
      for (int et = 0; et < 8; ++et) acc[tl][et] = (float4v){0.f, 0.f, 0.f, 0.f};

#pragma unroll
    for (int kc = 0; kc < 4; ++kc) {
      int dc = kc * 32 + q * 8;
      short8 af[8];
#pragma unroll
      for (int et = 0; et < 8; ++et)
        af[et] = *(const short8*)(pwL + (size_t)(et * 16 + ln) * 128 + dc);
      float wt[5][8], bl8[8];
#pragma unroll
      for (int k = 0; k < 5; ++k) {
        float4 wa = *(const float4*)&dwT[k * 128 + dc];
        float4 wb = *(const float4*)&dwT[k * 128 + dc + 4];
        wt[k][0] = wa.x; wt[k][1] = wa.y; wt[k][2] = wa.z; wt[k][3] = wa.w;
        wt[k][4] = wb.x; wt[k][5] = wb.y; wt[k][6] = wb.z; wt[k][7] = wb.w;
      }
      {
        float4 ba = *(const float4*)&dwbL[dc];
        float4 bb2 = *(const float4*)&dwbL[dc + 4];
        bl8[0] = ba.x; bl8[1] = ba.y; bl8[2] = ba.z; bl8[3] = ba.w;
        bl8[4] = bb2.x; bl8[5] = bb2.y; bl8[6] = bb2.z; bl8[7] = bb2.w;
      }
#pragma unroll
      for (int tl = 0; tl < 2; ++tl) {
        int t = tb + tl * 16 + ln;
        float a8[8];
#pragma unroll
        for (int j = 0; j < 8; ++j) a8[j] = bl8[j];
#pragma unroll
        for (int k = 0; k < 5; ++k) {
          int tt = t - 2 + k;
          if (tt >= 0 && tt < 256) {
            short8 u8 = *(const short8*)(us + tt * 136 + dc);
#pragma unroll
            for (int j = 0; j < 8; ++j) a8[j] += b2f((unsigned short)u8[j]) * wt[k][j];
          }
        }
        short8 bf;
#pragma unroll
        for (int j = 0; j < 8; ++j)
          bf[j] = (short)f2b(fast_gelu(a8[j]));
#pragma unroll
        for (int et = 0; et < 8; ++et)
          acc[tl][et] = __builtin_amdgcn_mfma_f32_16x16x32_bf16(af[et], bf, acc[tl][et], 0, 0, 0);
      }
    }
    __syncthreads();   // all us reads done; sred free

    // SE t-partial sums -> sred
#pragma unroll
    for (int et = 0; et < 8; ++et) {
      int e = et * 16 + q * 4;
      float4 pb = *(const float4*)&pwbL[e];
      float sv0 = acc[0][et][0] + acc[1][et][0] + 2.0f * pb.x;
      float sv1 = acc[0][et][1] + acc[1][et][1] + 2.0f * pb.y;
      float sv2 = acc[0][et][2] + acc[1][et][2] + 2.0f * pb.z;
      float sv3 = acc[0][et][3] + acc[1][et][3] + 2.0f * pb.w;
#pragma unroll
      for (int m = 1; m <= 8; m <<= 1) {
        sv0 += __shfl_xor(sv0, m, 64);
        sv1 += __shfl_xor(sv1, m, 64);
        sv2 += __shfl_xor(sv2, m, 64);
        sv3 += __shfl_xor(sv3, m, 64);
      }
      if (ln == 0) {
        float4 sv = {sv0, sv1, sv2, sv3};
        *(float4*)&sred[wv * 128 + e] = sv;
      }
    }
    __syncthreads();
    if (tid < 128) {
      float s = 0.f;
#pragma unroll
      for (int w = 0; w < 8; ++w) s += sred[w * 128 + tid];
      smv[tid] = s * (1.0f / 256.0f);
    }
    __syncthreads();
    // SE hidden layer: 256 threads, 8 lanes per output, shuffle-reduce
    if (tid < 256) {
      int o = tid >> 3, part = tid & 7;
      const float* wr = w1 + layer * 4096 + o * 128 + part * 16;
      const float* sv = smv + part * 16;
      float s = 0.f;
#pragma unroll
      for (int j = 0; j < 16; j += 4) {
        float4 w4 = *(const float4*)(wr + j);
        float4 v4 = *(const float4*)(sv + j);
        s += w4.x * v4.x + w4.y * v4.y + w4.z * v4.z + w4.w * v4.w;
      }
      s += __shfl_xor(s, 1, 64);
      s += __shfl_xor(s, 2, 64);
      s += __shfl_xor(s, 4, 64);
      if (part == 0) hh[o] = fmaxf(s + b1[layer * 32 + o], 0.0f);
    }
    __syncthreads();
    // SE gate: all 512 threads, 4 lanes per output
    {
      int o = tid >> 2, part = tid & 3;
      const float* wr = w2 + layer * 4096 + o * 32 + part * 8;
      float s = 0.f;
#pragma unroll
      for (int j = 0; j < 8; j += 4) {
        float4 w4 = *(const float4*)(wr + j);
        float4 h4 = *(const float4*)(hh + part * 8 + j);
        s += w4.x * h4.x + w4.y * h4.y + w4.z * h4.z + w4.w * h4.w;
      }
      s += __shfl_xor(s, 1, 64);
      s += __shfl_xor(s, 2, 64);
      if (part == 0) aL[o] = 1.0f / (1.0f + __expf(-(s + b2[layer * 128 + o])));
    }
    __syncthreads();

    // u += w * a  (in LDS, disjoint per lane)
#pragma unroll
    for (int tl = 0; tl < 2; ++tl) {
      int t = tb + tl * 16 + ln;
#pragma unroll
      for (int et = 0; et < 8; ++et) {
        int e = et * 16 + q * 4;
        float4 pb = *(const float4*)&pwbL[e];
        float4 ga = *(const float4*)&aL[e];
        short4v u4 = *(short4v*)(us + t * 136 + e);
        short4v r;
        r[0] = (short)f2b(b2f((unsigned short)u4[0]) + (acc[tl][et][0] + pb.x) * ga.x);
        r[1] = (short)f2b(b2f((unsigned short)u4[1]) + (acc[tl][et][1] + pb.y) * ga.y);
        r[2] = (short)f2b(b2f((unsigned short)u4[2]) + (acc[tl][et][2] + pb.z) * ga.z);
        r[3] = (short)f2b(b2f((unsigned short)u4[3]) + (acc[tl][et][3] + pb.w) * ga.w);
        *(short4v*)(us + t * 136 + e) = r;
      }
    }
  }
  __syncthreads();
#pragma unroll
  for (int p = 0; p < 8; ++p) {
    int t = p * 32 + r0;
    short8 v = *(short8*)(us + t * 136 + cu * 8);
    *(short8*)(uout + gbase + (size_t)t * 128 + cu * 8) = v;
  }
}

// ---------------- mean over M -> xe2bf bf16 (residual stream is bf16-only) ----------------
__global__ __launch_bounds__(256) void k_reduce2(const unsigned short* __restrict__ u,
                                                 unsigned short* __restrict__ xe2bf) {
  int i = blockIdx.x * 256 + threadIdx.x;
  int d0 = (i & 15) * 8;
  int t = (i >> 4) & 255;
  int b = i >> 12;
  float acc[8] = {0.f, 0.f, 0.f, 0.f, 0.f, 0.f, 0.f, 0.f};
#pragma unroll 4
  for (int m = 0; m < 12; ++m) {
    size_t base = ((size_t)(b * 12 + m) * 256 + t) * 128 + d0;
    short8 u8 = *(const short8*)(u + base);
#pragma unroll
    for (int j = 0; j < 8; ++j) acc[j] += b2f((unsigned short)u8[j]);
  }
  size_t off = (size_t)b * 32768 + (size_t)t * 128 + d0;
  short8 ob;
#pragma unroll
  for (int j = 0; j < 8; ++j) ob[j] = (short)f2b(acc[j] / 12.f);
  *(short8*)(xe2bf + off) = ob;
}

// ---------------- mamba: in-projection via MFMA, zero-LDS -> bf16 xz[t][e] ----------------
__global__ __launch_bounds__(256) void k_inproj(const unsigned short* __restrict__ xe2bf,
                                                const unsigned short* __restrict__ inwbf,
                                                unsigned short* __restrict__ xz) {
  int blk = blockIdx.x;
  int b = blk >> 3;
  int tt = (blk >> 1) & 3;
  int eh = blk & 1;
  int t0 = tt * 64, e0 = eh * 256;
  int tid = threadIdx.x;
  int wv = tid >> 6, ln = tid & 15, q = (tid >> 4) & 3;
  int t = t0 + wv * 16 + ln;
  const unsigned short* xrow = xe2bf + ((size_t)b * 256 + t) * 128 + q * 8;
  short8 bfrag[4];
#pragma unroll
  for (int kc = 0; kc < 4; ++kc) bfrag[kc] = *(const short8*)(xrow + kc * 32);
  float4v acc[16];
#pragma unroll
  for (int et = 0; et < 16; ++et) acc[et] = (float4v){0.f, 0.f, 0.f, 0.f};
#pragma unroll
  for (int et = 0; et < 16; ++et) {
    const unsigned short* arow = inwbf + (size_t)(e0 + et * 16 + ln) * 128 + q * 8;
#pragma unroll
    for (int kc = 0; kc < 4; ++kc) {
      short8 af = *(const short8*)(arow + kc * 32);
      acc[et] = __builtin_amdgcn_mfma_f32_16x16x32_bf16(af, bfrag[kc], acc[et], 0, 0, 0);
    }
  }
  unsigned short* orow = xz + ((size_t)b * 256 + t) * 512 + e0 + q * 4;
#pragma unroll
  for (int et = 0; et < 16; ++et) {
    short4v st = {(short)f2b(acc[et][0]), (short)f2b(acc[et][1]),
                  (short)f2b(acc[et][2]), (short)f2b(acc[et][3])};
    *(short4v*)(orow + et * 16) = st;
  }
}

// ---------------- mamba: fused causal conv+SiLU -> x-projection MFMA; writes xc + dbl ----------------
// 32-row tiles (tq 0..7), 512 blocks -> 2+ blocks/CU
__global__ __launch_bounds__(256) void k_xproj(const unsigned short* __restrict__ xz,
                                               const float* __restrict__ cw, const float* __restrict__ cb,
                                               const unsigned short* __restrict__ xwbf,
                                               unsigned short* __restrict__ xcg,
                                               float* __restrict__ dbl) {
  __shared__ unsigned short xis[35 * 264];
  int blk = blockIdx.x;
  int b = blk >> 3;
  int tq = blk & 7;
  int t0 = tq * 32;
  int tid = threadIdx.x;

  const short8 ZV = {0, 0, 0, 0, 0, 0, 0, 0};
  for (int idx = tid; idx < 1120; idx += 256) {
    int row = idx >> 5, cu = idx & 31;
    int t = t0 - 3 + row;
    short8 v = ZV;
    if (t >= 0) v = *(const short8*)(xz + ((size_t)b * 256 + t) * 512 + cu * 8);
    *(short8*)(xis + row * 264 + cu * 8) = v;
  }
  __syncthreads();

  int cu = tid & 31;
  int rb = tid >> 5;
  int c8 = cu * 8;
  float wl[4][8], bl[8];
#pragma unroll
  for (int j = 0; j < 8; ++j) {
    float4 w4 = *(const float4*)&cw[(c8 + j) * 4];
    wl[0][j] = w4.x; wl[1][j] = w4.y; wl[2][j] = w4.z; wl[3][j] = w4.w;
    bl[j] = cb[c8 + j];
  }

  short8 vv[4];
#pragma unroll
  for (int s = 0; s < 4; ++s) {
    int r = rb + s * 8;   // 0..31
    float acc[8];
#pragma unroll
    for (int j = 0; j < 8; ++j) acc[j] = bl[j];
#pragma unroll
    for (int k = 0; k < 4; ++k) {
      short8 u8 = *(const short8*)(xis + (r + k) * 264 + c8);
#pragma unroll
      for (int j = 0; j < 8; ++j) acc[j] += b2f((unsigned short)u8[j]) * wl[k][j];
    }
#pragma unroll
    for (int j = 0; j < 8; ++j)
      vv[s][j] = (short)f2b(acc[j] / (1.0f + __expf(-acc[j])));
    *(short8*)(xcg + ((size_t)b * 256 + t0 + r) * 256 + c8) = vv[s];
  }
  __syncthreads();
#pragma unroll
  for (int s = 0; s < 4; ++s)
    *(short8*)(xis + (rb + s * 8) * 264 + c8) = vv[s];
  __syncthreads();

  // xproj MFMA: 32 rows across wave-pairs; et split across halves
  int wv = tid >> 6, ln = tid & 15, q = (tid >> 4) & 3;
  int tl = (wv & 1) * 16 + ln;    // 0..31
  int eh = wv >> 1;               // 0: et 0,1 ; 1: et 2
  short8 bfrag[8];
#pragma unroll
  for (int kc = 0; kc < 8; ++kc)
    bfrag[kc] = *(const short8*)(xis + tl * 264 + kc * 32 + q * 8);
  float* drow = dbl + ((size_t)b * 256 + t0 + tl) * 40;
  if (eh == 0) {
    float4v acc[2];
    acc[0] = (float4v){0.f, 0.f, 0.f, 0.f};
    acc[1] = (float4v){0.f, 0.f, 0.f, 0.f};
#pragma unroll
    for (int et = 0; et < 2; ++et) {
      const unsigned short* arow = xwbf + (size_t)(et * 16 + ln) * 256 + q * 8;
#pragma unroll
      for (int kc = 0; kc < 8; ++kc) {
        short8 af = *(const short8*)(arow + kc * 32);
        acc[et] = __builtin_amdgcn_mfma_f32_16x16x32_bf16(af, bfrag[kc], acc[et], 0, 0, 0);
      }
    }
#pragma unroll
    for (int et = 0; et < 2; ++et)
#pragma unroll
      for (int r = 0; r < 4; ++r)
        drow[et * 16 + q * 4 + r] = acc[et][r];
  } else {
    float4v acc = (float4v){0.f, 0.f, 0.f, 0.f};
    const unsigned short* arow = xwbf + (size_t)(2 * 16 + ln) * 256 + q * 8;
#pragma unroll
    for (int kc = 0; kc < 8; ++kc) {
      short8 af = *(const short8*)(arow + kc * 32);
      acc = __builtin_amdgcn_mfma_f32_16x16x32_bf16(af, bfrag[kc], acc, 0, 0, 0);
    }
#pragma unroll
    for (int r = 0; r < 4; ++r) {
      int k = 32 + q * 4 + r;
      if (k < 40) drow[k] = acc[r];
    }
  }
}

// ---------------- mamba: fused dt + selective scan + y-finalize ----------------
// 256 threads; serial scan 2 states/thread across ALL 256 threads
__global__ __launch_bounds__(256) void k_scan2(const float* __restrict__ dbl,
                                               const unsigned short* __restrict__ xc,
                                               const unsigned short* __restrict__ xz,
                                               const float* __restrict__ Alog,
                                               const float* __restrict__ dtw, const float* __restrict__ dtbv,
                                               const float* __restrict__ Dp, unsigned short* __restrict__ y) {
  __shared__ float ds[32][40];
  __shared__ float dxs[32][32][4];
  __shared__ float yl[32][32];
  __shared__ float dtwL[32][8];
  __shared__ float dtbL[32];
  __shared__ float DpL[32];

  int b = blockIdx.x >> 3;
  int c0 = (blockIdx.x & 7) * 32;
  int tid = threadIdx.x;

  for (int idx = tid; idx < 256; idx += 256) dtwL[idx >> 3][idx & 7] = dtw[(c0 + (idx >> 3)) * 8 + (idx & 7)];
  if (tid < 32) { dtbL[tid] = dtbv[c0 + tid]; DpL[tid] = Dp[c0 + tid]; }

  int c_loc = tid >> 3;          // 0..31
  int c = c0 + c_loc;
  int sblk = (tid & 7) * 2;      // 0,2,..,14

  float2 Al = *(const float2*)&Alog[c * 16 + sblk];
  float A0 = -__expf(Al.x), A1 = -__expf(Al.y);
  float h0 = 0.f, h1 = 0.f;

  const float* dbp = dbl + (size_t)b * 10240;
  const unsigned short* xcp = xc + (size_t)b * 65536;
  const unsigned short* xzp = xz + (size_t)b * 131072;
  unsigned short* yp = y + (size_t)b * 65536;

  for (int chk = 0; chk < 8; ++chk) {
    int t0c = chk * 32;
    for (int idx = tid; idx < 1280; idx += 256) ((float*)ds)[idx] = dbp[t0c * 40 + idx];
    for (int idx = tid; idx < 512; idx += 256) {
      int t = idx >> 4, cc2 = (idx & 15) * 2;
      ushort2 xv = *(const ushort2*)&xcp[(size_t)(t0c + t) * 256 + c0 + cc2];
      ushort2 zv = *(const ushort2*)&xzp[(size_t)(t0c + t) * 512 + 256 + c0 + cc2];
      dxs[t][cc2][1] = b2f(xv.x);
      dxs[t][cc2 + 1][1] = b2f(xv.y);
      dxs[t][cc2][2] = b2f(zv.x);
      dxs[t][cc2 + 1][2] = b2f(zv.y);
    }
    __syncthreads();
    for (int idx = tid; idx < 1024; idx += 256) {
      int t = idx >> 5, cc = idx & 31;
      const float* dr = ds[t];
      const float* wr = dtwL[cc];
      float acc = dtbL[cc];
#pragma unroll
      for (int j = 0; j < 8; ++j) acc += wr[j] * dr[j];
      dxs[t][cc][0] = (acc > 20.0f) ? acc : __logf(1.0f + __expf(acc));
    }
    __syncthreads();
#pragma unroll 4
    for (int t = 0; t < 32; ++t) {
      float2 dx = *(const float2*)&dxs[t][c_loc][0];
      float2 Bv = *(const float2*)&ds[t][8 + sblk];
      float2 Cv = *(const float2*)&ds[t][24 + sblk];
      float dtv = dx.x;
      float bx = dtv * dx.y;
      h0 = __expf(dtv * A0) * h0 + Bv.x * bx;
      h1 = __expf(dtv * A1) * h1 + Bv.y * bx;
      float p = h0 * Cv.x;
      p = fmaf(h1, Cv.y, p);
      p += qxor1(p);
      p += qxor2(p);
      p += __shfl_xor(p, 4, 64);
      if ((tid & 7) == 0) yl[t][c_loc] = p;
    }
    __syncthreads();
    for (int idx = tid; idx < 512; idx += 256) {
      int t = idx >> 4, cc2 = (idx & 15) * 2;
      float p0 = yl[t][cc2], p1 = yl[t][cc2 + 1];
      float x0 = dxs[t][cc2][1], x1 = dxs[t][cc2 + 1][1];
      float z0 = dxs[t][cc2][2], z1 = dxs[t][cc2 + 1][2];
      float s0 = z0 / (1.0f + __expf(-z0));
      float s1 = z1 / (1.0f + __expf(-z1));
      ushort2 o = {f2b((p0 + DpL[cc2] * x0) * s0), f2b((p1 + DpL[cc2 + 1] * x1) * s1)};
      *(ushort2*)&yp[(size_t)(t0c + t) * 256 + c0 + cc2] = o;
    }
    __syncthreads();
  }
}

// ---------------- mamba: MFMA out-projection + residual(bf16) + LayerNorm ----------------
// 256 threads: waves split rows (wv&1) x et-halves (wv>>1); LN sums via LDS
__global__ __launch_bounds__(256) void k_outln(const unsigned short* __restrict__ yb,
                                               const unsigned short* __restrict__ owbf,
                                               unsigned short* __restrict__ xe2bf,
                                               const float* __restrict__ g, const float* __restrict__ bb) {
  __shared__ float sp1[2][32];
  __shared__ float sp2[2][32];
  int blk = blockIdx.x;
  int b = blk >> 3;
  int t0 = (blk & 7) * 32;
  int tid = threadIdx.x;
  int wv = tid >> 6, ln = tid & 15, q = (tid >> 4) & 3;
  int rh = wv & 1;
  int eh = wv >> 1;
  int trow = rh * 16 + ln;        // 0..31 local row
  int t = t0 + trow;

  const unsigned short* yrow = yb + ((size_t)b * 256 + t) * 256 + q * 8;
  short8 bfrag[8];
#pragma unroll
  for (int kc = 0; kc < 8; ++kc) bfrag[kc] = *(const short8*)(yrow + kc * 32);

  float4v acc[4];
#pragma unroll
  for (int e2 = 0; e2 < 4; ++e2) {
    int et = eh * 4 + e2;
    acc[e2] = (float4v){0.f, 0.f, 0.f, 0.f};
    const unsigned short* arow = owbf + (size_t)(et * 16 + ln) * 256 + q * 8;
#pragma unroll
    for (int kc = 0; kc < 8; ++kc) {
      short8 af = *(const short8*)(arow + kc * 32);
      acc[e2] = __builtin_amdgcn_mfma_f32_16x16x32_bf16(af, bfrag[kc], acc[e2], 0, 0, 0);
    }
  }

  unsigned short* xrow = xe2bf + ((size_t)b * 256 + t) * 128;
  float vals[4][4];
  float s1 = 0.f, s2 = 0.f;
#pragma unroll
  for (int e2 = 0; e2 < 4; ++e2) {
    int d = (eh * 4 + e2) * 16 + q * 4;
    short4v res = *(const short4v*)(xrow + d);
#pragma unroll
    for (int r = 0; r < 4; ++r) {
      float v = acc[e2][r] + b2f((unsigned short)res[r]);
      vals[e2][r] = v;
      s1 += v;
      s2 += v * v;
    }
  }
  // reduce across q within wave
  s1 += __shfl_xor(s1, 16, 64);
  s1 += __shfl_xor(s1, 32, 64);
  s2 += __shfl_xor(s2, 16, 64);
  s2 += __shfl_xor(s2, 32, 64);
  if ((tid & 63) < 16) { sp1[eh][trow] = s1; sp2[eh][trow] = s2; }
  __syncthreads();
  float S1 = sp1[0][trow] + sp1[1][trow];
  float S2 = sp2[0][trow] + sp2[1][trow];
  float mu = S1 * (1.0f / 128.0f);
  float rs = rsqrtf(S2 * (1.0f / 128.0f) - mu * mu + 1e-5f);

#pragma unroll
  for (int e2 = 0; e2 < 4; ++e2) {
    int d = (eh * 4 + e2) * 16 + q * 4;
    float4 g4 = *(const float4*)(g + d);
    float4 b4 = *(const float4*)(bb + d);
    float o0 = (vals[e2][0] - mu) * rs * g4.x + b4.x;
    float o1 = (vals[e2][1] - mu) * rs * g4.y + b4.y;
    float o2 = (vals[e2][2] - mu) * rs * g4.z + b4.z;
    float o3 = (vals[e2][3] - mu) * rs * g4.w + b4.w;
    short4v ob = {(short)f2b(o0), (short)f2b(o1), (short)f2b(o2), (short)f2b(o3)};
    *(short4v*)(xrow + d) = ob;
  }
}

// ---------------- merged tail: xflat transpose (blocks <2048) + final FC (blocks >=2048) ----------------
__global__ __launch_bounds__(256) void k_tail(const unsigned short* __restrict__ xe2bf,
                                              float* __restrict__ out,
                                              const unsigned short* __restrict__ fwbf,
                                              float* __restrict__ pred) {
  __shared__ float tile[32][33];
  int tid = threadIdx.x;
  if (blockIdx.x < 2048) {
    int b = blockIdx.x >> 5;
    int blk = blockIdx.x & 31;
    int t0 = (blk >> 2) * 32, d0 = (blk & 3) * 32;
#pragma unroll
    for (int q = 0; q < 4; ++q) {
      int t = (tid >> 5) + q * 8, dd = tid & 31;
      tile[t][dd] = b2f(xe2bf[(size_t)b * 32768 + (size_t)(t0 + t) * 128 + d0 + dd]);
    }
    __syncthreads();
#pragma unroll
    for (int q = 0; q < 4; ++q) {
      int dd = (tid >> 5) + q * 8, t = tid & 31;
      float v = tile[t][dd];
      size_t o = (size_t)b * 32768 + (size_t)(d0 + dd) * 256 + t0 + t;
      out[o] = v;
    }
    return;
  }
  // FC role
  int kb = blockIdx.x - 2048;
  int k0 = kb * 256;
  int wv = tid >> 6, ln = tid & 15, q = (tid >> 4) & 3;
  int b = wv * 16 + ln;
  const unsigned short* xrow = xe2bf + (size_t)b * 32768 + k0 + q * 8;
  float4v acc[2];
  acc[0] = (float4v){0.f, 0.f, 0.f, 0.f};
  acc[1] = (float4v){0.f, 0.f, 0.f, 0.f};
#pragma unroll
  for (int kc = 0; kc < 8; ++kc) {
    short8 bfrag = *(const short8*)(xrow + kc * 32);
#pragma unroll
    for (int et = 0; et < 2; ++et) {
      short8 af = *(const short8*)(fwbf + (size_t)(et * 16 + ln) * 32768 + k0 + kc * 32 + q * 8);
      acc[et] = __builtin_amdgcn_mfma_f32_16x16x32_bf16(af, bfrag, acc[et], 0, 0, 0);
    }
  }
#pragma unroll
  for (int et = 0; et < 2; ++et)
#pragma unroll
    for (int r = 0; r < 4; ++r) {
      int c = et * 16 + q * 4 + r;
      if (c < 18) atomicAdd(&pred[b * 18 + c], acc[et][r]);
    }
}

extern "C" void kernel_launch(void* const* d_in, const int* in_sizes, int n_in,
                              void* d_out, int out_size, void* d_ws, size_t ws_size,
                              hipStream_t stream) {
  (void)in_sizes; (void)n_in; (void)out_size; (void)ws_size;
  const float* inp    = (const float*)d_in[0];
  const float* emb_w  = (const float*)d_in[1];
  const float* emb_b  = (const float*)d_in[2];
  const float* dw_w   = (const float*)d_in[3];
  const float* dw_b   = (const float*)d_in[4];
  const float* pw_w   = (const float*)d_in[5];
  const float* pw_b   = (const float*)d_in[6];
  const float* se_w1  = (const float*)d_in[7];
  const float* se_b1  = (const float*)d_in[8];
  const float* se_w2  = (const float*)d_in[9];
  const float* se_b2  = (const float*)d_in[10];
  const float* in_w   = (const float*)d_in[11];
  const float* conv_w = (const float*)d_in[12];
  const float* conv_b = (const float*)d_in[13];
  const float* xp_w   = (const float*)d_in[14];
  const float* dt_w   = (const float*)d_in[15];
  const float* dt_b   = (const float*)d_in[16];
  const float* Alog   = (const float*)d_in[17];
  const float* Dp     = (const float*)d_in[18];
  const float* out_w  = (const float*)d_in[19];
  const float* ln_g   = (const float*)d_in[20];
  const float* ln_b   = (const float*)d_in[21];
  const float* fc_w   = (const float*)d_in[22];
  const float* fc_b   = (const float*)d_in[23];

  char* ws = (char*)d_ws;
  unsigned short* U0 = (unsigned short*)(ws);
  unsigned short* xz = (unsigned short*)(ws);                 // after reduce2
  unsigned short* xc = (unsigned short*)(ws + 33554432);
  unsigned short* yb = (unsigned short*)(ws + 50331648);
  unsigned short* fwbf = (unsigned short*)(ws + 113246208);
  float* dbl = (float*)(ws + 150994944);
  unsigned short* xe2bf = (unsigned short*)(ws + 153616384);

  float* xflat = (float*)d_out;
  float* pred  = xflat + (size_t)64 * 32768;
  unsigned short* pwbf  = (unsigned short*)d_out;   // weight scratch until k_tail
  unsigned short* inwbf = pwbf + 49152;
  unsigned short* owbf  = inwbf + 131072;
  unsigned short* xwbf  = owbf + 65536;
  unsigned short* ewbf  = xwbf + 24576;

  hipFuncSetAttribute((const void*)k_mega, hipFuncAttributeMaxDynamicSharedMemorySize, MEGA_LDS);

  k_cvt<<<3445, 256, 0, stream>>>(pw_w, in_w, out_w, xp_w, emb_w, fc_w, fc_b, pwbf, fwbf, pred);

  k_mega<<<768, 512, MEGA_LDS, stream>>>(inp, ewbf, emb_b, dw_w, dw_b, pwbf, pw_b,
                                         se_w1, se_b1, se_w2, se_b2, U0);

  k_reduce2<<<1024, 256, 0, stream>>>(U0, xe2bf);

  for (int i = 0; i < 2; ++i) {
    k_inproj<<<512, 256, 0, stream>>>(xe2bf, inwbf + i * 65536, xz);
    k_xproj<<<512, 256, 0, stream>>>(xz, conv_w + i * 1024, conv_b + i * 256,
                                     xwbf + i * 12288, xc, dbl);
    k_scan2<<<512, 256, 0, stream>>>(dbl, xc, xz, Alog + i * 4096,
                                     dt_w + i * 2048, dt_b + i * 256, Dp + i * 256, yb);
    k_outln<<<512, 256, 0, stream>>>(yb, owbf + i * 32768, xe2bf,
                                     ln_g + i * 128, ln_b + i * 128);
  }

  k_tail<<<2176, 256, 0, stream>>>(xe2bf, xflat, fwbf, pred);
}